// Round 2
// baseline (2008.958 us; speedup 1.0000x reference)
//
#include <hip/hip_runtime.h>

// ---------------------------------------------------------------------------
// Problem constants (fixed by setup_inputs)
// ---------------------------------------------------------------------------
#define N_OP   50000
#define N_M    5000
#define N_A    2000
#define C_OP   256
#define C_M    128
#define C_A    128
#define E_OO   200000
#define E_OM   200000
#define E_MA   60000
#define E_DIM  8

#define OUT_OP_OFF 0
#define OUT_M_OFF  (N_OP * C_OP)
#define OUT_A_OFF  (N_OP * C_OP + N_M * C_M)

typedef short bf16x8 __attribute__((ext_vector_type(8)));
typedef float f32x4 __attribute__((ext_vector_type(4)));
typedef __attribute__((address_space(1))) const unsigned gu32;
typedef __attribute__((address_space(3))) unsigned lu32;

__device__ __forceinline__ unsigned short f2bf(float f) {
    unsigned u = __float_as_uint(f);
    unsigned r = (u + 0x7FFFu + ((u >> 16) & 1u)) >> 16;
    return (unsigned short)r;
}
__device__ __forceinline__ float bf2f(unsigned short h) {
    return __uint_as_float(((unsigned)h) << 16);
}

// ---------------------------------------------------------------------------
// fp32 -> bf16 conversion (vectorized, n % 4 == 0)
// ---------------------------------------------------------------------------
__global__ void cvt_bf16(const float* __restrict__ x, unsigned short* __restrict__ o, int n4) {
    int i = blockIdx.x * blockDim.x + threadIdx.x;
    if (i < n4) {
        float4 v = ((const float4*)x)[i];
        ushort4 r;
        r.x = f2bf(v.x); r.y = f2bf(v.y); r.z = f2bf(v.z); r.w = f2bf(v.w);
        ((ushort4*)o)[i] = r;
    }
}

// Pack two [K][N1] fp32 weights into transposed bf16 Bt[2*N1][K]
__global__ void pack_w2(const float* __restrict__ Wl, const float* __restrict__ Wr,
                        int K, int N1, unsigned short* __restrict__ Bt) {
    int idx = blockIdx.x * blockDim.x + threadIdx.x;
    if (idx >= 2 * N1 * K) return;
    int n = idx / K, k = idx - n * K;
    float v = (n < N1) ? Wl[k * N1 + n] : Wr[k * N1 + (n - N1)];
    Bt[idx] = f2bf(v);
}
// Pack one [K][N] fp32 weight into transposed bf16 Bt[N][K]
__global__ void pack_w1(const float* __restrict__ W, int K, int N, unsigned short* __restrict__ Bt) {
    int idx = blockIdx.x * blockDim.x + threadIdx.x;
    if (idx >= N * K) return;
    int n = idx / K, k = idx - n * K;
    Bt[idx] = f2bf(W[k * N + n]);
}
__global__ void pack_bias2(const float* __restrict__ bl, const float* __restrict__ br,
                           int N1, float* __restrict__ bp) {
    int i = blockIdx.x * blockDim.x + threadIdx.x;
    if (i < 2 * N1) bp[i] = (i < N1) ? bl[i] : br[i - N1];
}

// ---------------------------------------------------------------------------
// MFMA bf16 GEMM (m97 structure): C[M][ldc](bf16) = A[M][K](bf16) @ Bt[N][K]^T
// + bias.  BM=128, BN=128, BK=64, 256 threads = 4 waves in 2x2, each wave a
// 64x64 sub-tile of 4x4 16x16x32 fragments.  grid = (ceil(M/128), N/128).
// ---------------------------------------------------------------------------
__device__ __forceinline__ void gload_lds16(const void* g, void* l) {
    __builtin_amdgcn_global_load_lds((gu32*)g, (lu32*)l, 16, 0, 0);
}

__global__ __launch_bounds__(256) void mfma_gemm(
    const unsigned short* __restrict__ A, const unsigned short* __restrict__ Bt,
    const float* __restrict__ bias, unsigned short* __restrict__ C,
    int M, int K, int ldc) {
    __shared__ unsigned short As[128 * 64];
    __shared__ unsigned short Bs[128 * 64];

    const int tid  = threadIdx.x;
    const int lane = tid & 63;
    const int wid  = tid >> 6;
    const int m0   = blockIdx.x * 128;
    const int n0   = blockIdx.y * 128;

    f32x4 acc[4][4] = {};

    const int srow = tid >> 3;           // 0..31 (tile row within a 32-row round)
    const int scol = (tid & 7) * 8;      // bf16 element offset within row

    for (int k0 = 0; k0 < K; k0 += 64) {
#pragma unroll
        for (int i = 0; i < 4; ++i) {    // A tile: 128 rows x 64 cols
            int gr = m0 + i * 32 + srow;
            if (gr >= M) gr = M - 1;     // clamp (write-guarded later)
            gload_lds16(A + (size_t)gr * K + k0 + scol, &As[i * 2048 + tid * 8]);
        }
#pragma unroll
        for (int i = 0; i < 4; ++i) {    // B tile: 128 Bt-rows x 64 cols
            int gn = n0 + i * 32 + srow;
            gload_lds16(Bt + (size_t)gn * K + k0 + scol, &Bs[i * 2048 + tid * 8]);
        }
        asm volatile("s_waitcnt vmcnt(0)" ::: "memory");
        __syncthreads();

        const int wr = (wid >> 1) * 64;
        const int wc = (wid & 1) * 64;
#pragma unroll
        for (int kh = 0; kh < 2; ++kh) {
            const int ko = kh * 32 + (lane >> 4) * 8;
            bf16x8 a[4], b[4];
#pragma unroll
            for (int mi = 0; mi < 4; ++mi)
                a[mi] = *(const bf16x8*)&As[(wr + mi * 16 + (lane & 15)) * 64 + ko];
#pragma unroll
            for (int ni = 0; ni < 4; ++ni)
                b[ni] = *(const bf16x8*)&Bs[(wc + ni * 16 + (lane & 15)) * 64 + ko];
#pragma unroll
            for (int mi = 0; mi < 4; ++mi)
#pragma unroll
                for (int ni = 0; ni < 4; ++ni)
                    acc[mi][ni] = __builtin_amdgcn_mfma_f32_16x16x32_bf16(
                        a[mi], b[ni], acc[mi][ni], 0, 0, 0);
        }
        __syncthreads();
    }

    // epilogue: D row=(lane>>4)*4+j (A side), col=lane&15 (B side)  [m89]
    const int wr = (wid >> 1) * 64, wc = (wid & 1) * 64;
    const int crow = (lane >> 4) * 4;
    const int ccol = lane & 15;
#pragma unroll
    for (int ni = 0; ni < 4; ++ni) {
        const int col = n0 + wc + ni * 16 + ccol;
        const float b = bias[col];
#pragma unroll
        for (int mi = 0; mi < 4; ++mi) {
#pragma unroll
            for (int j = 0; j < 4; ++j) {
                const int row = m0 + wr + mi * 16 + crow + j;
                if (row < M) C[(size_t)row * ldc + col] = f2bf(acc[mi][ni][j] + b);
            }
        }
    }
}

// ---------------------------------------------------------------------------
// Small fp32 GEMM for edge features (K=8), bf16 output
// ---------------------------------------------------------------------------
template <int K, int N, int TM>
__global__ void gemm_ef(const float* __restrict__ A, const float* __restrict__ W,
                        unsigned short* __restrict__ out) {
    __shared__ float As[TM][K];
    const int m0 = blockIdx.x * TM;
    const int tid = threadIdx.x;
    for (int idx = tid; idx < TM * K; idx += N) {
        int r = idx / K, k = idx - r * K;
        As[r][k] = A[(m0 + r) * K + k];
    }
    __syncthreads();
    float acc[TM] = {};
    for (int k = 0; k < K; ++k) {
        const float w = W[k * N + tid];
#pragma unroll
        for (int r = 0; r < TM; ++r) acc[r] += As[r][k] * w;
    }
#pragma unroll
    for (int r = 0; r < TM; ++r) out[(m0 + r) * N + tid] = f2bf(acc[r]);
}

// ---------------------------------------------------------------------------
// Per-node init
// ---------------------------------------------------------------------------
__global__ void init_node(unsigned* __restrict__ nmax, float* __restrict__ denom, int n) {
    int i = blockIdx.x * blockDim.x + threadIdx.x;
    if (i < n) { nmax[i] = 0u; denom[i] = 0.0f; }
}

template <int C>
__global__ void init_out(const float* __restrict__ x, const float* __restrict__ b1,
                         const float* __restrict__ b2, float* __restrict__ out, int total) {
    int i = blockIdx.x * blockDim.x + threadIdx.x;
    if (i < total) {
        int c = i & (C - 1);
        float v = x[i] + b1[c];
        if (b2) v += b2[c];
        out[i] = v;
    }
}

__device__ __forceinline__ unsigned enc_f32(float f) {
    unsigned u = __float_as_uint(f);
    return (u & 0x80000000u) ? ~u : (u | 0x80000000u);
}
__device__ __forceinline__ float dec_f32(unsigned u) {
    return (u & 0x80000000u) ? __uint_as_float(u ^ 0x80000000u) : __uint_as_float(~u);
}

// ---------------------------------------------------------------------------
// Edge logit: e = leaky_relu(xl[src]+xr[dst](+ef)) . att  (1 wave / edge)
// xl/xr are bf16 with row strides ldl/ldr (column offset pre-added).
// ---------------------------------------------------------------------------
template <int C, bool HAS_EF>
__global__ void edge_logit(const unsigned short* __restrict__ xl, int ldl,
                           const unsigned short* __restrict__ xr, int ldr,
                           const unsigned short* __restrict__ ef,
                           const float* __restrict__ att,
                           const int* __restrict__ src, const int* __restrict__ dst,
                           float* __restrict__ e_out, unsigned* __restrict__ nmax, int E) {
    const int edge = blockIdx.x * (blockDim.x >> 6) + (threadIdx.x >> 6);
    if (edge >= E) return;
    const int lane = threadIdx.x & 63;
    const int s = src[edge], d = dst[edge];
    constexpr int V = C / 64;
    const int c0 = lane * V;

    unsigned short lv[V], rv[V], ev[V];
    const unsigned short* pl = xl + (size_t)s * ldl + c0;
    const unsigned short* pr = xr + (size_t)d * ldr + c0;
    if constexpr (V == 4) {
        *(uint2*)lv = *(const uint2*)pl;
        *(uint2*)rv = *(const uint2*)pr;
        if (HAS_EF) *(uint2*)ev = *(const uint2*)(ef + (size_t)edge * C + c0);
    } else {
        *(unsigned*)lv = *(const unsigned*)pl;
        *(unsigned*)rv = *(const unsigned*)pr;
        if (HAS_EF) *(unsigned*)ev = *(const unsigned*)(ef + (size_t)edge * C + c0);
    }

    float acc = 0.0f;
#pragma unroll
    for (int v = 0; v < V; ++v) {
        float m = bf2f(lv[v]) + bf2f(rv[v]);
        if (HAS_EF) m += bf2f(ev[v]);
        m = (m >= 0.0f) ? m : 0.2f * m;
        acc += m * att[c0 + v];
    }
#pragma unroll
    for (int o = 32; o > 0; o >>= 1) acc += __shfl_xor(acc, o, 64);

    if (lane == 0) {
        e_out[edge] = acc;
        atomicMax(&nmax[d], enc_f32(acc));
    }
}

__global__ void edge_exp(float* __restrict__ e, const int* __restrict__ dst,
                         const unsigned* __restrict__ nmax, float* __restrict__ denom, int E) {
    int i = blockIdx.x * blockDim.x + threadIdx.x;
    if (i >= E) return;
    const int d = dst[i];
    const float ee = __expf(e[i] - dec_f32(nmax[d]));
    e[i] = ee;
    atomicAdd(&denom[d], ee);
}

// ---------------------------------------------------------------------------
// out[dst] += (ee/denom[dst]) * xl[src]  (1 wave / edge, f32 atomics)
// ---------------------------------------------------------------------------
template <int C>
__global__ void edge_aggregate(const unsigned short* __restrict__ xl, int ldl,
                               const float* __restrict__ ee, const float* __restrict__ denom,
                               const int* __restrict__ src, const int* __restrict__ dst,
                               float* __restrict__ out, int E) {
    const int edge = blockIdx.x * (blockDim.x >> 6) + (threadIdx.x >> 6);
    if (edge >= E) return;
    const int lane = threadIdx.x & 63;
    const int s = src[edge], d = dst[edge];
    const float alpha = ee[edge] / fmaxf(denom[d], 1e-16f);
    constexpr int V = C / 64;
    const int c0 = lane * V;

    unsigned short lv[V];
    const unsigned short* pl = xl + (size_t)s * ldl + c0;
    if constexpr (V == 4) *(uint2*)lv = *(const uint2*)pl;
    else                  *(unsigned*)lv = *(const unsigned*)pl;
#pragma unroll
    for (int v = 0; v < V; ++v)
        atomicAdd(&out[(size_t)d * C + c0 + v], alpha * bf2f(lv[v]));
}

// ---------------------------------------------------------------------------
// Workspace layout (float offsets).  Total ~80.5 MB (proven ws >= 104 MB).
// ---------------------------------------------------------------------------
#define F_H      0           // ushort[25,600,000]  H: gemm outputs (bf16)
#define F_XCOP   12800000    // ushort[12,800,000]  x_op bf16
#define F_XCM    19200000    // ushort[640,000]
#define F_XCA    19520000    // ushort[256,000]
#define F_BTP    19648000    // ushort[131072] Bt pred (Wl|Wr)^T
#define F_BTS    19713536    // ushort[131072] Bt succ
#define F_BTOL   19779072    // ushort[32768]  Bt o2m Wl^T [128][256]
#define F_BTOR   19795456    // ushort[16384]  Bt o2m Wr^T [128][128]
#define F_BTML   19803648    // ushort[16384]  Bt m2a Wl^T
#define F_BTMR   19811840    // ushort[16384]  Bt m2a Wr^T
#define F_BIASP  19820032    // f32[512]
#define F_BIASS  19820544    // f32[512]
#define F_EBUF   19821056    // f32[200,000]
#define F_NMAX   20021056    // u32[50,000]
#define F_DENOM  20071056    // f32[50,000]

extern "C" void kernel_launch(void* const* d_in, const int* in_sizes, int n_in,
                              void* d_out, int out_size, void* d_ws, size_t ws_size,
                              hipStream_t stream) {
    const float* x_op    = (const float*)d_in[0];
    const float* x_m     = (const float*)d_in[1];
    const float* x_a     = (const float*)d_in[2];
    const int*   ei_pred = (const int*)d_in[3];
    const int*   ei_succ = (const int*)d_in[4];
    const int*   src_o2m = (const int*)d_in[5];
    const int*   dst_o2m = (const int*)d_in[6];
    const int*   src_m2a = (const int*)d_in[7];
    const int*   dst_m2a = (const int*)d_in[8];
    const float* ea_m2a  = (const float*)d_in[9];

    const float* Wl_pred = (const float*)d_in[10];
    const float* bl_pred = (const float*)d_in[11];
    const float* Wr_pred = (const float*)d_in[12];
    const float* br_pred = (const float*)d_in[13];
    const float* att_pred= (const float*)d_in[14];
    const float* b_pred  = (const float*)d_in[15];

    const float* Wl_succ = (const float*)d_in[16];
    const float* bl_succ = (const float*)d_in[17];
    const float* Wr_succ = (const float*)d_in[18];
    const float* br_succ = (const float*)d_in[19];
    const float* att_succ= (const float*)d_in[20];
    const float* b_succ  = (const float*)d_in[21];

    const float* Wl_o2m  = (const float*)d_in[22];
    const float* bl_o2m  = (const float*)d_in[23];
    const float* Wr_o2m  = (const float*)d_in[24];
    const float* br_o2m  = (const float*)d_in[25];
    const float* att_o2m = (const float*)d_in[26];
    const float* b_o2m   = (const float*)d_in[27];

    const float* Wl_m2a  = (const float*)d_in[28];
    const float* bl_m2a  = (const float*)d_in[29];
    const float* Wr_m2a  = (const float*)d_in[30];
    const float* br_m2a  = (const float*)d_in[31];
    const float* att_m2a = (const float*)d_in[32];
    const float* b_m2a   = (const float*)d_in[33];
    const float* We_m2a  = (const float*)d_in[34];

    float* ws = (float*)d_ws;
    unsigned short* H     = (unsigned short*)(ws + F_H);
    unsigned short* xc_op = (unsigned short*)(ws + F_XCOP);
    unsigned short* xc_m  = (unsigned short*)(ws + F_XCM);
    unsigned short* xc_a  = (unsigned short*)(ws + F_XCA);
    unsigned short* BtP   = (unsigned short*)(ws + F_BTP);
    unsigned short* BtS   = (unsigned short*)(ws + F_BTS);
    unsigned short* BtOL  = (unsigned short*)(ws + F_BTOL);
    unsigned short* BtOR  = (unsigned short*)(ws + F_BTOR);
    unsigned short* BtML  = (unsigned short*)(ws + F_BTML);
    unsigned short* BtMR  = (unsigned short*)(ws + F_BTMR);
    float*    biasP = ws + F_BIASP;
    float*    biasS = ws + F_BIASS;
    float*    ebuf  = ws + F_EBUF;
    unsigned* nmax  = (unsigned*)(ws + F_NMAX);
    float*    denom = ws + F_DENOM;

    float* out_op = (float*)d_out + OUT_OP_OFF;
    float* out_m  = (float*)d_out + OUT_M_OFF;
    float* out_a  = (float*)d_out + OUT_A_OFF;

    // ---- conversions & weight packing ----
    cvt_bf16<<<(N_OP * C_OP / 4 + 255) / 256, 256, 0, stream>>>(x_op, xc_op, N_OP * C_OP / 4);
    cvt_bf16<<<(N_M * C_M / 4 + 255) / 256, 256, 0, stream>>>(x_m, xc_m, N_M * C_M / 4);
    cvt_bf16<<<(N_A * C_A / 4 + 255) / 256, 256, 0, stream>>>(x_a, xc_a, N_A * C_A / 4);
    pack_w2<<<(2 * 256 * 256 + 255) / 256, 256, 0, stream>>>(Wl_pred, Wr_pred, 256, 256, BtP);
    pack_w2<<<(2 * 256 * 256 + 255) / 256, 256, 0, stream>>>(Wl_succ, Wr_succ, 256, 256, BtS);
    pack_w1<<<(128 * 256 + 255) / 256, 256, 0, stream>>>(Wl_o2m, 256, 128, BtOL);
    pack_w1<<<(128 * 128 + 255) / 256, 256, 0, stream>>>(Wr_o2m, 128, 128, BtOR);
    pack_w1<<<(128 * 128 + 255) / 256, 256, 0, stream>>>(Wl_m2a, 128, 128, BtML);
    pack_w1<<<(128 * 128 + 255) / 256, 256, 0, stream>>>(Wr_m2a, 128, 128, BtMR);
    pack_bias2<<<2, 256, 0, stream>>>(bl_pred, br_pred, 256, biasP);
    pack_bias2<<<2, 256, 0, stream>>>(bl_succ, br_succ, 256, biasS);

    // ---- output init: residual + conv biases ----
    init_out<C_OP><<<(N_OP * C_OP + 255) / 256, 256, 0, stream>>>(x_op, b_pred, b_succ, out_op, N_OP * C_OP);
    init_out<C_M ><<<(N_M * C_M + 255) / 256, 256, 0, stream>>>(x_m, b_o2m, nullptr, out_m, N_M * C_M);
    init_out<C_A ><<<(N_A * C_A + 255) / 256, 256, 0, stream>>>(x_a, b_m2a, nullptr, out_a, N_A * C_A);

    const int MT_OP = (N_OP + 127) / 128;   // 391
    const int MT_M  = (N_M + 127) / 128;    // 40
    const int MT_A  = (N_A + 127) / 128;    // 16

    // ---------------- conv 1: pred (op->op, C=256), H = [50000][512] ----------------
    mfma_gemm<<<dim3(MT_OP, 4), 256, 0, stream>>>(xc_op, BtP, biasP, H, N_OP, 256, 512);
    init_node<<<(N_OP + 255) / 256, 256, 0, stream>>>(nmax, denom, N_OP);
    edge_logit<256, false><<<E_OO / 4, 256, 0, stream>>>(H, 512, H + 256, 512, nullptr, att_pred,
                                                         ei_pred, ei_pred + E_OO, ebuf, nmax, E_OO);
    edge_exp<<<(E_OO + 255) / 256, 256, 0, stream>>>(ebuf, ei_pred + E_OO, nmax, denom, E_OO);
    edge_aggregate<256><<<E_OO / 4, 256, 0, stream>>>(H, 512, ebuf, denom,
                                                      ei_pred, ei_pred + E_OO, out_op, E_OO);

    // ---------------- conv 2: succ ----------------
    mfma_gemm<<<dim3(MT_OP, 4), 256, 0, stream>>>(xc_op, BtS, biasS, H, N_OP, 256, 512);
    init_node<<<(N_OP + 255) / 256, 256, 0, stream>>>(nmax, denom, N_OP);
    edge_logit<256, false><<<E_OO / 4, 256, 0, stream>>>(H, 512, H + 256, 512, nullptr, att_succ,
                                                         ei_succ, ei_succ + E_OO, ebuf, nmax, E_OO);
    edge_exp<<<(E_OO + 255) / 256, 256, 0, stream>>>(ebuf, ei_succ + E_OO, nmax, denom, E_OO);
    edge_aggregate<256><<<E_OO / 4, 256, 0, stream>>>(H, 512, ebuf, denom,
                                                      ei_succ, ei_succ + E_OO, out_op, E_OO);

    // ---------------- conv 3: o2m (op->machine, C=128) ----------------
    {
        unsigned short* xlb = H;                 // [50000][128]
        unsigned short* xrb = H + 6400000;       // [5000][128]
        mfma_gemm<<<dim3(MT_OP, 1), 256, 0, stream>>>(xc_op, BtOL, bl_o2m, xlb, N_OP, 256, 128);
        mfma_gemm<<<dim3(MT_M, 1), 256, 0, stream>>>(xc_m, BtOR, br_o2m, xrb, N_M, 128, 128);
        init_node<<<(N_M + 255) / 256, 256, 0, stream>>>(nmax, denom, N_M);
        edge_logit<128, false><<<E_OM / 4, 256, 0, stream>>>(xlb, 128, xrb, 128, nullptr, att_o2m,
                                                             src_o2m, dst_o2m, ebuf, nmax, E_OM);
        edge_exp<<<(E_OM + 255) / 256, 256, 0, stream>>>(ebuf, dst_o2m, nmax, denom, E_OM);
        edge_aggregate<128><<<E_OM / 4, 256, 0, stream>>>(xlb, 128, ebuf, denom,
                                                          src_o2m, dst_o2m, out_m, E_OM);
    }

    // ---------------- conv 4: m2a (machine->agv, C=128, edge feats) ----------------
    {
        unsigned short* xlb = H;                 // [5000][128]
        unsigned short* xrb = H + 1000000;       // [2000][128]
        unsigned short* efb = H + 2000000;       // [60000][128]
        mfma_gemm<<<dim3(MT_M, 1), 256, 0, stream>>>(xc_m, BtML, bl_m2a, xlb, N_M, 128, 128);
        mfma_gemm<<<dim3(MT_A, 1), 256, 0, stream>>>(xc_a, BtMR, br_m2a, xrb, N_A, 128, 128);
        gemm_ef<8, 128, 4><<<E_MA / 4, 128, 0, stream>>>(ea_m2a, We_m2a, efb);
        init_node<<<(N_A + 255) / 256, 256, 0, stream>>>(nmax, denom, N_A);
        edge_logit<128, true><<<E_MA / 4, 256, 0, stream>>>(xlb, 128, xrb, 128, efb, att_m2a,
                                                            src_m2a, dst_m2a, ebuf, nmax, E_MA);
        edge_exp<<<(E_MA + 255) / 256, 256, 0, stream>>>(ebuf, dst_m2a, nmax, denom, E_MA);
        edge_aggregate<128><<<E_MA / 4, 256, 0, stream>>>(xlb, 128, ebuf, denom,
                                                          src_m2a, dst_m2a, out_a, E_MA);
    }
}

// Round 3
// 834.320 us; speedup vs baseline: 2.4079x; 2.4079x over previous
//
#include <hip/hip_runtime.h>

// ---------------------------------------------------------------------------
// Problem constants (fixed by setup_inputs)
// ---------------------------------------------------------------------------
#define N_OP   50000
#define N_M    5000
#define N_A    2000
#define C_OP   256
#define C_M    128
#define C_A    128
#define E_OO   200000
#define E_OM   200000
#define E_MA   60000
#define E_DIM  8

#define OUT_OP_OFF 0
#define OUT_M_OFF  (N_OP * C_OP)
#define OUT_A_OFF  (N_OP * C_OP + N_M * C_M)

typedef short bf16x8 __attribute__((ext_vector_type(8)));
typedef float f32x4 __attribute__((ext_vector_type(4)));
typedef __attribute__((address_space(1))) const unsigned gu32;
typedef __attribute__((address_space(3))) unsigned lu32;

__device__ __forceinline__ unsigned short f2bf(float f) {
    unsigned u = __float_as_uint(f);
    unsigned r = (u + 0x7FFFu + ((u >> 16) & 1u)) >> 16;
    return (unsigned short)r;
}
__device__ __forceinline__ float bf2f(unsigned short h) {
    return __uint_as_float(((unsigned)h) << 16);
}

// ---------------------------------------------------------------------------
// fp32 -> bf16 conversion (vectorized, n % 4 == 0)
// ---------------------------------------------------------------------------
__global__ void cvt_bf16(const float* __restrict__ x, unsigned short* __restrict__ o, int n4) {
    int i = blockIdx.x * blockDim.x + threadIdx.x;
    if (i < n4) {
        float4 v = ((const float4*)x)[i];
        ushort4 r;
        r.x = f2bf(v.x); r.y = f2bf(v.y); r.z = f2bf(v.z); r.w = f2bf(v.w);
        ((ushort4*)o)[i] = r;
    }
}

__global__ void pack_w2(const float* __restrict__ Wl, const float* __restrict__ Wr,
                        int K, int N1, unsigned short* __restrict__ Bt) {
    int idx = blockIdx.x * blockDim.x + threadIdx.x;
    if (idx >= 2 * N1 * K) return;
    int n = idx / K, k = idx - n * K;
    float v = (n < N1) ? Wl[k * N1 + n] : Wr[k * N1 + (n - N1)];
    Bt[idx] = f2bf(v);
}
__global__ void pack_w1(const float* __restrict__ W, int K, int N, unsigned short* __restrict__ Bt) {
    int idx = blockIdx.x * blockDim.x + threadIdx.x;
    if (idx >= N * K) return;
    int n = idx / K, k = idx - n * K;
    Bt[idx] = f2bf(W[k * N + n]);
}
__global__ void pack_bias2(const float* __restrict__ bl, const float* __restrict__ br,
                           int N1, float* __restrict__ bp) {
    int i = blockIdx.x * blockDim.x + threadIdx.x;
    if (i < 2 * N1) bp[i] = (i < N1) ? bl[i] : br[i - N1];
}

// ---------------------------------------------------------------------------
// MFMA bf16 GEMM (m97 structure) — unchanged from round 2 (verified).
// ---------------------------------------------------------------------------
__device__ __forceinline__ void gload_lds16(const void* g, void* l) {
    __builtin_amdgcn_global_load_lds((gu32*)g, (lu32*)l, 16, 0, 0);
}

__global__ __launch_bounds__(256) void mfma_gemm(
    const unsigned short* __restrict__ A, const unsigned short* __restrict__ Bt,
    const float* __restrict__ bias, unsigned short* __restrict__ C,
    int M, int K, int ldc) {
    __shared__ unsigned short As[128 * 64];
    __shared__ unsigned short Bs[128 * 64];

    const int tid  = threadIdx.x;
    const int lane = tid & 63;
    const int wid  = tid >> 6;
    const int m0   = blockIdx.x * 128;
    const int n0   = blockIdx.y * 128;

    f32x4 acc[4][4] = {};

    const int srow = tid >> 3;
    const int scol = (tid & 7) * 8;

    for (int k0 = 0; k0 < K; k0 += 64) {
#pragma unroll
        for (int i = 0; i < 4; ++i) {
            int gr = m0 + i * 32 + srow;
            if (gr >= M) gr = M - 1;
            gload_lds16(A + (size_t)gr * K + k0 + scol, &As[i * 2048 + tid * 8]);
        }
#pragma unroll
        for (int i = 0; i < 4; ++i) {
            int gn = n0 + i * 32 + srow;
            gload_lds16(Bt + (size_t)gn * K + k0 + scol, &Bs[i * 2048 + tid * 8]);
        }
        asm volatile("s_waitcnt vmcnt(0)" ::: "memory");
        __syncthreads();

        const int wr = (wid >> 1) * 64;
        const int wc = (wid & 1) * 64;
#pragma unroll
        for (int kh = 0; kh < 2; ++kh) {
            const int ko = kh * 32 + (lane >> 4) * 8;
            bf16x8 a[4], b[4];
#pragma unroll
            for (int mi = 0; mi < 4; ++mi)
                a[mi] = *(const bf16x8*)&As[(wr + mi * 16 + (lane & 15)) * 64 + ko];
#pragma unroll
            for (int ni = 0; ni < 4; ++ni)
                b[ni] = *(const bf16x8*)&Bs[(wc + ni * 16 + (lane & 15)) * 64 + ko];
#pragma unroll
            for (int mi = 0; mi < 4; ++mi)
#pragma unroll
                for (int ni = 0; ni < 4; ++ni)
                    acc[mi][ni] = __builtin_amdgcn_mfma_f32_16x16x32_bf16(
                        a[mi], b[ni], acc[mi][ni], 0, 0, 0);
        }
        __syncthreads();
    }

    const int wr = (wid >> 1) * 64, wc = (wid & 1) * 64;
    const int crow = (lane >> 4) * 4;
    const int ccol = lane & 15;
#pragma unroll
    for (int ni = 0; ni < 4; ++ni) {
        const int col = n0 + wc + ni * 16 + ccol;
        const float b = bias[col];
#pragma unroll
        for (int mi = 0; mi < 4; ++mi) {
#pragma unroll
            for (int j = 0; j < 4; ++j) {
                const int row = m0 + wr + mi * 16 + crow + j;
                if (row < M) C[(size_t)row * ldc + col] = f2bf(acc[mi][ni][j] + b);
            }
        }
    }
}

// ---------------------------------------------------------------------------
// Small fp32 GEMM for edge features (K=8), bf16 output
// ---------------------------------------------------------------------------
template <int K, int N, int TM>
__global__ void gemm_ef(const float* __restrict__ A, const float* __restrict__ W,
                        unsigned short* __restrict__ out) {
    __shared__ float As[TM][K];
    const int m0 = blockIdx.x * TM;
    const int tid = threadIdx.x;
    for (int idx = tid; idx < TM * K; idx += N) {
        int r = idx / K, k = idx - r * K;
        As[r][k] = A[(m0 + r) * K + k];
    }
    __syncthreads();
    float acc[TM] = {};
    for (int k = 0; k < K; ++k) {
        const float w = W[k * N + tid];
#pragma unroll
        for (int r = 0; r < TM; ++r) acc[r] += As[r][k] * w;
    }
#pragma unroll
    for (int r = 0; r < TM; ++r) out[(m0 + r) * N + tid] = f2bf(acc[r]);
}

// ---------------------------------------------------------------------------
// init_out: out = x + b1 (+ b2)  (residual + conv output biases pre-applied)
// ---------------------------------------------------------------------------
template <int C>
__global__ void init_out(const float* __restrict__ x, const float* __restrict__ b1,
                         const float* __restrict__ b2, float* __restrict__ out, int total) {
    int i = blockIdx.x * blockDim.x + threadIdx.x;
    if (i < total) {
        int c = i & (C - 1);
        float v = x[i] + b1[c];
        if (b2) v += b2[c];
        out[i] = v;
    }
}

// ---------------------------------------------------------------------------
// CSR build: zero -> histogram -> exclusive scan -> zero -> scatter
// ---------------------------------------------------------------------------
__global__ void zero_i32(int* __restrict__ p, int n) {
    int i = blockIdx.x * blockDim.x + threadIdx.x;
    if (i < n) p[i] = 0;
}
__global__ void hist_dst(const int* __restrict__ dst, int* __restrict__ cnt, int E) {
    int i = blockIdx.x * blockDim.x + threadIdx.x;
    if (i < E) atomicAdd(&cnt[dst[i]], 1);
}
// single-block exclusive scan, n <= a few hundred K
__global__ void ex_scan(const int* __restrict__ cnt, int* __restrict__ ptr, int n) {
    __shared__ int smem[1024];
    __shared__ int base;
    const int tid = threadIdx.x;
    if (tid == 0) base = 0;
    __syncthreads();
    for (int t0 = 0; t0 < n; t0 += 1024) {
        const int i = t0 + tid;
        const int v = (i < n) ? cnt[i] : 0;
        smem[tid] = v;
        __syncthreads();
        for (int o = 1; o < 1024; o <<= 1) {
            int t = (tid >= o) ? smem[tid - o] : 0;
            __syncthreads();
            smem[tid] += t;
            __syncthreads();
        }
        if (i < n) ptr[i] = base + smem[tid] - v;
        __syncthreads();
        if (tid == 1023) base += smem[1023];
        __syncthreads();
    }
    if (tid == 0) ptr[n] = base;
}
__global__ void scatter_e(const int* __restrict__ src, const int* __restrict__ dst,
                          const int* __restrict__ ptr, int* __restrict__ cur,
                          int* __restrict__ srcs, int* __restrict__ eidx, int E) {
    int i = blockIdx.x * blockDim.x + threadIdx.x;
    if (i >= E) return;
    const int d = dst[i];
    const int pos = ptr[d] + atomicAdd(&cur[d], 1);
    srcs[pos] = src[i];
    eidx[pos] = i;
}

// ---------------------------------------------------------------------------
// Edge logit: e = leaky_relu(xl[src]+xr[dst](+ef)) . att  (1 wave / edge)
// ---------------------------------------------------------------------------
template <int C, bool HAS_EF>
__global__ void edge_logit(const unsigned short* __restrict__ xl, int ldl,
                           const unsigned short* __restrict__ xr, int ldr,
                           const unsigned short* __restrict__ ef,
                           const float* __restrict__ att,
                           const int* __restrict__ src, const int* __restrict__ dst,
                           float* __restrict__ e_out, int E) {
    const int edge = blockIdx.x * (blockDim.x >> 6) + (threadIdx.x >> 6);
    if (edge >= E) return;
    const int lane = threadIdx.x & 63;
    const int s = src[edge], d = dst[edge];
    constexpr int V = C / 64;
    const int c0 = lane * V;

    unsigned short lv[V], rv[V], ev[V];
    const unsigned short* pl = xl + (size_t)s * ldl + c0;
    const unsigned short* pr = xr + (size_t)d * ldr + c0;
    if constexpr (V == 4) {
        *(uint2*)lv = *(const uint2*)pl;
        *(uint2*)rv = *(const uint2*)pr;
        if (HAS_EF) *(uint2*)ev = *(const uint2*)(ef + (size_t)edge * C + c0);
    } else {
        *(unsigned*)lv = *(const unsigned*)pl;
        *(unsigned*)rv = *(const unsigned*)pr;
        if (HAS_EF) *(unsigned*)ev = *(const unsigned*)(ef + (size_t)edge * C + c0);
    }

    float acc = 0.0f;
#pragma unroll
    for (int v = 0; v < V; ++v) {
        float m = bf2f(lv[v]) + bf2f(rv[v]);
        if (HAS_EF) m += bf2f(ev[v]);
        m = (m >= 0.0f) ? m : 0.2f * m;
        acc += m * att[c0 + v];
    }
#pragma unroll
    for (int o = 32; o > 0; o >>= 1) acc += __shfl_xor(acc, o, 64);

    if (lane == 0) e_out[edge] = acc;
}

// ---------------------------------------------------------------------------
// Fused softmax + aggregate over CSR: one wave per dst node, zero atomics.
// out[node] += sum_j softmax(e)_j * xl[srcs[j]]
// ---------------------------------------------------------------------------
template <int C>
__global__ void csr_agg(const unsigned short* __restrict__ xl, int ldl,
                        const float* __restrict__ e,
                        const int* __restrict__ ptr, const int* __restrict__ srcs,
                        const int* __restrict__ eidx,
                        float* __restrict__ out, int n) {
    const int node = blockIdx.x * (blockDim.x >> 6) + (threadIdx.x >> 6);
    if (node >= n) return;
    const int lane = threadIdx.x & 63;
    const int beg = ptr[node], end = ptr[node + 1];
    if (beg == end) return;

    float m = -3.0e38f;
    for (int j = beg + lane; j < end; j += 64) m = fmaxf(m, e[eidx[j]]);
#pragma unroll
    for (int o = 32; o > 0; o >>= 1) m = fmaxf(m, __shfl_xor(m, o, 64));

    float s = 0.0f;
    for (int j = beg + lane; j < end; j += 64) s += __expf(e[eidx[j]] - m);
#pragma unroll
    for (int o = 32; o > 0; o >>= 1) s += __shfl_xor(s, o, 64);
    const float inv = 1.0f / fmaxf(s, 1e-16f);

    constexpr int V = C / 64;
    float acc[V] = {};
    for (int j = beg; j < end; ++j) {
        const float w = __expf(e[eidx[j]] - m) * inv;
        const unsigned short* row = xl + (size_t)srcs[j] * ldl + lane * V;
        unsigned short lv[V];
        if constexpr (V == 4) *(uint2*)lv = *(const uint2*)row;
        else                  *(unsigned*)lv = *(const unsigned*)row;
#pragma unroll
        for (int v = 0; v < V; ++v) acc[v] += w * bf2f(lv[v]);
    }
    float* po = out + (size_t)node * C + lane * V;
#pragma unroll
    for (int v = 0; v < V; ++v) po[v] += acc[v];
}

// ---------------------------------------------------------------------------
// Workspace layout (float/int slots).  Total ~86 MB (ws proven >= 103.6 MB).
// ---------------------------------------------------------------------------
#define F_H      0           // ushort[25,600,000]
#define F_XCOP   12800000    // ushort[12,800,000]
#define F_XCM    19200000
#define F_XCA    19520000
#define F_BTP    19648000
#define F_BTS    19713536
#define F_BTOL   19779072
#define F_BTOR   19795456
#define F_BTML   19803648
#define F_BTMR   19811840
#define F_BIASP  19820032
#define F_BIASS  19820544
#define F_EBUF   19821056    // f32[200,000]
#define F_CNT    20030000    // int[50,000] (hist + cursor, reused)
#define F_PTR_P  20080008    // int[50,001]
#define F_SRC_P  20130016    // int[200,000]
#define F_EID_P  20330016
#define F_PTR_S  20530016    // int[50,001]
#define F_SRC_S  20580024
#define F_EID_S  20780024
#define F_PTR_O  20980024    // int[5,001]
#define F_SRC_O  20985032
#define F_EID_O  21185032
#define F_PTR_A  21385032    // int[2,001]
#define F_SRC_A  21387040
#define F_EID_A  21447040    // end 21,507,040 floats = 86.0 MB

static void build_csr(const int* src, const int* dst, int E, int n,
                      int* cnt, int* ptr, int* srcs, int* eidx, hipStream_t stream) {
    zero_i32<<<(n + 255) / 256, 256, 0, stream>>>(cnt, n);
    hist_dst<<<(E + 255) / 256, 256, 0, stream>>>(dst, cnt, E);
    ex_scan<<<1, 1024, 0, stream>>>(cnt, ptr, n);
    zero_i32<<<(n + 255) / 256, 256, 0, stream>>>(cnt, n);
    scatter_e<<<(E + 255) / 256, 256, 0, stream>>>(src, dst, ptr, cnt, srcs, eidx, E);
}

extern "C" void kernel_launch(void* const* d_in, const int* in_sizes, int n_in,
                              void* d_out, int out_size, void* d_ws, size_t ws_size,
                              hipStream_t stream) {
    const float* x_op    = (const float*)d_in[0];
    const float* x_m     = (const float*)d_in[1];
    const float* x_a     = (const float*)d_in[2];
    const int*   ei_pred = (const int*)d_in[3];
    const int*   ei_succ = (const int*)d_in[4];
    const int*   src_o2m = (const int*)d_in[5];
    const int*   dst_o2m = (const int*)d_in[6];
    const int*   src_m2a = (const int*)d_in[7];
    const int*   dst_m2a = (const int*)d_in[8];
    const float* ea_m2a  = (const float*)d_in[9];

    const float* Wl_pred = (const float*)d_in[10];
    const float* bl_pred = (const float*)d_in[11];
    const float* Wr_pred = (const float*)d_in[12];
    const float* br_pred = (const float*)d_in[13];
    const float* att_pred= (const float*)d_in[14];
    const float* b_pred  = (const float*)d_in[15];

    const float* Wl_succ = (const float*)d_in[16];
    const float* bl_succ = (const float*)d_in[17];
    const float* Wr_succ = (const float*)d_in[18];
    const float* br_succ = (const float*)d_in[19];
    const float* att_succ= (const float*)d_in[20];
    const float* b_succ  = (const float*)d_in[21];

    const float* Wl_o2m  = (const float*)d_in[22];
    const float* bl_o2m  = (const float*)d_in[23];
    const float* Wr_o2m  = (const float*)d_in[24];
    const float* br_o2m  = (const float*)d_in[25];
    const float* att_o2m = (const float*)d_in[26];
    const float* b_o2m   = (const float*)d_in[27];

    const float* Wl_m2a  = (const float*)d_in[28];
    const float* bl_m2a  = (const float*)d_in[29];
    const float* Wr_m2a  = (const float*)d_in[30];
    const float* br_m2a  = (const float*)d_in[31];
    const float* att_m2a = (const float*)d_in[32];
    const float* b_m2a   = (const float*)d_in[33];
    const float* We_m2a  = (const float*)d_in[34];

    float* ws = (float*)d_ws;
    unsigned short* H     = (unsigned short*)(ws + F_H);
    unsigned short* xc_op = (unsigned short*)(ws + F_XCOP);
    unsigned short* xc_m  = (unsigned short*)(ws + F_XCM);
    unsigned short* xc_a  = (unsigned short*)(ws + F_XCA);
    unsigned short* BtP   = (unsigned short*)(ws + F_BTP);
    unsigned short* BtS   = (unsigned short*)(ws + F_BTS);
    unsigned short* BtOL  = (unsigned short*)(ws + F_BTOL);
    unsigned short* BtOR  = (unsigned short*)(ws + F_BTOR);
    unsigned short* BtML  = (unsigned short*)(ws + F_BTML);
    unsigned short* BtMR  = (unsigned short*)(ws + F_BTMR);
    float* biasP = ws + F_BIASP;
    float* biasS = ws + F_BIASS;
    float* ebuf  = ws + F_EBUF;
    int* cnt   = (int*)(ws + F_CNT);
    int* ptrP  = (int*)(ws + F_PTR_P); int* srcP = (int*)(ws + F_SRC_P); int* eidP = (int*)(ws + F_EID_P);
    int* ptrS  = (int*)(ws + F_PTR_S); int* srcS = (int*)(ws + F_SRC_S); int* eidS = (int*)(ws + F_EID_S);
    int* ptrO  = (int*)(ws + F_PTR_O); int* srcO = (int*)(ws + F_SRC_O); int* eidO = (int*)(ws + F_EID_O);
    int* ptrA  = (int*)(ws + F_PTR_A); int* srcA = (int*)(ws + F_SRC_A); int* eidA = (int*)(ws + F_EID_A);

    float* out_op = (float*)d_out + OUT_OP_OFF;
    float* out_m  = (float*)d_out + OUT_M_OFF;
    float* out_a  = (float*)d_out + OUT_A_OFF;

    // ---- CSR builds (independent of GEMMs) ----
    build_csr(ei_pred, ei_pred + E_OO, E_OO, N_OP, cnt, ptrP, srcP, eidP, stream);
    build_csr(ei_succ, ei_succ + E_OO, E_OO, N_OP, cnt, ptrS, srcS, eidS, stream);
    build_csr(src_o2m, dst_o2m, E_OM, N_M, cnt, ptrO, srcO, eidO, stream);
    build_csr(src_m2a, dst_m2a, E_MA, N_A, cnt, ptrA, srcA, eidA, stream);

    // ---- conversions & weight packing ----
    cvt_bf16<<<(N_OP * C_OP / 4 + 255) / 256, 256, 0, stream>>>(x_op, xc_op, N_OP * C_OP / 4);
    cvt_bf16<<<(N_M * C_M / 4 + 255) / 256, 256, 0, stream>>>(x_m, xc_m, N_M * C_M / 4);
    cvt_bf16<<<(N_A * C_A / 4 + 255) / 256, 256, 0, stream>>>(x_a, xc_a, N_A * C_A / 4);
    pack_w2<<<(2 * 256 * 256 + 255) / 256, 256, 0, stream>>>(Wl_pred, Wr_pred, 256, 256, BtP);
    pack_w2<<<(2 * 256 * 256 + 255) / 256, 256, 0, stream>>>(Wl_succ, Wr_succ, 256, 256, BtS);
    pack_w1<<<(128 * 256 + 255) / 256, 256, 0, stream>>>(Wl_o2m, 256, 128, BtOL);
    pack_w1<<<(128 * 128 + 255) / 256, 256, 0, stream>>>(Wr_o2m, 128, 128, BtOR);
    pack_w1<<<(128 * 128 + 255) / 256, 256, 0, stream>>>(Wl_m2a, 128, 128, BtML);
    pack_w1<<<(128 * 128 + 255) / 256, 256, 0, stream>>>(Wr_m2a, 128, 128, BtMR);
    pack_bias2<<<2, 256, 0, stream>>>(bl_pred, br_pred, 256, biasP);
    pack_bias2<<<2, 256, 0, stream>>>(bl_succ, br_succ, 256, biasS);

    // ---- output init: residual + conv biases ----
    init_out<C_OP><<<(N_OP * C_OP + 255) / 256, 256, 0, stream>>>(x_op, b_pred, b_succ, out_op, N_OP * C_OP);
    init_out<C_M ><<<(N_M * C_M + 255) / 256, 256, 0, stream>>>(x_m, b_o2m, nullptr, out_m, N_M * C_M);
    init_out<C_A ><<<(N_A * C_A + 255) / 256, 256, 0, stream>>>(x_a, b_m2a, nullptr, out_a, N_A * C_A);

    const int MT_OP = (N_OP + 127) / 128;
    const int MT_M  = (N_M + 127) / 128;
    const int MT_A  = (N_A + 127) / 128;

    // ---------------- conv 1: pred (op->op, C=256), H = [50000][512] ----------------
    mfma_gemm<<<dim3(MT_OP, 4), 256, 0, stream>>>(xc_op, BtP, biasP, H, N_OP, 256, 512);
    edge_logit<256, false><<<E_OO / 4, 256, 0, stream>>>(H, 512, H + 256, 512, nullptr, att_pred,
                                                         ei_pred, ei_pred + E_OO, ebuf, E_OO);
    csr_agg<256><<<(N_OP + 3) / 4, 256, 0, stream>>>(H, 512, ebuf, ptrP, srcP, eidP, out_op, N_OP);

    // ---------------- conv 2: succ ----------------
    mfma_gemm<<<dim3(MT_OP, 4), 256, 0, stream>>>(xc_op, BtS, biasS, H, N_OP, 256, 512);
    edge_logit<256, false><<<E_OO / 4, 256, 0, stream>>>(H, 512, H + 256, 512, nullptr, att_succ,
                                                         ei_succ, ei_succ + E_OO, ebuf, E_OO);
    csr_agg<256><<<(N_OP + 3) / 4, 256, 0, stream>>>(H, 512, ebuf, ptrS, srcS, eidS, out_op, N_OP);

    // ---------------- conv 3: o2m (op->machine, C=128) ----------------
    {
        unsigned short* xlb = H;                 // [50000][128]
        unsigned short* xrb = H + 6400000;       // [5000][128]
        mfma_gemm<<<dim3(MT_OP, 1), 256, 0, stream>>>(xc_op, BtOL, bl_o2m, xlb, N_OP, 256, 128);
        mfma_gemm<<<dim3(MT_M, 1), 256, 0, stream>>>(xc_m, BtOR, br_o2m, xrb, N_M, 128, 128);
        edge_logit<128, false><<<E_OM / 4, 256, 0, stream>>>(xlb, 128, xrb, 128, nullptr, att_o2m,
                                                             src_o2m, dst_o2m, ebuf, E_OM);
        csr_agg<128><<<(N_M + 3) / 4, 256, 0, stream>>>(xlb, 128, ebuf, ptrO, srcO, eidO, out_m, N_M);
    }

    // ---------------- conv 4: m2a (machine->agv, C=128, edge feats) ----------------
    {
        unsigned short* xlb = H;                 // [5000][128]
        unsigned short* xrb = H + 1000000;       // [2000][128]
        unsigned short* efb = H + 2000000;       // [60000][128]
        mfma_gemm<<<dim3(MT_M, 1), 256, 0, stream>>>(xc_m, BtML, bl_m2a, xlb, N_M, 128, 128);
        mfma_gemm<<<dim3(MT_A, 1), 256, 0, stream>>>(xc_a, BtMR, br_m2a, xrb, N_A, 128, 128);
        gemm_ef<8, 128, 4><<<E_MA / 4, 128, 0, stream>>>(ea_m2a, We_m2a, efb);
        edge_logit<128, true><<<E_MA / 4, 256, 0, stream>>>(xlb, 128, xrb, 128, efb, att_m2a,
                                                            src_m2a, dst_m2a, ebuf, E_MA);
        csr_agg<128><<<(N_A + 3) / 4, 256, 0, stream>>>(xlb, 128, ebuf, ptrA, srcA, eidA, out_a, N_A);
    }
}

// Round 4
// 665.921 us; speedup vs baseline: 3.0168x; 1.2529x over previous
//
#include <hip/hip_runtime.h>

// ---------------------------------------------------------------------------
// Problem constants (fixed by setup_inputs)
// ---------------------------------------------------------------------------
#define N_OP   50000
#define N_M    5000
#define N_A    2000
#define C_OP   256
#define C_M    128
#define C_A    128
#define E_OO   200000
#define E_OM   200000
#define E_MA   60000
#define E_DIM  8

#define OUT_OP_OFF 0
#define OUT_M_OFF  (N_OP * C_OP)
#define OUT_A_OFF  (N_OP * C_OP + N_M * C_M)

typedef short bf16x8 __attribute__((ext_vector_type(8)));
typedef float f32x4 __attribute__((ext_vector_type(4)));
typedef __attribute__((address_space(1))) const unsigned gu32;
typedef __attribute__((address_space(3))) unsigned lu32;

__device__ __forceinline__ unsigned short f2bf(float f) {
    unsigned u = __float_as_uint(f);
    unsigned r = (u + 0x7FFFu + ((u >> 16) & 1u)) >> 16;
    return (unsigned short)r;
}
__device__ __forceinline__ float bf2f(unsigned short h) {
    return __uint_as_float(((unsigned)h) << 16);
}

// ---------------------------------------------------------------------------
// fp32 -> bf16 conversion (vectorized, n % 4 == 0)
// ---------------------------------------------------------------------------
__global__ void cvt_bf16(const float* __restrict__ x, unsigned short* __restrict__ o, int n4) {
    int i = blockIdx.x * blockDim.x + threadIdx.x;
    if (i < n4) {
        float4 v = ((const float4*)x)[i];
        ushort4 r;
        r.x = f2bf(v.x); r.y = f2bf(v.y); r.z = f2bf(v.z); r.w = f2bf(v.w);
        ((ushort4*)o)[i] = r;
    }
}

__global__ void pack_w2(const float* __restrict__ Wl, const float* __restrict__ Wr,
                        int K, int N1, unsigned short* __restrict__ Bt) {
    int idx = blockIdx.x * blockDim.x + threadIdx.x;
    if (idx >= 2 * N1 * K) return;
    int n = idx / K, k = idx - n * K;
    float v = (n < N1) ? Wl[k * N1 + n] : Wr[k * N1 + (n - N1)];
    Bt[idx] = f2bf(v);
}
__global__ void pack_w1(const float* __restrict__ W, int K, int N, unsigned short* __restrict__ Bt) {
    int idx = blockIdx.x * blockDim.x + threadIdx.x;
    if (idx >= N * K) return;
    int n = idx / K, k = idx - n * K;
    Bt[idx] = f2bf(W[k * N + n]);
}
__global__ void pack_bias2(const float* __restrict__ bl, const float* __restrict__ br,
                           int N1, float* __restrict__ bp) {
    int i = blockIdx.x * blockDim.x + threadIdx.x;
    if (i < 2 * N1) bp[i] = (i < N1) ? bl[i] : br[i - N1];
}

// ---------------------------------------------------------------------------
// MFMA bf16 GEMM (m97 structure) — verified rounds 2-3.
// ---------------------------------------------------------------------------
__device__ __forceinline__ void gload_lds16(const void* g, void* l) {
    __builtin_amdgcn_global_load_lds((gu32*)g, (lu32*)l, 16, 0, 0);
}

__global__ __launch_bounds__(256) void mfma_gemm(
    const unsigned short* __restrict__ A, const unsigned short* __restrict__ Bt,
    const float* __restrict__ bias, unsigned short* __restrict__ C,
    int M, int K, int ldc) {
    __shared__ unsigned short As[128 * 64];
    __shared__ unsigned short Bs[128 * 64];

    const int tid  = threadIdx.x;
    const int lane = tid & 63;
    const int wid  = tid >> 6;
    const int m0   = blockIdx.x * 128;
    const int n0   = blockIdx.y * 128;

    f32x4 acc[4][4] = {};

    const int srow = tid >> 3;
    const int scol = (tid & 7) * 8;

    for (int k0 = 0; k0 < K; k0 += 64) {
#pragma unroll
        for (int i = 0; i < 4; ++i) {
            int gr = m0 + i * 32 + srow;
            if (gr >= M) gr = M - 1;
            gload_lds16(A + (size_t)gr * K + k0 + scol, &As[i * 2048 + tid * 8]);
        }
#pragma unroll
        for (int i = 0; i < 4; ++i) {
            int gn = n0 + i * 32 + srow;
            gload_lds16(Bt + (size_t)gn * K + k0 + scol, &Bs[i * 2048 + tid * 8]);
        }
        asm volatile("s_waitcnt vmcnt(0)" ::: "memory");
        __syncthreads();

        const int wr = (wid >> 1) * 64;
        const int wc = (wid & 1) * 64;
#pragma unroll
        for (int kh = 0; kh < 2; ++kh) {
            const int ko = kh * 32 + (lane >> 4) * 8;
            bf16x8 a[4], b[4];
#pragma unroll
            for (int mi = 0; mi < 4; ++mi)
                a[mi] = *(const bf16x8*)&As[(wr + mi * 16 + (lane & 15)) * 64 + ko];
#pragma unroll
            for (int ni = 0; ni < 4; ++ni)
                b[ni] = *(const bf16x8*)&Bs[(wc + ni * 16 + (lane & 15)) * 64 + ko];
#pragma unroll
            for (int mi = 0; mi < 4; ++mi)
#pragma unroll
                for (int ni = 0; ni < 4; ++ni)
                    acc[mi][ni] = __builtin_amdgcn_mfma_f32_16x16x32_bf16(
                        a[mi], b[ni], acc[mi][ni], 0, 0, 0);
        }
        __syncthreads();
    }

    const int wr = (wid >> 1) * 64, wc = (wid & 1) * 64;
    const int crow = (lane >> 4) * 4;
    const int ccol = lane & 15;
#pragma unroll
    for (int ni = 0; ni < 4; ++ni) {
        const int col = n0 + wc + ni * 16 + ccol;
        const float b = bias[col];
#pragma unroll
        for (int mi = 0; mi < 4; ++mi) {
#pragma unroll
            for (int j = 0; j < 4; ++j) {
                const int row = m0 + wr + mi * 16 + crow + j;
                if (row < M) C[(size_t)row * ldc + col] = f2bf(acc[mi][ni][j] + b);
            }
        }
    }
}

// ---------------------------------------------------------------------------
// Small fp32 GEMM for edge features (K=8), bf16 output
// ---------------------------------------------------------------------------
template <int K, int N, int TM>
__global__ void gemm_ef(const float* __restrict__ A, const float* __restrict__ W,
                        unsigned short* __restrict__ out) {
    __shared__ float As[TM][K];
    const int m0 = blockIdx.x * TM;
    const int tid = threadIdx.x;
    for (int idx = tid; idx < TM * K; idx += N) {
        int r = idx / K, k = idx - r * K;
        As[r][k] = A[(m0 + r) * K + k];
    }
    __syncthreads();
    float acc[TM] = {};
    for (int k = 0; k < K; ++k) {
        const float w = W[k * N + tid];
#pragma unroll
        for (int r = 0; r < TM; ++r) acc[r] += As[r][k] * w;
    }
#pragma unroll
    for (int r = 0; r < TM; ++r) out[(m0 + r) * N + tid] = f2bf(acc[r]);
}

// ---------------------------------------------------------------------------
// init_out: out = x + b1 (+ b2)
// ---------------------------------------------------------------------------
template <int C>
__global__ void init_out(const float* __restrict__ x, const float* __restrict__ b1,
                         const float* __restrict__ b2, float* __restrict__ out, int total) {
    int i = blockIdx.x * blockDim.x + threadIdx.x;
    if (i < total) {
        int c = i & (C - 1);
        float v = x[i] + b1[c];
        if (b2) v += b2[c];
        out[i] = v;
    }
}

// ---------------------------------------------------------------------------
// CSR build: zero2 -> histogram -> hierarchical scan (3 kernels) -> scatter
// ---------------------------------------------------------------------------
__global__ void zero2_i32(int* __restrict__ a, int* __restrict__ b, int n) {
    int i = blockIdx.x * blockDim.x + threadIdx.x;
    if (i < n) { a[i] = 0; b[i] = 0; }
}
__global__ void hist_dst(const int* __restrict__ dst, int* __restrict__ cnt, int E) {
    int i = blockIdx.x * blockDim.x + threadIdx.x;
    if (i < E) atomicAdd(&cnt[dst[i]], 1);
}
// phase 1: per-block exclusive scan of 1024 entries + block sum
__global__ void scan_blk(const int* __restrict__ cnt, int* __restrict__ ptr,
                         int* __restrict__ bsum, int n) {
    __shared__ int smem[1024];
    const int tid = threadIdx.x;
    const int i = blockIdx.x * 1024 + tid;
    const int v = (i < n) ? cnt[i] : 0;
    smem[tid] = v;
    __syncthreads();
    for (int o = 1; o < 1024; o <<= 1) {
        int t = (tid >= o) ? smem[tid - o] : 0;
        __syncthreads();
        smem[tid] += t;
        __syncthreads();
    }
    if (i < n) ptr[i] = smem[tid] - v;       // block-local exclusive
    if (tid == 1023) bsum[blockIdx.x] = smem[1023];
}
// phase 2: scan the (<=1024) block sums; write total to ptr[n]
__global__ void scan_tops(const int* __restrict__ bsum, int* __restrict__ boff,
                          int* __restrict__ ptr_n, int nb) {
    __shared__ int smem[1024];
    const int tid = threadIdx.x;
    const int v = (tid < nb) ? bsum[tid] : 0;
    smem[tid] = v;
    __syncthreads();
    for (int o = 1; o < 1024; o <<= 1) {
        int t = (tid >= o) ? smem[tid - o] : 0;
        __syncthreads();
        smem[tid] += t;
        __syncthreads();
    }
    if (tid < nb) boff[tid] = smem[tid] - v;
    if (tid == 1023) *ptr_n = smem[1023];
}
// phase 3: add block offsets
__global__ void scan_add(int* __restrict__ ptr, const int* __restrict__ boff, int n) {
    int i = blockIdx.x * blockDim.x + threadIdx.x;
    if (i < n) ptr[i] += boff[i >> 10];
}
__global__ void scatter_e(const int* __restrict__ src, const int* __restrict__ dst,
                          const int* __restrict__ ptr, int* __restrict__ cur,
                          int* __restrict__ srcs, int* __restrict__ eidx, int E) {
    int i = blockIdx.x * blockDim.x + threadIdx.x;
    if (i >= E) return;
    const int d = dst[i];
    const int pos = ptr[d] + atomicAdd(&cur[d], 1);
    srcs[pos] = src[i];
    eidx[pos] = i;
}

// ---------------------------------------------------------------------------
// Edge logit: e = leaky_relu(xl[src]+xr[dst](+ef)) . att  (1 wave / edge)
// ---------------------------------------------------------------------------
template <int C, bool HAS_EF>
__global__ void edge_logit(const unsigned short* __restrict__ xl, int ldl,
                           const unsigned short* __restrict__ xr, int ldr,
                           const unsigned short* __restrict__ ef,
                           const float* __restrict__ att,
                           const int* __restrict__ src, const int* __restrict__ dst,
                           float* __restrict__ e_out, int E) {
    const int edge = blockIdx.x * (blockDim.x >> 6) + (threadIdx.x >> 6);
    if (edge >= E) return;
    const int lane = threadIdx.x & 63;
    const int s = src[edge], d = dst[edge];
    constexpr int V = C / 64;
    const int c0 = lane * V;

    unsigned short lv[V], rv[V], ev[V];
    const unsigned short* pl = xl + (size_t)s * ldl + c0;
    const unsigned short* pr = xr + (size_t)d * ldr + c0;
    if constexpr (V == 4) {
        *(uint2*)lv = *(const uint2*)pl;
        *(uint2*)rv = *(const uint2*)pr;
        if (HAS_EF) *(uint2*)ev = *(const uint2*)(ef + (size_t)edge * C + c0);
    } else {
        *(unsigned*)lv = *(const unsigned*)pl;
        *(unsigned*)rv = *(const unsigned*)pr;
        if (HAS_EF) *(unsigned*)ev = *(const unsigned*)(ef + (size_t)edge * C + c0);
    }

    float acc = 0.0f;
#pragma unroll
    for (int v = 0; v < V; ++v) {
        float m = bf2f(lv[v]) + bf2f(rv[v]);
        if (HAS_EF) m += bf2f(ev[v]);
        m = (m >= 0.0f) ? m : 0.2f * m;
        acc += m * att[c0 + v];
    }
#pragma unroll
    for (int o = 32; o > 0; o >>= 1) acc += __shfl_xor(acc, o, 64);

    if (lane == 0) e_out[edge] = acc;
}

// ---------------------------------------------------------------------------
// Fused softmax + aggregate over CSR: one wave per dst node, zero atomics.
// ---------------------------------------------------------------------------
template <int C>
__global__ void csr_agg(const unsigned short* __restrict__ xl, int ldl,
                        const float* __restrict__ e,
                        const int* __restrict__ ptr, const int* __restrict__ srcs,
                        const int* __restrict__ eidx,
                        float* __restrict__ out, int n) {
    const int node = blockIdx.x * (blockDim.x >> 6) + (threadIdx.x >> 6);
    if (node >= n) return;
    const int lane = threadIdx.x & 63;
    const int beg = ptr[node], end = ptr[node + 1];
    if (beg == end) return;

    float m = -3.0e38f;
    for (int j = beg + lane; j < end; j += 64) m = fmaxf(m, e[eidx[j]]);
#pragma unroll
    for (int o = 32; o > 0; o >>= 1) m = fmaxf(m, __shfl_xor(m, o, 64));

    float s = 0.0f;
    for (int j = beg + lane; j < end; j += 64) s += __expf(e[eidx[j]] - m);
#pragma unroll
    for (int o = 32; o > 0; o >>= 1) s += __shfl_xor(s, o, 64);
    const float inv = 1.0f / fmaxf(s, 1e-16f);

    constexpr int V = C / 64;
    float acc[V] = {};
    for (int j = beg; j < end; ++j) {
        const float w = __expf(e[eidx[j]] - m) * inv;
        const unsigned short* row = xl + (size_t)srcs[j] * ldl + lane * V;
        unsigned short lv[V];
        if constexpr (V == 4) *(uint2*)lv = *(const uint2*)row;
        else                  *(unsigned*)lv = *(const unsigned*)row;
#pragma unroll
        for (int v = 0; v < V; ++v) acc[v] += w * bf2f(lv[v]);
    }
    float* po = out + (size_t)node * C + lane * V;
#pragma unroll
    for (int v = 0; v < V; ++v) po[v] += acc[v];
}

// ---------------------------------------------------------------------------
// Workspace layout (float/int slots).  Total ~86.3 MB (ws proven >= 103.6 MB).
// ---------------------------------------------------------------------------
#define F_H      0
#define F_XCOP   12800000
#define F_XCM    19200000
#define F_XCA    19520000
#define F_BTP    19648000
#define F_BTS    19713536
#define F_BTOL   19779072
#define F_BTOR   19795456
#define F_BTML   19803648
#define F_BTMR   19811840
#define F_BIASP  19820032
#define F_BIASS  19820544
#define F_EBUF   19821056
#define F_CNT    20030000    // int[50,000]
#define F_PTR_P  20080008    // int[50,001]
#define F_SRC_P  20130016
#define F_EID_P  20330016
#define F_PTR_S  20530016
#define F_SRC_S  20580024
#define F_EID_S  20780024
#define F_PTR_O  20980024
#define F_SRC_O  20985032
#define F_EID_O  21185032
#define F_PTR_A  21385032
#define F_SRC_A  21387040
#define F_EID_A  21447040    // int[60,000] -> ends 21,507,040
#define F_CUR    21507040    // int[50,000]
#define F_BSUM   21557040    // int[1,024]
#define F_BOFF   21558064    // int[1,024]  -> ends 21,559,088 (~86.3 MB)

static void build_csr(const int* src, const int* dst, int E, int n,
                      int* cnt, int* cur, int* bsum, int* boff,
                      int* ptr, int* srcs, int* eidx, hipStream_t stream) {
    const int nb = (n + 1023) / 1024;
    zero2_i32<<<(n + 255) / 256, 256, 0, stream>>>(cnt, cur, n);
    hist_dst<<<(E + 255) / 256, 256, 0, stream>>>(dst, cnt, E);
    scan_blk<<<nb, 1024, 0, stream>>>(cnt, ptr, bsum, n);
    scan_tops<<<1, 1024, 0, stream>>>(bsum, boff, ptr + n, nb);
    scan_add<<<(n + 255) / 256, 256, 0, stream>>>(ptr, boff, n);
    scatter_e<<<(E + 255) / 256, 256, 0, stream>>>(src, dst, ptr, cur, srcs, eidx, E);
}

extern "C" void kernel_launch(void* const* d_in, const int* in_sizes, int n_in,
                              void* d_out, int out_size, void* d_ws, size_t ws_size,
                              hipStream_t stream) {
    const float* x_op    = (const float*)d_in[0];
    const float* x_m     = (const float*)d_in[1];
    const float* x_a     = (const float*)d_in[2];
    const int*   ei_pred = (const int*)d_in[3];
    const int*   ei_succ = (const int*)d_in[4];
    const int*   src_o2m = (const int*)d_in[5];
    const int*   dst_o2m = (const int*)d_in[6];
    const int*   src_m2a = (const int*)d_in[7];
    const int*   dst_m2a = (const int*)d_in[8];
    const float* ea_m2a  = (const float*)d_in[9];

    const float* Wl_pred = (const float*)d_in[10];
    const float* bl_pred = (const float*)d_in[11];
    const float* Wr_pred = (const float*)d_in[12];
    const float* br_pred = (const float*)d_in[13];
    const float* att_pred= (const float*)d_in[14];
    const float* b_pred  = (const float*)d_in[15];

    const float* Wl_succ = (const float*)d_in[16];
    const float* bl_succ = (const float*)d_in[17];
    const float* Wr_succ = (const float*)d_in[18];
    const float* br_succ = (const float*)d_in[19];
    const float* att_succ= (const float*)d_in[20];
    const float* b_succ  = (const float*)d_in[21];

    const float* Wl_o2m  = (const float*)d_in[22];
    const float* bl_o2m  = (const float*)d_in[23];
    const float* Wr_o2m  = (const float*)d_in[24];
    const float* br_o2m  = (const float*)d_in[25];
    const float* att_o2m = (const float*)d_in[26];
    const float* b_o2m   = (const float*)d_in[27];

    const float* Wl_m2a  = (const float*)d_in[28];
    const float* bl_m2a  = (const float*)d_in[29];
    const float* Wr_m2a  = (const float*)d_in[30];
    const float* br_m2a  = (const float*)d_in[31];
    const float* att_m2a = (const float*)d_in[32];
    const float* b_m2a   = (const float*)d_in[33];
    const float* We_m2a  = (const float*)d_in[34];

    float* ws = (float*)d_ws;
    unsigned short* H     = (unsigned short*)(ws + F_H);
    unsigned short* xc_op = (unsigned short*)(ws + F_XCOP);
    unsigned short* xc_m  = (unsigned short*)(ws + F_XCM);
    unsigned short* xc_a  = (unsigned short*)(ws + F_XCA);
    unsigned short* BtP   = (unsigned short*)(ws + F_BTP);
    unsigned short* BtS   = (unsigned short*)(ws + F_BTS);
    unsigned short* BtOL  = (unsigned short*)(ws + F_BTOL);
    unsigned short* BtOR  = (unsigned short*)(ws + F_BTOR);
    unsigned short* BtML  = (unsigned short*)(ws + F_BTML);
    unsigned short* BtMR  = (unsigned short*)(ws + F_BTMR);
    float* biasP = ws + F_BIASP;
    float* biasS = ws + F_BIASS;
    float* ebuf  = ws + F_EBUF;
    int* cnt  = (int*)(ws + F_CNT);
    int* cur  = (int*)(ws + F_CUR);
    int* bsum = (int*)(ws + F_BSUM);
    int* boff = (int*)(ws + F_BOFF);
    int* ptrP = (int*)(ws + F_PTR_P); int* srcP = (int*)(ws + F_SRC_P); int* eidP = (int*)(ws + F_EID_P);
    int* ptrS = (int*)(ws + F_PTR_S); int* srcS = (int*)(ws + F_SRC_S); int* eidS = (int*)(ws + F_EID_S);
    int* ptrO = (int*)(ws + F_PTR_O); int* srcO = (int*)(ws + F_SRC_O); int* eidO = (int*)(ws + F_EID_O);
    int* ptrA = (int*)(ws + F_PTR_A); int* srcA = (int*)(ws + F_SRC_A); int* eidA = (int*)(ws + F_EID_A);

    float* out_op = (float*)d_out + OUT_OP_OFF;
    float* out_m  = (float*)d_out + OUT_M_OFF;
    float* out_a  = (float*)d_out + OUT_A_OFF;

    // ---- CSR builds ----
    build_csr(ei_pred, ei_pred + E_OO, E_OO, N_OP, cnt, cur, bsum, boff, ptrP, srcP, eidP, stream);
    build_csr(ei_succ, ei_succ + E_OO, E_OO, N_OP, cnt, cur, bsum, boff, ptrS, srcS, eidS, stream);
    build_csr(src_o2m, dst_o2m, E_OM, N_M, cnt, cur, bsum, boff, ptrO, srcO, eidO, stream);
    build_csr(src_m2a, dst_m2a, E_MA, N_A, cnt, cur, bsum, boff, ptrA, srcA, eidA, stream);

    // ---- conversions & weight packing ----
    cvt_bf16<<<(N_OP * C_OP / 4 + 255) / 256, 256, 0, stream>>>(x_op, xc_op, N_OP * C_OP / 4);
    cvt_bf16<<<(N_M * C_M / 4 + 255) / 256, 256, 0, stream>>>(x_m, xc_m, N_M * C_M / 4);
    cvt_bf16<<<(N_A * C_A / 4 + 255) / 256, 256, 0, stream>>>(x_a, xc_a, N_A * C_A / 4);
    pack_w2<<<(2 * 256 * 256 + 255) / 256, 256, 0, stream>>>(Wl_pred, Wr_pred, 256, 256, BtP);
    pack_w2<<<(2 * 256 * 256 + 255) / 256, 256, 0, stream>>>(Wl_succ, Wr_succ, 256, 256, BtS);
    pack_w1<<<(128 * 256 + 255) / 256, 256, 0, stream>>>(Wl_o2m, 256, 128, BtOL);
    pack_w1<<<(128 * 128 + 255) / 256, 256, 0, stream>>>(Wr_o2m, 128, 128, BtOR);
    pack_w1<<<(128 * 128 + 255) / 256, 256, 0, stream>>>(Wl_m2a, 128, 128, BtML);
    pack_w1<<<(128 * 128 + 255) / 256, 256, 0, stream>>>(Wr_m2a, 128, 128, BtMR);
    pack_bias2<<<2, 256, 0, stream>>>(bl_pred, br_pred, 256, biasP);
    pack_bias2<<<2, 256, 0, stream>>>(bl_succ, br_succ, 256, biasS);

    // ---- output init: residual + conv biases ----
    init_out<C_OP><<<(N_OP * C_OP + 255) / 256, 256, 0, stream>>>(x_op, b_pred, b_succ, out_op, N_OP * C_OP);
    init_out<C_M ><<<(N_M * C_M + 255) / 256, 256, 0, stream>>>(x_m, b_o2m, nullptr, out_m, N_M * C_M);
    init_out<C_A ><<<(N_A * C_A + 255) / 256, 256, 0, stream>>>(x_a, b_m2a, nullptr, out_a, N_A * C_A);

    const int MT_OP = (N_OP + 127) / 128;
    const int MT_M  = (N_M + 127) / 128;
    const int MT_A  = (N_A + 127) / 128;

    // ---------------- conv 1: pred (op->op, C=256), H = [50000][512] ----------------
    mfma_gemm<<<dim3(MT_OP, 4), 256, 0, stream>>>(xc_op, BtP, biasP, H, N_OP, 256, 512);
    edge_logit<256, false><<<E_OO / 4, 256, 0, stream>>>(H, 512, H + 256, 512, nullptr, att_pred,
                                                         ei_pred, ei_pred + E_OO, ebuf, E_OO);
    csr_agg<256><<<(N_OP + 3) / 4, 256, 0, stream>>>(H, 512, ebuf, ptrP, srcP, eidP, out_op, N_OP);

    // ---------------- conv 2: succ ----------------
    mfma_gemm<<<dim3(MT_OP, 4), 256, 0, stream>>>(xc_op, BtS, biasS, H, N_OP, 256, 512);
    edge_logit<256, false><<<E_OO / 4, 256, 0, stream>>>(H, 512, H + 256, 512, nullptr, att_succ,
                                                         ei_succ, ei_succ + E_OO, ebuf, E_OO);
    csr_agg<256><<<(N_OP + 3) / 4, 256, 0, stream>>>(H, 512, ebuf, ptrS, srcS, eidS, out_op, N_OP);

    // ---------------- conv 3: o2m (op->machine, C=128) ----------------
    {
        unsigned short* xlb = H;                 // [50000][128]
        unsigned short* xrb = H + 6400000;       // [5000][128]
        mfma_gemm<<<dim3(MT_OP, 1), 256, 0, stream>>>(xc_op, BtOL, bl_o2m, xlb, N_OP, 256, 128);
        mfma_gemm<<<dim3(MT_M, 1), 256, 0, stream>>>(xc_m, BtOR, br_o2m, xrb, N_M, 128, 128);
        edge_logit<128, false><<<E_OM / 4, 256, 0, stream>>>(xlb, 128, xrb, 128, nullptr, att_o2m,
                                                             src_o2m, dst_o2m, ebuf, E_OM);
        csr_agg<128><<<(N_M + 3) / 4, 256, 0, stream>>>(xlb, 128, ebuf, ptrO, srcO, eidO, out_m, N_M);
    }

    // ---------------- conv 4: m2a (machine->agv, C=128, edge feats) ----------------
    {
        unsigned short* xlb = H;                 // [5000][128]
        unsigned short* xrb = H + 1000000;       // [2000][128]
        unsigned short* efb = H + 2000000;       // [60000][128]
        mfma_gemm<<<dim3(MT_M, 1), 256, 0, stream>>>(xc_m, BtML, bl_m2a, xlb, N_M, 128, 128);
        mfma_gemm<<<dim3(MT_A, 1), 256, 0, stream>>>(xc_a, BtMR, br_m2a, xrb, N_A, 128, 128);
        gemm_ef<8, 128, 4><<<E_MA / 4, 128, 0, stream>>>(ea_m2a, We_m2a, efb);
        edge_logit<128, true><<<E_MA / 4, 256, 0, stream>>>(xlb, 128, xrb, 128, efb, att_m2a,
                                                            src_m2a, dst_m2a, ebuf, E_MA);
        csr_agg<128><<<(N_A + 3) / 4, 256, 0, stream>>>(xlb, 128, ebuf, ptrA, srcA, eidA, out_a, N_A);
    }
}

// Round 5
// 555.635 us; speedup vs baseline: 3.6156x; 1.1985x over previous
//
#include <hip/hip_runtime.h>

// ---------------------------------------------------------------------------
// Problem constants (fixed by setup_inputs)
// ---------------------------------------------------------------------------
#define N_OP   50000
#define N_M    5000
#define N_A    2000
#define C_OP   256
#define C_M    128
#define C_A    128
#define E_OO   200000
#define E_OM   200000
#define E_MA   60000
#define E_DIM  8

#define OUT_OP_OFF 0
#define OUT_M_OFF  (N_OP * C_OP)
#define OUT_A_OFF  (N_OP * C_OP + N_M * C_M)

typedef short bf16x8 __attribute__((ext_vector_type(8)));
typedef float f32x4 __attribute__((ext_vector_type(4)));
typedef __attribute__((address_space(1))) const unsigned gu32;
typedef __attribute__((address_space(3))) unsigned lu32;

__device__ __forceinline__ unsigned short f2bf(float f) {
    unsigned u = __float_as_uint(f);
    unsigned r = (u + 0x7FFFu + ((u >> 16) & 1u)) >> 16;
    return (unsigned short)r;
}
__device__ __forceinline__ float bf2f(unsigned short h) {
    return __uint_as_float(((unsigned)h) << 16);
}

// ---------------------------------------------------------------------------
// Fused residual-init + bf16 conversion: out = x + b1 (+b2), xc = bf16(x)
// ---------------------------------------------------------------------------
template <int C>
__global__ void init_cvt(const float* __restrict__ x, const float* __restrict__ b1,
                         const float* __restrict__ b2, float* __restrict__ out,
                         unsigned short* __restrict__ xc, int total4) {
    int i = blockIdx.x * blockDim.x + threadIdx.x;
    if (i >= total4) return;
    float4 v = ((const float4*)x)[i];
    const int cb = i & (C / 4 - 1);
    float4 b = ((const float4*)b1)[cb];
    if (b2) {
        float4 b2v = ((const float4*)b2)[cb];
        b.x += b2v.x; b.y += b2v.y; b.z += b2v.z; b.w += b2v.w;
    }
    float4 o;
    o.x = v.x + b.x; o.y = v.y + b.y; o.z = v.z + b.z; o.w = v.w + b.w;
    ((float4*)out)[i] = o;
    ushort4 r;
    r.x = f2bf(v.x); r.y = f2bf(v.y); r.z = f2bf(v.z); r.w = f2bf(v.w);
    ((ushort4*)xc)[i] = r;
}

__global__ void pack_w2(const float* __restrict__ Wl, const float* __restrict__ Wr,
                        int K, int N1, unsigned short* __restrict__ Bt) {
    int idx = blockIdx.x * blockDim.x + threadIdx.x;
    if (idx >= 2 * N1 * K) return;
    int n = idx / K, k = idx - n * K;
    float v = (n < N1) ? Wl[k * N1 + n] : Wr[k * N1 + (n - N1)];
    Bt[idx] = f2bf(v);
}
__global__ void pack_w1(const float* __restrict__ W, int K, int N, unsigned short* __restrict__ Bt) {
    int idx = blockIdx.x * blockDim.x + threadIdx.x;
    if (idx >= N * K) return;
    int n = idx / K, k = idx - n * K;
    Bt[idx] = f2bf(W[k * N + n]);
}
__global__ void pack_bias2(const float* __restrict__ bl, const float* __restrict__ br,
                           int N1, float* __restrict__ bp) {
    int i = blockIdx.x * blockDim.x + threadIdx.x;
    if (i < 2 * N1) bp[i] = (i < N1) ? bl[i] : br[i - N1];
}

// ---------------------------------------------------------------------------
// MFMA bf16 GEMM: 128x128 tile, BK=64, double-buffered LDS with 2-phase
// pipeline (stage next tile before compute, one vmcnt(0)+barrier per step),
// XOR-swizzled LDS (pre-swizzled global source + swizzled ds_read -> no bank
// conflicts on the 128B-stride b128 reads).
// ---------------------------------------------------------------------------
__device__ __forceinline__ void gload_lds16(const void* g, void* l) {
    __builtin_amdgcn_global_load_lds((gu32*)g, (lu32*)l, 16, 0, 0);
}

__global__ __launch_bounds__(256) void mfma_gemm(
    const unsigned short* __restrict__ A, const unsigned short* __restrict__ Bt,
    const float* __restrict__ bias, unsigned short* __restrict__ C,
    int M, int K, int ldc) {
    __shared__ unsigned short As[2][128 * 64];
    __shared__ unsigned short Bs[2][128 * 64];

    const int tid  = threadIdx.x;
    const int lane = tid & 63;
    const int wid  = tid >> 6;
    const int m0   = blockIdx.x * 128;
    const int n0   = blockIdx.y * 128;

    f32x4 acc[4][4] = {};

    const int srow   = tid >> 3;                       // 0..31 (row within 32-chunk)
    const int scolb  = (tid & 7) * 16;                 // linear byte col in LDS row
    const int scole  = (scolb ^ ((srow & 7) << 4)) >> 1; // swizzled global elem col

    int grA[4], grB[4];
#pragma unroll
    for (int i = 0; i < 4; ++i) {
        int gr = m0 + i * 32 + srow;
        grA[i] = (gr < M) ? gr : M - 1;
        grB[i] = n0 + i * 32 + srow;
    }

    const int nt = K >> 6;
    int cur = 0;

#define STAGE(buf, k0)                                                          \
    {                                                                           \
        _Pragma("unroll")                                                       \
        for (int i = 0; i < 4; ++i)                                             \
            gload_lds16(A + (size_t)grA[i] * K + (k0) + scole,                  \
                        &As[buf][i * 2048 + tid * 8]);                          \
        _Pragma("unroll")                                                       \
        for (int i = 0; i < 4; ++i)                                             \
            gload_lds16(Bt + (size_t)grB[i] * K + (k0) + scole,                 \
                        &Bs[buf][i * 2048 + tid * 8]);                          \
    }

    STAGE(0, 0)
    asm volatile("s_waitcnt vmcnt(0)" ::: "memory");
    __syncthreads();

    const int wr = (wid >> 1) * 64;
    const int wc = (wid & 1) * 64;

    for (int t = 0; t < nt; ++t) {
        if (t + 1 < nt) STAGE(cur ^ 1, (t + 1) * 64)
#pragma unroll
        for (int kh = 0; kh < 2; ++kh) {
            const int kob = kh * 64 + (lane >> 4) * 16;   // byte col within row
            bf16x8 a[4], b[4];
#pragma unroll
            for (int mi = 0; mi < 4; ++mi) {
                const int row = wr + mi * 16 + (lane & 15);
                a[mi] = *(const bf16x8*)((const char*)As[cur] + row * 128 +
                                         (kob ^ ((row & 7) << 4)));
            }
#pragma unroll
            for (int ni = 0; ni < 4; ++ni) {
                const int row = wc + ni * 16 + (lane & 15);
                b[ni] = *(const bf16x8*)((const char*)Bs[cur] + row * 128 +
                                         (kob ^ ((row & 7) << 4)));
            }
#pragma unroll
            for (int mi = 0; mi < 4; ++mi)
#pragma unroll
                for (int ni = 0; ni < 4; ++ni)
                    acc[mi][ni] = __builtin_amdgcn_mfma_f32_16x16x32_bf16(
                        a[mi], b[ni], acc[mi][ni], 0, 0, 0);
        }
        asm volatile("s_waitcnt vmcnt(0)" ::: "memory");
        __syncthreads();
        cur ^= 1;
    }
#undef STAGE

    // epilogue: row-outer, ni-inner so 4 stores cover a contiguous 128B span
    const int crow = (lane >> 4) * 4;
    const int ccol = lane & 15;
    float bcol[4];
#pragma unroll
    for (int ni = 0; ni < 4; ++ni) bcol[ni] = bias[n0 + wc + ni * 16 + ccol];
#pragma unroll
    for (int mi = 0; mi < 4; ++mi) {
#pragma unroll
        for (int j = 0; j < 4; ++j) {
            const int row = m0 + wr + mi * 16 + crow + j;
            if (row < M) {
                unsigned short* pc = C + (size_t)row * ldc + n0 + wc + ccol;
#pragma unroll
                for (int ni = 0; ni < 4; ++ni)
                    pc[ni * 16] = f2bf(acc[mi][ni][j] + bcol[ni]);
            }
        }
    }
}

// ---------------------------------------------------------------------------
// Small fp32 GEMM for edge features (K=8), rows permuted by eid (CSR order),
// bf16 output indexed by CSR slot.
// ---------------------------------------------------------------------------
template <int K, int N, int TM>
__global__ void gemm_ef(const float* __restrict__ A, const float* __restrict__ W,
                        const int* __restrict__ eid, unsigned short* __restrict__ out) {
    __shared__ float As[TM][K];
    const int m0 = blockIdx.x * TM;
    const int tid = threadIdx.x;
    for (int idx = tid; idx < TM * K; idx += N) {
        int r = idx / K, k = idx - r * K;
        As[r][k] = A[(size_t)eid[m0 + r] * K + k];
    }
    __syncthreads();
    float acc[TM] = {};
    for (int k = 0; k < K; ++k) {
        const float w = W[k * N + tid];
#pragma unroll
        for (int r = 0; r < TM; ++r) acc[r] += As[r][k] * w;
    }
#pragma unroll
    for (int r = 0; r < TM; ++r) out[(size_t)(m0 + r) * N + tid] = f2bf(acc[r]);
}

// ---------------------------------------------------------------------------
// CSR build: zero2 -> histogram -> hierarchical scan -> scatter (src,dst,eid)
// ---------------------------------------------------------------------------
__global__ void zero2_i32(int* __restrict__ a, int* __restrict__ b, int n) {
    int i = blockIdx.x * blockDim.x + threadIdx.x;
    if (i < n) { a[i] = 0; b[i] = 0; }
}
__global__ void hist_dst(const int* __restrict__ dst, int* __restrict__ cnt, int E) {
    int i = blockIdx.x * blockDim.x + threadIdx.x;
    if (i < E) atomicAdd(&cnt[dst[i]], 1);
}
__global__ void scan_blk(const int* __restrict__ cnt, int* __restrict__ ptr,
                         int* __restrict__ bsum, int n) {
    __shared__ int smem[1024];
    const int tid = threadIdx.x;
    const int i = blockIdx.x * 1024 + tid;
    const int v = (i < n) ? cnt[i] : 0;
    smem[tid] = v;
    __syncthreads();
    for (int o = 1; o < 1024; o <<= 1) {
        int t = (tid >= o) ? smem[tid - o] : 0;
        __syncthreads();
        smem[tid] += t;
        __syncthreads();
    }
    if (i < n) ptr[i] = smem[tid] - v;
    if (tid == 1023) bsum[blockIdx.x] = smem[1023];
}
__global__ void scan_tops(const int* __restrict__ bsum, int* __restrict__ boff,
                          int* __restrict__ ptr_n, int nb) {
    __shared__ int smem[1024];
    const int tid = threadIdx.x;
    const int v = (tid < nb) ? bsum[tid] : 0;
    smem[tid] = v;
    __syncthreads();
    for (int o = 1; o < 1024; o <<= 1) {
        int t = (tid >= o) ? smem[tid - o] : 0;
        __syncthreads();
        smem[tid] += t;
        __syncthreads();
    }
    if (tid < nb) boff[tid] = smem[tid] - v;
    if (tid == 1023) *ptr_n = smem[1023];
}
__global__ void scan_add(int* __restrict__ ptr, const int* __restrict__ boff, int n) {
    int i = blockIdx.x * blockDim.x + threadIdx.x;
    if (i < n) ptr[i] += boff[i >> 10];
}
__global__ void scatter_e(const int* __restrict__ src, const int* __restrict__ dst,
                          const int* __restrict__ ptr, int* __restrict__ cur,
                          int* __restrict__ srcs, int* __restrict__ dsts,
                          int* __restrict__ eidx, int E) {
    int i = blockIdx.x * blockDim.x + threadIdx.x;
    if (i >= E) return;
    const int d = dst[i];
    const int pos = ptr[d] + atomicAdd(&cur[d], 1);
    srcs[pos] = src[i];
    dsts[pos] = d;
    eidx[pos] = i;
}

// ---------------------------------------------------------------------------
// Edge logit over CSR-ordered slots: e[slot] = leaky(xl[srcs]+xr[dsts](+ef)).att
// Consecutive slots share dst -> xr row reads are cache-hot.
// ---------------------------------------------------------------------------
template <int C, bool HAS_EF>
__global__ void edge_logit(const unsigned short* __restrict__ xl, int ldl,
                           const unsigned short* __restrict__ xr, int ldr,
                           const unsigned short* __restrict__ ef,
                           const float* __restrict__ att,
                           const int* __restrict__ srcs, const int* __restrict__ dsts,
                           float* __restrict__ e_out, int E) {
    const int slot = blockIdx.x * (blockDim.x >> 6) + (threadIdx.x >> 6);
    if (slot >= E) return;
    const int lane = threadIdx.x & 63;
    const int s = srcs[slot], d = dsts[slot];
    constexpr int V = C / 64;
    const int c0 = lane * V;

    unsigned short lv[V], rv[V], ev[V];
    const unsigned short* pl = xl + (size_t)s * ldl + c0;
    const unsigned short* pr = xr + (size_t)d * ldr + c0;
    if constexpr (V == 4) {
        *(uint2*)lv = *(const uint2*)pl;
        *(uint2*)rv = *(const uint2*)pr;
        if (HAS_EF) *(uint2*)ev = *(const uint2*)(ef + (size_t)slot * C + c0);
    } else {
        *(unsigned*)lv = *(const unsigned*)pl;
        *(unsigned*)rv = *(const unsigned*)pr;
        if (HAS_EF) *(unsigned*)ev = *(const unsigned*)(ef + (size_t)slot * C + c0);
    }

    float acc = 0.0f;
#pragma unroll
    for (int v = 0; v < V; ++v) {
        float m = bf2f(lv[v]) + bf2f(rv[v]);
        if (HAS_EF) m += bf2f(ev[v]);
        m = (m >= 0.0f) ? m : 0.2f * m;
        acc += m * att[c0 + v];
    }
#pragma unroll
    for (int o = 32; o > 0; o >>= 1) acc += __shfl_xor(acc, o, 64);

    if (lane == 0) e_out[slot] = acc;
}

// ---------------------------------------------------------------------------
// Fused softmax + aggregate over CSR (e already CSR-ordered): one wave/node.
// ---------------------------------------------------------------------------
template <int C>
__global__ void csr_agg(const unsigned short* __restrict__ xl, int ldl,
                        const float* __restrict__ e,
                        const int* __restrict__ ptr, const int* __restrict__ srcs,
                        float* __restrict__ out, int n) {
    const int node = blockIdx.x * (blockDim.x >> 6) + (threadIdx.x >> 6);
    if (node >= n) return;
    const int lane = threadIdx.x & 63;
    const int beg = ptr[node], end = ptr[node + 1];
    if (beg == end) return;

    float m = -3.0e38f;
    for (int j = beg + lane; j < end; j += 64) m = fmaxf(m, e[j]);
#pragma unroll
    for (int o = 32; o > 0; o >>= 1) m = fmaxf(m, __shfl_xor(m, o, 64));

    float s = 0.0f;
    for (int j = beg + lane; j < end; j += 64) s += __expf(e[j] - m);
#pragma unroll
    for (int o = 32; o > 0; o >>= 1) s += __shfl_xor(s, o, 64);
    const float inv = 1.0f / fmaxf(s, 1e-16f);

    constexpr int V = C / 64;
    float acc[V] = {};
    for (int j = beg; j < end; ++j) {
        const float w = __expf(e[j] - m) * inv;
        const unsigned short* row = xl + (size_t)srcs[j] * ldl + lane * V;
        unsigned short lv[V];
        if constexpr (V == 4) *(uint2*)lv = *(const uint2*)row;
        else                  *(unsigned*)lv = *(const unsigned*)row;
#pragma unroll
        for (int v = 0; v < V; ++v) acc[v] += w * bf2f(lv[v]);
    }
    float* po = out + (size_t)node * C + lane * V;
#pragma unroll
    for (int v = 0; v < V; ++v) po[v] += acc[v];
}

// ---------------------------------------------------------------------------
// Workspace layout (float slots).  Ends ~88.9 MB (ws >= 103.6 MB proven).
// ---------------------------------------------------------------------------
#define F_H      0
#define F_XCOP   12800000
#define F_XCM    19200000
#define F_XCA    19520000
#define F_BTP    19648000
#define F_BTS    19713536
#define F_BTOL   19779072
#define F_BTOR   19795456
#define F_BTML   19803648
#define F_BTMR   19811840
#define F_BIASP  19820032
#define F_BIASS  19820544
#define F_EBUF   19821056
#define F_CNT    20030000
#define F_PTR_P  20080008
#define F_SRC_P  20130016
#define F_EID_P  20330016
#define F_PTR_S  20530016
#define F_SRC_S  20580024
#define F_EID_S  20780024
#define F_PTR_O  20980024
#define F_SRC_O  20985032
#define F_EID_O  21185032
#define F_PTR_A  21385032
#define F_SRC_A  21387040
#define F_EID_A  21447040
#define F_CUR    21507040
#define F_BSUM   21557040
#define F_BOFF   21558064
#define F_DST_P  21559088
#define F_DST_S  21759088
#define F_DST_O  21959088
#define F_DST_A  22159088    // ends 22,219,088 floats = 88.9 MB

static void build_csr(const int* src, const int* dst, int E, int n,
                      int* cnt, int* cur, int* bsum, int* boff,
                      int* ptr, int* srcs, int* dsts, int* eidx, hipStream_t stream) {
    const int nb = (n + 1023) / 1024;
    zero2_i32<<<(n + 255) / 256, 256, 0, stream>>>(cnt, cur, n);
    hist_dst<<<(E + 255) / 256, 256, 0, stream>>>(dst, cnt, E);
    scan_blk<<<nb, 1024, 0, stream>>>(cnt, ptr, bsum, n);
    scan_tops<<<1, 1024, 0, stream>>>(bsum, boff, ptr + n, nb);
    scan_add<<<(n + 255) / 256, 256, 0, stream>>>(ptr, boff, n);
    scatter_e<<<(E + 255) / 256, 256, 0, stream>>>(src, dst, ptr, cur, srcs, dsts, eidx, E);
}

extern "C" void kernel_launch(void* const* d_in, const int* in_sizes, int n_in,
                              void* d_out, int out_size, void* d_ws, size_t ws_size,
                              hipStream_t stream) {
    const float* x_op    = (const float*)d_in[0];
    const float* x_m     = (const float*)d_in[1];
    const float* x_a     = (const float*)d_in[2];
    const int*   ei_pred = (const int*)d_in[3];
    const int*   ei_succ = (const int*)d_in[4];
    const int*   src_o2m = (const int*)d_in[5];
    const int*   dst_o2m = (const int*)d_in[6];
    const int*   src_m2a = (const int*)d_in[7];
    const int*   dst_m2a = (const int*)d_in[8];
    const float* ea_m2a  = (const float*)d_in[9];

    const float* Wl_pred = (const float*)d_in[10];
    const float* bl_pred = (const float*)d_in[11];
    const float* Wr_pred = (const float*)d_in[12];
    const float* br_pred = (const float*)d_in[13];
    const float* att_pred= (const float*)d_in[14];
    const float* b_pred  = (const float*)d_in[15];

    const float* Wl_succ = (const float*)d_in[16];
    const float* bl_succ = (const float*)d_in[17];
    const float* Wr_succ = (const float*)d_in[18];
    const float* br_succ = (const float*)d_in[19];
    const float* att_succ= (const float*)d_in[20];
    const float* b_succ  = (const float*)d_in[21];

    const float* Wl_o2m  = (const float*)d_in[22];
    const float* bl_o2m  = (const float*)d_in[23];
    const float* Wr_o2m  = (const float*)d_in[24];
    const float* br_o2m  = (const float*)d_in[25];
    const float* att_o2m = (const float*)d_in[26];
    const float* b_o2m   = (const float*)d_in[27];

    const float* Wl_m2a  = (const float*)d_in[28];
    const float* bl_m2a  = (const float*)d_in[29];
    const float* Wr_m2a  = (const float*)d_in[30];
    const float* br_m2a  = (const float*)d_in[31];
    const float* att_m2a = (const float*)d_in[32];
    const float* b_m2a   = (const float*)d_in[33];
    const float* We_m2a  = (const float*)d_in[34];

    float* ws = (float*)d_ws;
    unsigned short* H     = (unsigned short*)(ws + F_H);
    unsigned short* xc_op = (unsigned short*)(ws + F_XCOP);
    unsigned short* xc_m  = (unsigned short*)(ws + F_XCM);
    unsigned short* xc_a  = (unsigned short*)(ws + F_XCA);
    unsigned short* BtP   = (unsigned short*)(ws + F_BTP);
    unsigned short* BtS   = (unsigned short*)(ws + F_BTS);
    unsigned short* BtOL  = (unsigned short*)(ws + F_BTOL);
    unsigned short* BtOR  = (unsigned short*)(ws + F_BTOR);
    unsigned short* BtML  = (unsigned short*)(ws + F_BTML);
    unsigned short* BtMR  = (unsigned short*)(ws + F_BTMR);
    float* biasP = ws + F_BIASP;
    float* biasS = ws + F_BIASS;
    float* ebuf  = ws + F_EBUF;
    int* cnt  = (int*)(ws + F_CNT);
    int* cur  = (int*)(ws + F_CUR);
    int* bsum = (int*)(ws + F_BSUM);
    int* boff = (int*)(ws + F_BOFF);
    int* ptrP = (int*)(ws + F_PTR_P); int* srcP = (int*)(ws + F_SRC_P); int* eidP = (int*)(ws + F_EID_P); int* dstP = (int*)(ws + F_DST_P);
    int* ptrS = (int*)(ws + F_PTR_S); int* srcS = (int*)(ws + F_SRC_S); int* eidS = (int*)(ws + F_EID_S); int* dstS = (int*)(ws + F_DST_S);
    int* ptrO = (int*)(ws + F_PTR_O); int* srcO = (int*)(ws + F_SRC_O); int* eidO = (int*)(ws + F_EID_O); int* dstO = (int*)(ws + F_DST_O);
    int* ptrA = (int*)(ws + F_PTR_A); int* srcA = (int*)(ws + F_SRC_A); int* eidA = (int*)(ws + F_EID_A); int* dstA = (int*)(ws + F_DST_A);

    float* out_op = (float*)d_out + OUT_OP_OFF;
    float* out_m  = (float*)d_out + OUT_M_OFF;
    float* out_a  = (float*)d_out + OUT_A_OFF;

    // ---- CSR builds ----
    build_csr(ei_pred, ei_pred + E_OO, E_OO, N_OP, cnt, cur, bsum, boff, ptrP, srcP, dstP, eidP, stream);
    build_csr(ei_succ, ei_succ + E_OO, E_OO, N_OP, cnt, cur, bsum, boff, ptrS, srcS, dstS, eidS, stream);
    build_csr(src_o2m, dst_o2m, E_OM, N_M, cnt, cur, bsum, boff, ptrO, srcO, dstO, eidO, stream);
    build_csr(src_m2a, dst_m2a, E_MA, N_A, cnt, cur, bsum, boff, ptrA, srcA, dstA, eidA, stream);

    // ---- fused residual-init + conversions; weight packing ----
    init_cvt<C_OP><<<(N_OP * C_OP / 4 + 255) / 256, 256, 0, stream>>>(x_op, b_pred, b_succ, out_op, xc_op, N_OP * C_OP / 4);
    init_cvt<C_M ><<<(N_M * C_M / 4 + 255) / 256, 256, 0, stream>>>(x_m, b_o2m, nullptr, out_m, xc_m, N_M * C_M / 4);
    init_cvt<C_A ><<<(N_A * C_A / 4 + 255) / 256, 256, 0, stream>>>(x_a, b_m2a, nullptr, out_a, xc_a, N_A * C_A / 4);
    pack_w2<<<(2 * 256 * 256 + 255) / 256, 256, 0, stream>>>(Wl_pred, Wr_pred, 256, 256, BtP);
    pack_w2<<<(2 * 256 * 256 + 255) / 256, 256, 0, stream>>>(Wl_succ, Wr_succ, 256, 256, BtS);
    pack_w1<<<(128 * 256 + 255) / 256, 256, 0, stream>>>(Wl_o2m, 256, 128, BtOL);
    pack_w1<<<(128 * 128 + 255) / 256, 256, 0, stream>>>(Wr_o2m, 128, 128, BtOR);
    pack_w1<<<(128 * 128 + 255) / 256, 256, 0, stream>>>(Wl_m2a, 128, 128, BtML);
    pack_w1<<<(128 * 128 + 255) / 256, 256, 0, stream>>>(Wr_m2a, 128, 128, BtMR);
    pack_bias2<<<2, 256, 0, stream>>>(bl_pred, br_pred, 256, biasP);
    pack_bias2<<<2, 256, 0, stream>>>(bl_succ, br_succ, 256, biasS);

    const int MT_OP = (N_OP + 127) / 128;
    const int MT_M  = (N_M + 127) / 128;
    const int MT_A  = (N_A + 127) / 128;

    // ---------------- conv 1: pred (op->op, C=256), H = [50000][512] ----------------
    mfma_gemm<<<dim3(MT_OP, 4), 256, 0, stream>>>(xc_op, BtP, biasP, H, N_OP, 256, 512);
    edge_logit<256, false><<<E_OO / 4, 256, 0, stream>>>(H, 512, H + 256, 512, nullptr, att_pred,
                                                         srcP, dstP, ebuf, E_OO);
    csr_agg<256><<<(N_OP + 3) / 4, 256, 0, stream>>>(H, 512, ebuf, ptrP, srcP, out_op, N_OP);

    // ---------------- conv 2: succ ----------------
    mfma_gemm<<<dim3(MT_OP, 4), 256, 0, stream>>>(xc_op, BtS, biasS, H, N_OP, 256, 512);
    edge_logit<256, false><<<E_OO / 4, 256, 0, stream>>>(H, 512, H + 256, 512, nullptr, att_succ,
                                                         srcS, dstS, ebuf, E_OO);
    csr_agg<256><<<(N_OP + 3) / 4, 256, 0, stream>>>(H, 512, ebuf, ptrS, srcS, out_op, N_OP);

    // ---------------- conv 3: o2m (op->machine, C=128) ----------------
    {
        unsigned short* xlb = H;                 // [50000][128]
        unsigned short* xrb = H + 6400000;       // [5000][128]
        mfma_gemm<<<dim3(MT_OP, 1), 256, 0, stream>>>(xc_op, BtOL, bl_o2m, xlb, N_OP, 256, 128);
        mfma_gemm<<<dim3(MT_M, 1), 256, 0, stream>>>(xc_m, BtOR, br_o2m, xrb, N_M, 128, 128);
        edge_logit<128, false><<<E_OM / 4, 256, 0, stream>>>(xlb, 128, xrb, 128, nullptr, att_o2m,
                                                             srcO, dstO, ebuf, E_OM);
        csr_agg<128><<<(N_M + 3) / 4, 256, 0, stream>>>(xlb, 128, ebuf, ptrO, srcO, out_m, N_M);
    }

    // ---------------- conv 4: m2a (machine->agv, C=128, edge feats) ----------------
    {
        unsigned short* xlb = H;                 // [5000][128]
        unsigned short* xrb = H + 1000000;       // [2000][128]
        unsigned short* efb = H + 2000000;       // [60000][128] CSR-slot order
        mfma_gemm<<<dim3(MT_M, 1), 256, 0, stream>>>(xc_m, BtML, bl_m2a, xlb, N_M, 128, 128);
        mfma_gemm<<<dim3(MT_A, 1), 256, 0, stream>>>(xc_a, BtMR, br_m2a, xrb, N_A, 128, 128);
        gemm_ef<8, 128, 4><<<E_MA / 4, 128, 0, stream>>>(ea_m2a, We_m2a, eidA, efb);
        edge_logit<128, true><<<E_MA / 4, 256, 0, stream>>>(xlb, 128, xrb, 128, efb, att_m2a,
                                                            srcA, dstA, ebuf, E_MA);
        csr_agg<128><<<(N_A + 3) / 4, 256, 0, stream>>>(xlb, 128, ebuf, ptrA, srcA, out_a, N_A);
    }
}

// Round 6
// 482.436 us; speedup vs baseline: 4.1642x; 1.1517x over previous
//
#include <hip/hip_runtime.h>

// ---------------------------------------------------------------------------
// Problem constants (fixed by setup_inputs)
// ---------------------------------------------------------------------------
#define N_OP   50000
#define N_M    5000
#define N_A    2000
#define C_OP   256
#define C_M    128
#define C_A    128
#define E_OO   200000
#define E_OM   200000
#define E_MA   60000
#define E_DIM  8

#define OUT_OP_OFF 0
#define OUT_M_OFF  (N_OP * C_OP)
#define OUT_A_OFF  (N_OP * C_OP + N_M * C_M)

typedef short bf16x8 __attribute__((ext_vector_type(8)));
typedef float f32x4 __attribute__((ext_vector_type(4)));
typedef __attribute__((address_space(1))) const unsigned gu32;
typedef __attribute__((address_space(3))) unsigned lu32;

__device__ __forceinline__ unsigned short f2bf(float f) {
    unsigned u = __float_as_uint(f);
    unsigned r = (u + 0x7FFFu + ((u >> 16) & 1u)) >> 16;
    return (unsigned short)r;
}
__device__ __forceinline__ float bf2f(unsigned short h) {
    return __uint_as_float(((unsigned)h) << 16);
}

// ---------------------------------------------------------------------------
// Fused residual-init + bf16 conversion: out = x + b1 (+b2), xc = bf16(x)
// ---------------------------------------------------------------------------
template <int C>
__global__ void init_cvt(const float* __restrict__ x, const float* __restrict__ b1,
                         const float* __restrict__ b2, float* __restrict__ out,
                         unsigned short* __restrict__ xc, int total4) {
    int i = blockIdx.x * blockDim.x + threadIdx.x;
    if (i >= total4) return;
    float4 v = ((const float4*)x)[i];
    const int cb = i & (C / 4 - 1);
    float4 b = ((const float4*)b1)[cb];
    if (b2) {
        float4 b2v = ((const float4*)b2)[cb];
        b.x += b2v.x; b.y += b2v.y; b.z += b2v.z; b.w += b2v.w;
    }
    float4 o;
    o.x = v.x + b.x; o.y = v.y + b.y; o.z = v.z + b.z; o.w = v.w + b.w;
    ((float4*)out)[i] = o;
    ushort4 r;
    r.x = f2bf(v.x); r.y = f2bf(v.y); r.z = f2bf(v.z); r.w = f2bf(v.w);
    ((ushort4*)xc)[i] = r;
}

__global__ void pack_w2(const float* __restrict__ Wl, const float* __restrict__ Wr,
                        int K, int N1, unsigned short* __restrict__ Bt) {
    int idx = blockIdx.x * blockDim.x + threadIdx.x;
    if (idx >= 2 * N1 * K) return;
    int n = idx / K, k = idx - n * K;
    float v = (n < N1) ? Wl[k * N1 + n] : Wr[k * N1 + (n - N1)];
    Bt[idx] = f2bf(v);
}
__global__ void pack_w1(const float* __restrict__ W, int K, int N, unsigned short* __restrict__ Bt) {
    int idx = blockIdx.x * blockDim.x + threadIdx.x;
    if (idx >= N * K) return;
    int n = idx / K, k = idx - n * K;
    Bt[idx] = f2bf(W[k * N + n]);
}
__global__ void pack_bias2(const float* __restrict__ bl, const float* __restrict__ br,
                           int N1, float* __restrict__ bp) {
    int i = blockIdx.x * blockDim.x + threadIdx.x;
    if (i < 2 * N1) bp[i] = (i < N1) ? bl[i] : br[i - N1];
}

// ---------------------------------------------------------------------------
// MFMA bf16 GEMM: 128x128 tile, BK=64, double-buffered, XOR-swizzled LDS
// (verified round 5).
// ---------------------------------------------------------------------------
__device__ __forceinline__ void gload_lds16(const void* g, void* l) {
    __builtin_amdgcn_global_load_lds((gu32*)g, (lu32*)l, 16, 0, 0);
}

__global__ __launch_bounds__(256) void mfma_gemm(
    const unsigned short* __restrict__ A, const unsigned short* __restrict__ Bt,
    const float* __restrict__ bias, unsigned short* __restrict__ C,
    int M, int K, int ldc) {
    __shared__ unsigned short As[2][128 * 64];
    __shared__ unsigned short Bs[2][128 * 64];

    const int tid  = threadIdx.x;
    const int lane = tid & 63;
    const int wid  = tid >> 6;
    const int m0   = blockIdx.x * 128;
    const int n0   = blockIdx.y * 128;

    f32x4 acc[4][4] = {};

    const int srow   = tid >> 3;
    const int scolb  = (tid & 7) * 16;
    const int scole  = (scolb ^ ((srow & 7) << 4)) >> 1;

    int grA[4], grB[4];
#pragma unroll
    for (int i = 0; i < 4; ++i) {
        int gr = m0 + i * 32 + srow;
        grA[i] = (gr < M) ? gr : M - 1;
        grB[i] = n0 + i * 32 + srow;
    }

    const int nt = K >> 6;
    int cur = 0;

#define STAGE(buf, k0)                                                          \
    {                                                                           \
        _Pragma("unroll")                                                       \
        for (int i = 0; i < 4; ++i)                                             \
            gload_lds16(A + (size_t)grA[i] * K + (k0) + scole,                  \
                        &As[buf][i * 2048 + tid * 8]);                          \
        _Pragma("unroll")                                                       \
        for (int i = 0; i < 4; ++i)                                             \
            gload_lds16(Bt + (size_t)grB[i] * K + (k0) + scole,                 \
                        &Bs[buf][i * 2048 + tid * 8]);                          \
    }

    STAGE(0, 0)
    asm volatile("s_waitcnt vmcnt(0)" ::: "memory");
    __syncthreads();

    const int wr = (wid >> 1) * 64;
    const int wc = (wid & 1) * 64;

    for (int t = 0; t < nt; ++t) {
        if (t + 1 < nt) STAGE(cur ^ 1, (t + 1) * 64)
#pragma unroll
        for (int kh = 0; kh < 2; ++kh) {
            const int kob = kh * 64 + (lane >> 4) * 16;
            bf16x8 a[4], b[4];
#pragma unroll
            for (int mi = 0; mi < 4; ++mi) {
                const int row = wr + mi * 16 + (lane & 15);
                a[mi] = *(const bf16x8*)((const char*)As[cur] + row * 128 +
                                         (kob ^ ((row & 7) << 4)));
            }
#pragma unroll
            for (int ni = 0; ni < 4; ++ni) {
                const int row = wc + ni * 16 + (lane & 15);
                b[ni] = *(const bf16x8*)((const char*)Bs[cur] + row * 128 +
                                         (kob ^ ((row & 7) << 4)));
            }
#pragma unroll
            for (int mi = 0; mi < 4; ++mi)
#pragma unroll
                for (int ni = 0; ni < 4; ++ni)
                    acc[mi][ni] = __builtin_amdgcn_mfma_f32_16x16x32_bf16(
                        a[mi], b[ni], acc[mi][ni], 0, 0, 0);
        }
        asm volatile("s_waitcnt vmcnt(0)" ::: "memory");
        __syncthreads();
        cur ^= 1;
    }
#undef STAGE

    const int crow = (lane >> 4) * 4;
    const int ccol = lane & 15;
    float bcol[4];
#pragma unroll
    for (int ni = 0; ni < 4; ++ni) bcol[ni] = bias[n0 + wc + ni * 16 + ccol];
#pragma unroll
    for (int mi = 0; mi < 4; ++mi) {
#pragma unroll
        for (int j = 0; j < 4; ++j) {
            const int row = m0 + wr + mi * 16 + crow + j;
            if (row < M) {
                unsigned short* pc = C + (size_t)row * ldc + n0 + wc + ccol;
#pragma unroll
                for (int ni = 0; ni < 4; ++ni)
                    pc[ni * 16] = f2bf(acc[mi][ni][j] + bcol[ni]);
            }
        }
    }
}

// ---------------------------------------------------------------------------
// Small fp32 GEMM for edge features (K=8), rows permuted by eid (CSR order)
// ---------------------------------------------------------------------------
template <int K, int N, int TM>
__global__ void gemm_ef(const float* __restrict__ A, const float* __restrict__ W,
                        const int* __restrict__ eid, unsigned short* __restrict__ out) {
    __shared__ float As[TM][K];
    const int m0 = blockIdx.x * TM;
    const int tid = threadIdx.x;
    for (int idx = tid; idx < TM * K; idx += N) {
        int r = idx / K, k = idx - r * K;
        As[r][k] = A[(size_t)eid[m0 + r] * K + k];
    }
    __syncthreads();
    float acc[TM] = {};
    for (int k = 0; k < K; ++k) {
        const float w = W[k * N + tid];
#pragma unroll
        for (int r = 0; r < TM; ++r) acc[r] += As[r][k] * w;
    }
#pragma unroll
    for (int r = 0; r < TM; ++r) out[(size_t)(m0 + r) * N + tid] = f2bf(acc[r]);
}

// ---------------------------------------------------------------------------
// CSR build: zero2 -> histogram -> hierarchical scan -> scatter (src,eid)
// ---------------------------------------------------------------------------
__global__ void zero2_i32(int* __restrict__ a, int* __restrict__ b, int n) {
    int i = blockIdx.x * blockDim.x + threadIdx.x;
    if (i < n) { a[i] = 0; b[i] = 0; }
}
__global__ void hist_dst(const int* __restrict__ dst, int* __restrict__ cnt, int E) {
    int i = blockIdx.x * blockDim.x + threadIdx.x;
    if (i < E) atomicAdd(&cnt[dst[i]], 1);
}
__global__ void scan_blk(const int* __restrict__ cnt, int* __restrict__ ptr,
                         int* __restrict__ bsum, int n) {
    __shared__ int smem[1024];
    const int tid = threadIdx.x;
    const int i = blockIdx.x * 1024 + tid;
    const int v = (i < n) ? cnt[i] : 0;
    smem[tid] = v;
    __syncthreads();
    for (int o = 1; o < 1024; o <<= 1) {
        int t = (tid >= o) ? smem[tid - o] : 0;
        __syncthreads();
        smem[tid] += t;
        __syncthreads();
    }
    if (i < n) ptr[i] = smem[tid] - v;
    if (tid == 1023) bsum[blockIdx.x] = smem[1023];
}
__global__ void scan_tops(const int* __restrict__ bsum, int* __restrict__ boff,
                          int* __restrict__ ptr_n, int nb) {
    __shared__ int smem[1024];
    const int tid = threadIdx.x;
    const int v = (tid < nb) ? bsum[tid] : 0;
    smem[tid] = v;
    __syncthreads();
    for (int o = 1; o < 1024; o <<= 1) {
        int t = (tid >= o) ? smem[tid - o] : 0;
        __syncthreads();
        smem[tid] += t;
        __syncthreads();
    }
    if (tid < nb) boff[tid] = smem[tid] - v;
    if (tid == 1023) *ptr_n = smem[1023];
}
__global__ void scan_add(int* __restrict__ ptr, const int* __restrict__ boff, int n) {
    int i = blockIdx.x * blockDim.x + threadIdx.x;
    if (i < n) ptr[i] += boff[i >> 10];
}
__global__ void scatter_e(const int* __restrict__ src, const int* __restrict__ dst,
                          const int* __restrict__ ptr, int* __restrict__ cur,
                          int* __restrict__ srcs, int* __restrict__ eidx, int E) {
    int i = blockIdx.x * blockDim.x + threadIdx.x;
    if (i >= E) return;
    const int d = dst[i];
    const int pos = ptr[d] + atomicAdd(&cur[d], 1);
    srcs[pos] = src[i];
    eidx[pos] = i;
}

// ---------------------------------------------------------------------------
// Fused GATv2 edge pipeline over CSR: one wave per dst node.
//   pass A (per <=64-edge chunk): gather xl[src] rows, e_j = att.leaky(
//     xl+xr(+ef)); wave-cooperative dot, e parked in lane j; online max/sum.
//   pass B: re-read rows (L1-hot) and accumulate w_j * xl[src].
// Zero atomics, e never leaves registers, xr read once per node.
// ---------------------------------------------------------------------------
template <int C, bool HAS_EF>
__global__ void csr_fused(const unsigned short* __restrict__ xl, int ldl,
                          const unsigned short* __restrict__ xr, int ldr,
                          const unsigned short* __restrict__ ef,
                          const float* __restrict__ att,
                          const int* __restrict__ ptr, const int* __restrict__ srcs,
                          float* __restrict__ out, int n) {
    const int node = blockIdx.x * (blockDim.x >> 6) + (threadIdx.x >> 6);
    if (node >= n) return;
    const int lane = threadIdx.x & 63;
    const int beg = ptr[node], end = ptr[node + 1];
    if (beg == end) return;

    constexpr int V = C / 64;
    const int c0 = lane * V;

    float av[V], rvf[V];
    {
        const unsigned short* pr = xr + (size_t)node * ldr + c0;
        unsigned short rv[V];
        if constexpr (V == 4) *(uint2*)rv = *(const uint2*)pr;
        else                  *(unsigned*)rv = *(const unsigned*)pr;
#pragma unroll
        for (int v = 0; v < V; ++v) { rvf[v] = bf2f(rv[v]); av[v] = att[c0 + v]; }
    }

    float runM = -3.0e38f, runS = 0.0f;
    float acc[V] = {};

    for (int cbeg = beg; cbeg < end; cbeg += 64) {
        const int cn = min(64, end - cbeg);
        const int sj = (lane < cn) ? srcs[cbeg + lane] : 0;

        // ---- pass A: logits for this chunk ----
        float ev = -3.0e38f;
        for (int j = 0; j < cn; ++j) {
            const int s = __shfl(sj, j, 64);
            const unsigned short* pl = xl + (size_t)s * ldl + c0;
            unsigned short lv[V], efv[V];
            if constexpr (V == 4) {
                *(uint2*)lv = *(const uint2*)pl;
                if (HAS_EF) *(uint2*)efv = *(const uint2*)(ef + (size_t)(cbeg + j) * C + c0);
            } else {
                *(unsigned*)lv = *(const unsigned*)pl;
                if (HAS_EF) *(unsigned*)efv = *(const unsigned*)(ef + (size_t)(cbeg + j) * C + c0);
            }
            float part = 0.0f;
#pragma unroll
            for (int v = 0; v < V; ++v) {
                float m = bf2f(lv[v]) + rvf[v];
                if (HAS_EF) m += bf2f(efv[v]);
                m = (m >= 0.0f) ? m : 0.2f * m;
                part += m * av[v];
            }
#pragma unroll
            for (int o = 32; o > 0; o >>= 1) part += __shfl_xor(part, o, 64);
            if (lane == j) ev = part;
        }

        // ---- online softmax update ----
        float cm = ev;
#pragma unroll
        for (int o = 32; o > 0; o >>= 1) cm = fmaxf(cm, __shfl_xor(cm, o, 64));
        const float newM = fmaxf(runM, cm);
        const float scale = __expf(runM - newM);   // 0 on first chunk
        runS *= scale;
#pragma unroll
        for (int v = 0; v < V; ++v) acc[v] *= scale;

        const float w = (lane < cn) ? __expf(ev - newM) : 0.0f;
        float cs = w;
#pragma unroll
        for (int o = 32; o > 0; o >>= 1) cs += __shfl_xor(cs, o, 64);
        runS += cs;
        runM = newM;

        // ---- pass B: weighted aggregate (rows L1-hot) ----
        for (int j = 0; j < cn; ++j) {
            const int s = __shfl(sj, j, 64);
            const float wj = __shfl(w, j, 64);
            const unsigned short* pl = xl + (size_t)s * ldl + c0;
            unsigned short lv[V];
            if constexpr (V == 4) *(uint2*)lv = *(const uint2*)pl;
            else                  *(unsigned*)lv = *(const unsigned*)pl;
#pragma unroll
            for (int v = 0; v < V; ++v) acc[v] += wj * bf2f(lv[v]);
        }
    }

    const float inv = 1.0f / fmaxf(runS, 1e-16f);
    float* po = out + (size_t)node * C + c0;
#pragma unroll
    for (int v = 0; v < V; ++v) po[v] += acc[v] * inv;
}

// ---------------------------------------------------------------------------
// Workspace layout (float slots).  Ends ~86.3 MB (ws >= 103.6 MB proven).
// ---------------------------------------------------------------------------
#define F_H      0
#define F_XCOP   12800000
#define F_XCM    19200000
#define F_XCA    19520000
#define F_BTP    19648000
#define F_BTS    19713536
#define F_BTOL   19779072
#define F_BTOR   19795456
#define F_BTML   19803648
#define F_BTMR   19811840
#define F_BIASP  19820032
#define F_BIASS  19820544
#define F_CNT    20030000
#define F_PTR_P  20080008
#define F_SRC_P  20130016
#define F_EID_P  20330016
#define F_PTR_S  20530016
#define F_SRC_S  20580024
#define F_EID_S  20780024
#define F_PTR_O  20980024
#define F_SRC_O  20985032
#define F_EID_O  21185032
#define F_PTR_A  21385032
#define F_SRC_A  21387040
#define F_EID_A  21447040
#define F_CUR    21507040
#define F_BSUM   21557040
#define F_BOFF   21558064    // ends 21,559,088 floats = 86.2 MB

static void build_csr(const int* src, const int* dst, int E, int n,
                      int* cnt, int* cur, int* bsum, int* boff,
                      int* ptr, int* srcs, int* eidx, hipStream_t stream) {
    const int nb = (n + 1023) / 1024;
    zero2_i32<<<(n + 255) / 256, 256, 0, stream>>>(cnt, cur, n);
    hist_dst<<<(E + 255) / 256, 256, 0, stream>>>(dst, cnt, E);
    scan_blk<<<nb, 1024, 0, stream>>>(cnt, ptr, bsum, n);
    scan_tops<<<1, 1024, 0, stream>>>(bsum, boff, ptr + n, nb);
    scan_add<<<(n + 255) / 256, 256, 0, stream>>>(ptr, boff, n);
    scatter_e<<<(E + 255) / 256, 256, 0, stream>>>(src, dst, ptr, cur, srcs, eidx, E);
}

extern "C" void kernel_launch(void* const* d_in, const int* in_sizes, int n_in,
                              void* d_out, int out_size, void* d_ws, size_t ws_size,
                              hipStream_t stream) {
    const float* x_op    = (const float*)d_in[0];
    const float* x_m     = (const float*)d_in[1];
    const float* x_a     = (const float*)d_in[2];
    const int*   ei_pred = (const int*)d_in[3];
    const int*   ei_succ = (const int*)d_in[4];
    const int*   src_o2m = (const int*)d_in[5];
    const int*   dst_o2m = (const int*)d_in[6];
    const int*   src_m2a = (const int*)d_in[7];
    const int*   dst_m2a = (const int*)d_in[8];
    const float* ea_m2a  = (const float*)d_in[9];

    const float* Wl_pred = (const float*)d_in[10];
    const float* bl_pred = (const float*)d_in[11];
    const float* Wr_pred = (const float*)d_in[12];
    const float* br_pred = (const float*)d_in[13];
    const float* att_pred= (const float*)d_in[14];
    const float* b_pred  = (const float*)d_in[15];

    const float* Wl_succ = (const float*)d_in[16];
    const float* bl_succ = (const float*)d_in[17];
    const float* Wr_succ = (const float*)d_in[18];
    const float* br_succ = (const float*)d_in[19];
    const float* att_succ= (const float*)d_in[20];
    const float* b_succ  = (const float*)d_in[21];

    const float* Wl_o2m  = (const float*)d_in[22];
    const float* bl_o2m  = (const float*)d_in[23];
    const float* Wr_o2m  = (const float*)d_in[24];
    const float* br_o2m  = (const float*)d_in[25];
    const float* att_o2m = (const float*)d_in[26];
    const float* b_o2m   = (const float*)d_in[27];

    const float* Wl_m2a  = (const float*)d_in[28];
    const float* bl_m2a  = (const float*)d_in[29];
    const float* Wr_m2a  = (const float*)d_in[30];
    const float* br_m2a  = (const float*)d_in[31];
    const float* att_m2a = (const float*)d_in[32];
    const float* b_m2a   = (const float*)d_in[33];
    const float* We_m2a  = (const float*)d_in[34];

    float* ws = (float*)d_ws;
    unsigned short* H     = (unsigned short*)(ws + F_H);
    unsigned short* xc_op = (unsigned short*)(ws + F_XCOP);
    unsigned short* xc_m  = (unsigned short*)(ws + F_XCM);
    unsigned short* xc_a  = (unsigned short*)(ws + F_XCA);
    unsigned short* BtP   = (unsigned short*)(ws + F_BTP);
    unsigned short* BtS   = (unsigned short*)(ws + F_BTS);
    unsigned short* BtOL  = (unsigned short*)(ws + F_BTOL);
    unsigned short* BtOR  = (unsigned short*)(ws + F_BTOR);
    unsigned short* BtML  = (unsigned short*)(ws + F_BTML);
    unsigned short* BtMR  = (unsigned short*)(ws + F_BTMR);
    float* biasP = ws + F_BIASP;
    float* biasS = ws + F_BIASS;
    int* cnt  = (int*)(ws + F_CNT);
    int* cur  = (int*)(ws + F_CUR);
    int* bsum = (int*)(ws + F_BSUM);
    int* boff = (int*)(ws + F_BOFF);
    int* ptrP = (int*)(ws + F_PTR_P); int* srcP = (int*)(ws + F_SRC_P); int* eidP = (int*)(ws + F_EID_P);
    int* ptrS = (int*)(ws + F_PTR_S); int* srcS = (int*)(ws + F_SRC_S); int* eidS = (int*)(ws + F_EID_S);
    int* ptrO = (int*)(ws + F_PTR_O); int* srcO = (int*)(ws + F_SRC_O); int* eidO = (int*)(ws + F_EID_O);
    int* ptrA = (int*)(ws + F_PTR_A); int* srcA = (int*)(ws + F_SRC_A); int* eidA = (int*)(ws + F_EID_A);

    float* out_op = (float*)d_out + OUT_OP_OFF;
    float* out_m  = (float*)d_out + OUT_M_OFF;
    float* out_a  = (float*)d_out + OUT_A_OFF;

    // ---- CSR builds ----
    build_csr(ei_pred, ei_pred + E_OO, E_OO, N_OP, cnt, cur, bsum, boff, ptrP, srcP, eidP, stream);
    build_csr(ei_succ, ei_succ + E_OO, E_OO, N_OP, cnt, cur, bsum, boff, ptrS, srcS, eidS, stream);
    build_csr(src_o2m, dst_o2m, E_OM, N_M, cnt, cur, bsum, boff, ptrO, srcO, eidO, stream);
    build_csr(src_m2a, dst_m2a, E_MA, N_A, cnt, cur, bsum, boff, ptrA, srcA, eidA, stream);

    // ---- fused residual-init + conversions; weight packing ----
    init_cvt<C_OP><<<(N_OP * C_OP / 4 + 255) / 256, 256, 0, stream>>>(x_op, b_pred, b_succ, out_op, xc_op, N_OP * C_OP / 4);
    init_cvt<C_M ><<<(N_M * C_M / 4 + 255) / 256, 256, 0, stream>>>(x_m, b_o2m, nullptr, out_m, xc_m, N_M * C_M / 4);
    init_cvt<C_A ><<<(N_A * C_A / 4 + 255) / 256, 256, 0, stream>>>(x_a, b_m2a, nullptr, out_a, xc_a, N_A * C_A / 4);
    pack_w2<<<(2 * 256 * 256 + 255) / 256, 256, 0, stream>>>(Wl_pred, Wr_pred, 256, 256, BtP);
    pack_w2<<<(2 * 256 * 256 + 255) / 256, 256, 0, stream>>>(Wl_succ, Wr_succ, 256, 256, BtS);
    pack_w1<<<(128 * 256 + 255) / 256, 256, 0, stream>>>(Wl_o2m, 256, 128, BtOL);
    pack_w1<<<(128 * 128 + 255) / 256, 256, 0, stream>>>(Wr_o2m, 128, 128, BtOR);
    pack_w1<<<(128 * 128 + 255) / 256, 256, 0, stream>>>(Wl_m2a, 128, 128, BtML);
    pack_w1<<<(128 * 128 + 255) / 256, 256, 0, stream>>>(Wr_m2a, 128, 128, BtMR);
    pack_bias2<<<2, 256, 0, stream>>>(bl_pred, br_pred, 256, biasP);
    pack_bias2<<<2, 256, 0, stream>>>(bl_succ, br_succ, 256, biasS);

    const int MT_OP = (N_OP + 127) / 128;
    const int MT_M  = (N_M + 127) / 128;
    const int MT_A  = (N_A + 127) / 128;

    // ---------------- conv 1: pred (op->op, C=256), H = [50000][512] ----------------
    mfma_gemm<<<dim3(MT_OP, 4), 256, 0, stream>>>(xc_op, BtP, biasP, H, N_OP, 256, 512);
    csr_fused<256, false><<<(N_OP + 3) / 4, 256, 0, stream>>>(H, 512, H + 256, 512, nullptr,
                                                              att_pred, ptrP, srcP, out_op, N_OP);

    // ---------------- conv 2: succ ----------------
    mfma_gemm<<<dim3(MT_OP, 4), 256, 0, stream>>>(xc_op, BtS, biasS, H, N_OP, 256, 512);
    csr_fused<256, false><<<(N_OP + 3) / 4, 256, 0, stream>>>(H, 512, H + 256, 512, nullptr,
                                                              att_succ, ptrS, srcS, out_op, N_OP);

    // ---------------- conv 3: o2m (op->machine, C=128) ----------------
    {
        unsigned short* xlb = H;                 // [50000][128]
        unsigned short* xrb = H + 6400000;       // [5000][128]
        mfma_gemm<<<dim3(MT_OP, 1), 256, 0, stream>>>(xc_op, BtOL, bl_o2m, xlb, N_OP, 256, 128);
        mfma_gemm<<<dim3(MT_M, 1), 256, 0, stream>>>(xc_m, BtOR, br_o2m, xrb, N_M, 128, 128);
        csr_fused<128, false><<<(N_M + 3) / 4, 256, 0, stream>>>(xlb, 128, xrb, 128, nullptr,
                                                                 att_o2m, ptrO, srcO, out_m, N_M);
    }

    // ---------------- conv 4: m2a (machine->agv, C=128, edge feats) ----------------
    {
        unsigned short* xlb = H;                 // [5000][128]
        unsigned short* xrb = H + 1000000;       // [2000][128]
        unsigned short* efb = H + 2000000;       // [60000][128] CSR-slot order
        mfma_gemm<<<dim3(MT_M, 1), 256, 0, stream>>>(xc_m, BtML, bl_m2a, xlb, N_M, 128, 128);
        mfma_gemm<<<dim3(MT_A, 1), 256, 0, stream>>>(xc_a, BtMR, br_m2a, xrb, N_A, 128, 128);
        gemm_ef<8, 128, 4><<<E_MA / 4, 128, 0, stream>>>(ea_m2a, We_m2a, eidA, efb);
        csr_fused<128, true><<<(N_A + 3) / 4, 256, 0, stream>>>(xlb, 128, xrb, 128, efb,
                                                                att_m2a, ptrA, srcA, out_a, N_A);
    }
}

// Round 7
// 397.442 us; speedup vs baseline: 5.0547x; 1.2139x over previous
//
#include <hip/hip_runtime.h>

// ---------------------------------------------------------------------------
// Problem constants (fixed by setup_inputs)
// ---------------------------------------------------------------------------
#define N_OP   50000
#define N_M    5000
#define N_A    2000
#define C_OP   256
#define C_M    128
#define C_A    128
#define E_OO   200000
#define E_OM   200000
#define E_MA   60000
#define E_DIM  8

#define OUT_OP_OFF 0
#define OUT_M_OFF  (N_OP * C_OP)
#define OUT_A_OFF  (N_OP * C_OP + N_M * C_M)

typedef short bf16x8 __attribute__((ext_vector_type(8)));
typedef float f32x4 __attribute__((ext_vector_type(4)));
typedef __attribute__((address_space(1))) const unsigned gu32;
typedef __attribute__((address_space(3))) unsigned lu32;

__device__ __forceinline__ unsigned short f2bf(float f) {
    unsigned u = __float_as_uint(f);
    unsigned r = (u + 0x7FFFu + ((u >> 16) & 1u)) >> 16;
    return (unsigned short)r;
}
__device__ __forceinline__ float bf2f(unsigned short h) {
    return __uint_as_float(((unsigned)h) << 16);
}

// ---------------------------------------------------------------------------
// Fused residual-init + bf16 conversion for all 3 node types (1 launch).
// ---------------------------------------------------------------------------
__device__ __forceinline__ void init_one(const float* __restrict__ x,
                                         const float* __restrict__ b1,
                                         const float* __restrict__ b2,
                                         float* __restrict__ out,
                                         unsigned short* __restrict__ xc,
                                         int i, int cmask) {
    float4 v = ((const float4*)x)[i];
    const int cb = i & cmask;
    float4 b = ((const float4*)b1)[cb];
    if (b2) {
        float4 t = ((const float4*)b2)[cb];
        b.x += t.x; b.y += t.y; b.z += t.z; b.w += t.w;
    }
    float4 o;
    o.x = v.x + b.x; o.y = v.y + b.y; o.z = v.z + b.z; o.w = v.w + b.w;
    ((float4*)out)[i] = o;
    ushort4 r;
    r.x = f2bf(v.x); r.y = f2bf(v.y); r.z = f2bf(v.z); r.w = f2bf(v.w);
    ((ushort4*)xc)[i] = r;
}

#define I3_OP (N_OP * C_OP / 4)                 // 3,200,000
#define I3_M  (I3_OP + N_M * C_M / 4)           // 3,360,000
#define I3_A  (I3_M + N_A * C_A / 4)            // 3,424,000

__global__ void init3(const float* __restrict__ x_op, const float* __restrict__ x_m,
                      const float* __restrict__ x_a,
                      const float* __restrict__ bP, const float* __restrict__ bS,
                      const float* __restrict__ bO, const float* __restrict__ bA,
                      float* __restrict__ out_op, float* __restrict__ out_m,
                      float* __restrict__ out_a,
                      unsigned short* __restrict__ xcop, unsigned short* __restrict__ xcm,
                      unsigned short* __restrict__ xca) {
    int i = blockIdx.x * blockDim.x + threadIdx.x;
    if (i < I3_OP)      init_one(x_op, bP, bS, out_op, xcop, i, 63);
    else if (i < I3_M)  init_one(x_m, bO, nullptr, out_m, xcm, i - I3_OP, 31);
    else if (i < I3_A)  init_one(x_a, bA, nullptr, out_a, xca, i - I3_M, 31);
}

// ---------------------------------------------------------------------------
// All weight/bias packing in one launch.
// ---------------------------------------------------------------------------
#define PK_P   131072
#define PK_S   262144
#define PK_OL  294912
#define PK_OR  311296
#define PK_ML  327680
#define PK_MR  344064
#define PK_BP  344576
#define PK_BS  345088

__global__ void pack_all(const float* __restrict__ WlP, const float* __restrict__ WrP,
                         const float* __restrict__ WlS, const float* __restrict__ WrS,
                         const float* __restrict__ WOl, const float* __restrict__ WOr,
                         const float* __restrict__ WMl, const float* __restrict__ WMr,
                         const float* __restrict__ blP, const float* __restrict__ brP,
                         const float* __restrict__ blS, const float* __restrict__ brS,
                         unsigned short* __restrict__ BtP, unsigned short* __restrict__ BtS,
                         unsigned short* __restrict__ BtOL, unsigned short* __restrict__ BtOR,
                         unsigned short* __restrict__ BtML, unsigned short* __restrict__ BtMR,
                         float* __restrict__ biasP, float* __restrict__ biasS) {
    int i = blockIdx.x * blockDim.x + threadIdx.x;
    if (i < PK_P) {
        int n = i >> 8, k = i & 255;
        BtP[i] = f2bf((n < 256) ? WlP[k * 256 + n] : WrP[k * 256 + (n - 256)]);
    } else if (i < PK_S) {
        int j = i - PK_P; int n = j >> 8, k = j & 255;
        BtS[j] = f2bf((n < 256) ? WlS[k * 256 + n] : WrS[k * 256 + (n - 256)]);
    } else if (i < PK_OL) {
        int j = i - PK_S; int n = j >> 8, k = j & 255;
        BtOL[j] = f2bf(WOl[k * 128 + n]);
    } else if (i < PK_OR) {
        int j = i - PK_OL; int n = j >> 7, k = j & 127;
        BtOR[j] = f2bf(WOr[k * 128 + n]);
    } else if (i < PK_ML) {
        int j = i - PK_OR; int n = j >> 7, k = j & 127;
        BtML[j] = f2bf(WMl[k * 128 + n]);
    } else if (i < PK_MR) {
        int j = i - PK_ML; int n = j >> 7, k = j & 127;
        BtMR[j] = f2bf(WMr[k * 128 + n]);
    } else if (i < PK_BP) {
        int j = i - PK_MR;
        biasP[j] = (j < 256) ? blP[j] : brP[j - 256];
    } else if (i < PK_BS) {
        int j = i - PK_BP;
        biasS[j] = (j < 256) ? blS[j] : brS[j - 256];
    }
}

// ---------------------------------------------------------------------------
// MFMA bf16 GEMM: 128x128 tile, BK=64, double-buffered, XOR-swizzled LDS
// (verified rounds 5-6).
// ---------------------------------------------------------------------------
__device__ __forceinline__ void gload_lds16(const void* g, void* l) {
    __builtin_amdgcn_global_load_lds((gu32*)g, (lu32*)l, 16, 0, 0);
}

__global__ __launch_bounds__(256) void mfma_gemm(
    const unsigned short* __restrict__ A, const unsigned short* __restrict__ Bt,
    const float* __restrict__ bias, unsigned short* __restrict__ C,
    int M, int K, int ldc) {
    __shared__ unsigned short As[2][128 * 64];
    __shared__ unsigned short Bs[2][128 * 64];

    const int tid  = threadIdx.x;
    const int lane = tid & 63;
    const int wid  = tid >> 6;
    const int m0   = blockIdx.x * 128;
    const int n0   = blockIdx.y * 128;

    f32x4 acc[4][4] = {};

    const int srow   = tid >> 3;
    const int scolb  = (tid & 7) * 16;
    const int scole  = (scolb ^ ((srow & 7) << 4)) >> 1;

    int grA[4], grB[4];
#pragma unroll
    for (int i = 0; i < 4; ++i) {
        int gr = m0 + i * 32 + srow;
        grA[i] = (gr < M) ? gr : M - 1;
        grB[i] = n0 + i * 32 + srow;
    }

    const int nt = K >> 6;
    int cur = 0;

#define STAGE(buf, k0)                                                          \
    {                                                                           \
        _Pragma("unroll")                                                       \
        for (int i = 0; i < 4; ++i)                                             \
            gload_lds16(A + (size_t)grA[i] * K + (k0) + scole,                  \
                        &As[buf][i * 2048 + tid * 8]);                          \
        _Pragma("unroll")                                                       \
        for (int i = 0; i < 4; ++i)                                             \
            gload_lds16(Bt + (size_t)grB[i] * K + (k0) + scole,                 \
                        &Bs[buf][i * 2048 + tid * 8]);                          \
    }

    STAGE(0, 0)
    asm volatile("s_waitcnt vmcnt(0)" ::: "memory");
    __syncthreads();

    const int wr = (wid >> 1) * 64;
    const int wc = (wid & 1) * 64;

    for (int t = 0; t < nt; ++t) {
        if (t + 1 < nt) STAGE(cur ^ 1, (t + 1) * 64)
#pragma unroll
        for (int kh = 0; kh < 2; ++kh) {
            const int kob = kh * 64 + (lane >> 4) * 16;
            bf16x8 a[4], b[4];
#pragma unroll
            for (int mi = 0; mi < 4; ++mi) {
                const int row = wr + mi * 16 + (lane & 15);
                a[mi] = *(const bf16x8*)((const char*)As[cur] + row * 128 +
                                         (kob ^ ((row & 7) << 4)));
            }
#pragma unroll
            for (int ni = 0; ni < 4; ++ni) {
                const int row = wc + ni * 16 + (lane & 15);
                b[ni] = *(const bf16x8*)((const char*)Bs[cur] + row * 128 +
                                         (kob ^ ((row & 7) << 4)));
            }
#pragma unroll
            for (int mi = 0; mi < 4; ++mi)
#pragma unroll
                for (int ni = 0; ni < 4; ++ni)
                    acc[mi][ni] = __builtin_amdgcn_mfma_f32_16x16x32_bf16(
                        a[mi], b[ni], acc[mi][ni], 0, 0, 0);
        }
        asm volatile("s_waitcnt vmcnt(0)" ::: "memory");
        __syncthreads();
        cur ^= 1;
    }
#undef STAGE

    const int crow = (lane >> 4) * 4;
    const int ccol = lane & 15;
    float bcol[4];
#pragma unroll
    for (int ni = 0; ni < 4; ++ni) bcol[ni] = bias[n0 + wc + ni * 16 + ccol];
#pragma unroll
    for (int mi = 0; mi < 4; ++mi) {
#pragma unroll
        for (int j = 0; j < 4; ++j) {
            const int row = m0 + wr + mi * 16 + crow + j;
            if (row < M) {
                unsigned short* pc = C + (size_t)row * ldc + n0 + wc + ccol;
#pragma unroll
                for (int ni = 0; ni < 4; ++ni)
                    pc[ni * 16] = f2bf(acc[mi][ni][j] + bcol[ni]);
            }
        }
    }
}

// ---------------------------------------------------------------------------
// Small fp32 GEMM for edge features (K=8), rows permuted by eid (CSR order)
// ---------------------------------------------------------------------------
template <int K, int N, int TM>
__global__ void gemm_ef(const float* __restrict__ A, const float* __restrict__ W,
                        const int* __restrict__ eid, unsigned short* __restrict__ out) {
    __shared__ float As[TM][K];
    const int m0 = blockIdx.x * TM;
    const int tid = threadIdx.x;
    for (int idx = tid; idx < TM * K; idx += N) {
        int r = idx / K, k = idx - r * K;
        As[r][k] = A[(size_t)eid[m0 + r] * K + k];
    }
    __syncthreads();
    float acc[TM] = {};
    for (int k = 0; k < K; ++k) {
        const float w = W[k * N + tid];
#pragma unroll
        for (int r = 0; r < TM; ++r) acc[r] += As[r][k] * w;
    }
#pragma unroll
    for (int r = 0; r < TM; ++r) out[(size_t)(m0 + r) * N + tid] = f2bf(acc[r]);
}

// ---------------------------------------------------------------------------
// Batched CSR build for all 4 relations (6 launches total).
// Segment tables (compile-time): P,S: n=50000,E=200000; O: n=5000,E=200000;
// A: n=2000,E=60000.
// ---------------------------------------------------------------------------
#define NB_P 49
#define NB_S 49
#define NB_O 5
#define NB_A 2
#define NTOT 107000          // 50000+50000+5000+2000
#define ETOT 660000

__global__ void zero4(int* __restrict__ p, int n) {
    int i = blockIdx.x * blockDim.x + threadIdx.x;
    if (i < n) p[i] = 0;
}

__global__ void hist4(const int* __restrict__ dP, const int* __restrict__ dS,
                      const int* __restrict__ dO, const int* __restrict__ dA,
                      int* __restrict__ cP, int* __restrict__ cS,
                      int* __restrict__ cO, int* __restrict__ cA) {
    int i = blockIdx.x * blockDim.x + threadIdx.x;
    if (i < 200000)      atomicAdd(&cP[dP[i]], 1);
    else if (i < 400000) atomicAdd(&cS[dS[i - 200000]], 1);
    else if (i < 600000) atomicAdd(&cO[dO[i - 400000]], 1);
    else if (i < ETOT)   atomicAdd(&cA[dA[i - 600000]], 1);
}

__global__ void scan_blk4(const int* __restrict__ cP, const int* __restrict__ cS,
                          const int* __restrict__ cO, const int* __restrict__ cA,
                          int* __restrict__ pP, int* __restrict__ pS,
                          int* __restrict__ pO, int* __restrict__ pA,
                          int* __restrict__ bsum) {
    __shared__ int smem[1024];
    int b = blockIdx.x;
    const int* cnt; int* ptr; int n; int bo;
    if (b < NB_P)                { cnt = cP; ptr = pP; n = 50000; bo = 0; }
    else if (b < NB_P + NB_S)    { cnt = cS; ptr = pS; n = 50000; bo = 64;  b -= NB_P; }
    else if (b < NB_P + NB_S + NB_O) { cnt = cO; ptr = pO; n = 5000; bo = 128; b -= NB_P + NB_S; }
    else                         { cnt = cA; ptr = pA; n = 2000; bo = 192; b -= NB_P + NB_S + NB_O; }
    const int tid = threadIdx.x;
    const int i = b * 1024 + tid;
    const int v = (i < n) ? cnt[i] : 0;
    smem[tid] = v;
    __syncthreads();
    for (int o = 1; o < 1024; o <<= 1) {
        int t = (tid >= o) ? smem[tid - o] : 0;
        __syncthreads();
        smem[tid] += t;
        __syncthreads();
    }
    if (i < n) ptr[i] = smem[tid] - v;
    if (tid == 1023) bsum[bo + b] = smem[1023];
}

__global__ void scan_tops4(const int* __restrict__ bsum, int* __restrict__ boff,
                           int* __restrict__ pP, int* __restrict__ pS,
                           int* __restrict__ pO, int* __restrict__ pA) {
    __shared__ int smem[1024];
    const int seg = blockIdx.x;
    const int nb = (seg < 2) ? 49 : (seg == 2 ? 5 : 2);
    const int off = seg * 64;
    int* ptr_n = (seg == 0) ? pP + 50000 : (seg == 1) ? pS + 50000
               : (seg == 2) ? pO + 5000 : pA + 2000;
    const int tid = threadIdx.x;
    const int v = (tid < nb) ? bsum[off + tid] : 0;
    smem[tid] = v;
    __syncthreads();
    for (int o = 1; o < 1024; o <<= 1) {
        int t = (tid >= o) ? smem[tid - o] : 0;
        __syncthreads();
        smem[tid] += t;
        __syncthreads();
    }
    if (tid < nb) boff[off + tid] = smem[tid] - v;
    if (tid == 1023) *ptr_n = smem[1023];
}

__global__ void scan_add4(int* __restrict__ pP, int* __restrict__ pS,
                          int* __restrict__ pO, int* __restrict__ pA,
                          const int* __restrict__ boff) {
    int i = blockIdx.x * blockDim.x + threadIdx.x;
    int* ptr; int loc; int off;
    if (i < 50000)       { ptr = pP; loc = i;          off = 0; }
    else if (i < 100000) { ptr = pS; loc = i - 50000;  off = 64; }
    else if (i < 105000) { ptr = pO; loc = i - 100000; off = 128; }
    else if (i < NTOT)   { ptr = pA; loc = i - 105000; off = 192; }
    else return;
    ptr[loc] += boff[off + (loc >> 10)];
}

__global__ void scatter4(const int* __restrict__ sP, const int* __restrict__ dP,
                         const int* __restrict__ sS, const int* __restrict__ dS,
                         const int* __restrict__ sO, const int* __restrict__ dO,
                         const int* __restrict__ sA, const int* __restrict__ dA,
                         const int* __restrict__ pP, const int* __restrict__ pS,
                         const int* __restrict__ pO, const int* __restrict__ pA,
                         int* __restrict__ uP, int* __restrict__ uS,
                         int* __restrict__ uO, int* __restrict__ uA,
                         int* __restrict__ srP, int* __restrict__ srS,
                         int* __restrict__ srO, int* __restrict__ srA,
                         int* __restrict__ eiA) {
    int i = blockIdx.x * blockDim.x + threadIdx.x;
    if (i < 200000) {
        const int d = dP[i];
        srP[pP[d] + atomicAdd(&uP[d], 1)] = sP[i];
    } else if (i < 400000) {
        const int j = i - 200000; const int d = dS[j];
        srS[pS[d] + atomicAdd(&uS[d], 1)] = sS[j];
    } else if (i < 600000) {
        const int j = i - 400000; const int d = dO[j];
        srO[pO[d] + atomicAdd(&uO[d], 1)] = sO[j];
    } else if (i < ETOT) {
        const int j = i - 600000; const int d = dA[j];
        const int pos = pA[d] + atomicAdd(&uA[d], 1);
        srA[pos] = sA[j];
        eiA[pos] = j;
    }
}

// ---------------------------------------------------------------------------
// Fused GATv2 edge pipeline, single-pass online softmax: one wave per node.
// Per edge: gather row once (prefetched), wave-dot via butterfly shfl (sum
// lands in ALL lanes -> logit is wave-uniform), rescale-on-max-move, and
// accumulate w*row while the row is still in registers.  Zero atomics.
// ---------------------------------------------------------------------------
template <int C, bool HAS_EF>
__global__ void csr_fused(const unsigned short* __restrict__ xl, int ldl,
                          const unsigned short* __restrict__ xr, int ldr,
                          const unsigned short* __restrict__ ef,
                          const float* __restrict__ att,
                          const int* __restrict__ ptr, const int* __restrict__ srcs,
                          float* __restrict__ out, int n) {
    const int node = blockIdx.x * (blockDim.x >> 6) + (threadIdx.x >> 6);
    if (node >= n) return;
    const int lane = threadIdx.x & 63;
    const int beg = ptr[node], end = ptr[node + 1];
    if (beg == end) return;

    constexpr int V = C / 64;
    const int c0 = lane * V;

    float av[V], rvf[V];
    {
        const unsigned short* pr = xr + (size_t)node * ldr + c0;
        unsigned short rv[V];
        if constexpr (V == 4) *(uint2*)rv = *(const uint2*)pr;
        else                  *(unsigned*)rv = *(const unsigned*)pr;
#pragma unroll
        for (int v = 0; v < V; ++v) { rvf[v] = bf2f(rv[v]); av[v] = att[c0 + v]; }
    }

    float runM = -3.0e38f, runS = 0.0f;
    float acc[V] = {};

    unsigned short lv[V];
    {
        const unsigned short* pl = xl + (size_t)srcs[beg] * ldl + c0;
        if constexpr (V == 4) *(uint2*)lv = *(const uint2*)pl;
        else                  *(unsigned*)lv = *(const unsigned*)pl;
    }

    for (int j = beg; j < end; ++j) {
        float cf[V];
#pragma unroll
        for (int v = 0; v < V; ++v) cf[v] = bf2f(lv[v]);
        if (j + 1 < end) {                      // prefetch next row
            const unsigned short* pl = xl + (size_t)srcs[j + 1] * ldl + c0;
            if constexpr (V == 4) *(uint2*)lv = *(const uint2*)pl;
            else                  *(unsigned*)lv = *(const unsigned*)pl;
        }

        float part = 0.0f;
        if constexpr (HAS_EF) {
            unsigned short efv[V];
            const unsigned short* pe = ef + (size_t)j * C + c0;
            if constexpr (V == 4) *(uint2*)efv = *(const uint2*)pe;
            else                  *(unsigned*)efv = *(const unsigned*)pe;
#pragma unroll
            for (int v = 0; v < V; ++v) {
                float m = cf[v] + rvf[v] + bf2f(efv[v]);
                m = (m >= 0.0f) ? m : 0.2f * m;
                part += m * av[v];
            }
        } else {
#pragma unroll
            for (int v = 0; v < V; ++v) {
                float m = cf[v] + rvf[v];
                m = (m >= 0.0f) ? m : 0.2f * m;
                part += m * av[v];
            }
        }
#pragma unroll
        for (int o = 32; o > 0; o >>= 1) part += __shfl_xor(part, o, 64);

        float w;
        if (part > runM) {                      // wave-uniform branch
            const float sc = __expf(runM - part);
            runS *= sc;
#pragma unroll
            for (int v = 0; v < V; ++v) acc[v] *= sc;
            runM = part;
            w = 1.0f;
        } else {
            w = __expf(part - runM);
        }
        runS += w;
#pragma unroll
        for (int v = 0; v < V; ++v) acc[v] += w * cf[v];
    }

    const float inv = 1.0f / fmaxf(runS, 1e-16f);
    float* po = out + (size_t)node * C + c0;
    if constexpr (V == 4) {
        float4 o = *(float4*)po;
        o.x += acc[0] * inv; o.y += acc[1] * inv;
        o.z += acc[2] * inv; o.w += acc[3] * inv;
        *(float4*)po = o;
    } else {
        float2 o = *(float2*)po;
        o.x += acc[0] * inv; o.y += acc[1] * inv;
        *(float2*)po = o;
    }
}

// ---------------------------------------------------------------------------
// Workspace layout (float slots).  Ends ~85.9 MB (ws >= 103.6 MB proven).
// ---------------------------------------------------------------------------
#define F_H      0
#define F_XCOP   12800000
#define F_XCM    19200000
#define F_XCA    19520000
#define F_BTP    19648000
#define F_BTS    19713536
#define F_BTOL   19779072
#define F_BTOR   19795456
#define F_BTML   19803648
#define F_BTMR   19811840
#define F_BIASP  19820032
#define F_BIASS  19820544
#define F_CNT4   19821056    // int[107000]: cntP,cntS,cntO,cntA contiguous
#define F_CUR4   19928056    // int[107000]
#define F_BSUM   20035056    // int[256]
#define F_BOFF   20035312    // int[256]
#define F_PTR_P  20035568    // int[50001]
#define F_SRC_P  20085569    // int[200000]
#define F_PTR_S  20285569    // int[50001]
#define F_SRC_S  20335570    // int[200000]
#define F_PTR_O  20535570    // int[5001]
#define F_SRC_O  20540571    // int[200000]
#define F_PTR_A  20740571    // int[2001]
#define F_SRC_A  20742572    // int[60000]
#define F_EID_A  20802572    // int[60000]  -> ends 20,862,572 floats = 83.5 MB

extern "C" void kernel_launch(void* const* d_in, const int* in_sizes, int n_in,
                              void* d_out, int out_size, void* d_ws, size_t ws_size,
                              hipStream_t stream) {
    const float* x_op    = (const float*)d_in[0];
    const float* x_m     = (const float*)d_in[1];
    const float* x_a     = (const float*)d_in[2];
    const int*   ei_pred = (const int*)d_in[3];
    const int*   ei_succ = (const int*)d_in[4];
    const int*   src_o2m = (const int*)d_in[5];
    const int*   dst_o2m = (const int*)d_in[6];
    const int*   src_m2a = (const int*)d_in[7];
    const int*   dst_m2a = (const int*)d_in[8];
    const float* ea_m2a  = (const float*)d_in[9];

    const float* Wl_pred = (const float*)d_in[10];
    const float* bl_pred = (const float*)d_in[11];
    const float* Wr_pred = (const float*)d_in[12];
    const float* br_pred = (const float*)d_in[13];
    const float* att_pred= (const float*)d_in[14];
    const float* b_pred  = (const float*)d_in[15];

    const float* Wl_succ = (const float*)d_in[16];
    const float* bl_succ = (const float*)d_in[17];
    const float* Wr_succ = (const float*)d_in[18];
    const float* br_succ = (const float*)d_in[19];
    const float* att_succ= (const float*)d_in[20];
    const float* b_succ  = (const float*)d_in[21];

    const float* Wl_o2m  = (const float*)d_in[22];
    const float* bl_o2m  = (const float*)d_in[23];
    const float* Wr_o2m  = (const float*)d_in[24];
    const float* br_o2m  = (const float*)d_in[25];
    const float* att_o2m = (const float*)d_in[26];
    const float* b_o2m   = (const float*)d_in[27];

    const float* Wl_m2a  = (const float*)d_in[28];
    const float* bl_m2a  = (const float*)d_in[29];
    const float* Wr_m2a  = (const float*)d_in[30];
    const float* br_m2a  = (const float*)d_in[31];
    const float* att_m2a = (const float*)d_in[32];
    const float* b_m2a   = (const float*)d_in[33];
    const float* We_m2a  = (const float*)d_in[34];

    float* ws = (float*)d_ws;
    unsigned short* H     = (unsigned short*)(ws + F_H);
    unsigned short* xc_op = (unsigned short*)(ws + F_XCOP);
    unsigned short* xc_m  = (unsigned short*)(ws + F_XCM);
    unsigned short* xc_a  = (unsigned short*)(ws + F_XCA);
    unsigned short* BtP   = (unsigned short*)(ws + F_BTP);
    unsigned short* BtS   = (unsigned short*)(ws + F_BTS);
    unsigned short* BtOL  = (unsigned short*)(ws + F_BTOL);
    unsigned short* BtOR  = (unsigned short*)(ws + F_BTOR);
    unsigned short* BtML  = (unsigned short*)(ws + F_BTML);
    unsigned short* BtMR  = (unsigned short*)(ws + F_BTMR);
    float* biasP = ws + F_BIASP;
    float* biasS = ws + F_BIASS;
    int* cntP = (int*)(ws + F_CNT4);
    int* cntS = cntP + 50000;
    int* cntO = cntP + 100000;
    int* cntA = cntP + 105000;
    int* curP = (int*)(ws + F_CUR4);
    int* curS = curP + 50000;
    int* curO = curP + 100000;
    int* curA = curP + 105000;
    int* bsum = (int*)(ws + F_BSUM);
    int* boff = (int*)(ws + F_BOFF);
    int* ptrP = (int*)(ws + F_PTR_P); int* srcP = (int*)(ws + F_SRC_P);
    int* ptrS = (int*)(ws + F_PTR_S); int* srcS = (int*)(ws + F_SRC_S);
    int* ptrO = (int*)(ws + F_PTR_O); int* srcO = (int*)(ws + F_SRC_O);
    int* ptrA = (int*)(ws + F_PTR_A); int* srcA = (int*)(ws + F_SRC_A);
    int* eidA = (int*)(ws + F_EID_A);

    float* out_op = (float*)d_out + OUT_OP_OFF;
    float* out_m  = (float*)d_out + OUT_M_OFF;
    float* out_a  = (float*)d_out + OUT_A_OFF;

    // ---- batched CSR build (6 launches) ----
    zero4<<<(2 * NTOT + 255) / 256, 256, 0, stream>>>(cntP, 2 * NTOT);
    hist4<<<(ETOT + 255) / 256, 256, 0, stream>>>(ei_pred + E_OO, ei_succ + E_OO,
                                                  dst_o2m, dst_m2a, cntP, cntS, cntO, cntA);
    scan_blk4<<<NB_P + NB_S + NB_O + NB_A, 1024, 0, stream>>>(cntP, cntS, cntO, cntA,
                                                              ptrP, ptrS, ptrO, ptrA, bsum);
    scan_tops4<<<4, 1024, 0, stream>>>(bsum, boff, ptrP, ptrS, ptrO, ptrA);
    scan_add4<<<(NTOT + 255) / 256, 256, 0, stream>>>(ptrP, ptrS, ptrO, ptrA, boff);
    scatter4<<<(ETOT + 255) / 256, 256, 0, stream>>>(
        ei_pred, ei_pred + E_OO, ei_succ, ei_succ + E_OO,
        src_o2m, dst_o2m, src_m2a, dst_m2a,
        ptrP, ptrS, ptrO, ptrA, curP, curS, curO, curA,
        srcP, srcS, srcO, srcA, eidA);

    // ---- fused init + pack (2 launches) ----
    init3<<<(I3_A + 255) / 256, 256, 0, stream>>>(x_op, x_m, x_a, b_pred, b_succ, b_o2m, b_m2a,
                                                  out_op, out_m, out_a, xc_op, xc_m, xc_a);
    pack_all<<<(PK_BS + 255) / 256, 256, 0, stream>>>(
        Wl_pred, Wr_pred, Wl_succ, Wr_succ, Wl_o2m, Wr_o2m, Wl_m2a, Wr_m2a,
        bl_pred, br_pred, bl_succ, br_succ,
        BtP, BtS, BtOL, BtOR, BtML, BtMR, biasP, biasS);

    const int MT_OP = (N_OP + 127) / 128;
    const int MT_M  = (N_M + 127) / 128;
    const int MT_A  = (N_A + 127) / 128;

    // ---------------- conv 1: pred (op->op, C=256), H = [50000][512] ----------------
    mfma_gemm<<<dim3(MT_OP, 4), 256, 0, stream>>>(xc_op, BtP, biasP, H, N_OP, 256, 512);
    csr_fused<256, false><<<(N_OP + 3) / 4, 256, 0, stream>>>(H, 512, H + 256, 512, nullptr,
                                                              att_pred, ptrP, srcP, out_op, N_OP);

    // ---------------- conv 2: succ ----------------
    mfma_gemm<<<dim3(MT_OP, 4), 256, 0, stream>>>(xc_op, BtS, biasS, H, N_OP, 256, 512);
    csr_fused<256, false><<<(N_OP + 3) / 4, 256, 0, stream>>>(H, 512, H + 256, 512, nullptr,
                                                              att_succ, ptrS, srcS, out_op, N_OP);

    // ---------------- conv 3: o2m (op->machine, C=128) ----------------
    {
        unsigned short* xlb = H;                 // [50000][128]
        unsigned short* xrb = H + 6400000;       // [5000][128]
        mfma_gemm<<<dim3(MT_OP, 1), 256, 0, stream>>>(xc_op, BtOL, bl_o2m, xlb, N_OP, 256, 128);
        mfma_gemm<<<dim3(MT_M, 1), 256, 0, stream>>>(xc_m, BtOR, br_o2m, xrb, N_M, 128, 128);
        csr_fused<128, false><<<(N_M + 3) / 4, 256, 0, stream>>>(xlb, 128, xrb, 128, nullptr,
                                                                 att_o2m, ptrO, srcO, out_m, N_M);
    }

    // ---------------- conv 4: m2a (machine->agv, C=128, edge feats) ----------------
    {
        unsigned short* xlb = H;                 // [5000][128]
        unsigned short* xrb = H + 1000000;       // [2000][128]
        unsigned short* efb = H + 2000000;       // [60000][128] CSR-slot order
        mfma_gemm<<<dim3(MT_M, 1), 256, 0, stream>>>(xc_m, BtML, bl_m2a, xlb, N_M, 128, 128);
        mfma_gemm<<<dim3(MT_A, 1), 256, 0, stream>>>(xc_a, BtMR, br_m2a, xrb, N_A, 128, 128);
        gemm_ef<8, 128, 4><<<E_MA / 4, 128, 0, stream>>>(ea_m2a, We_m2a, eidA, efb);
        csr_fused<128, true><<<(N_A + 3) / 4, 256, 0, stream>>>(xlb, 128, xrb, 128, efb,
                                                                att_m2a, ptrA, srcA, out_a, N_A);
    }
}

// Round 8
// 379.004 us; speedup vs baseline: 5.3006x; 1.0486x over previous
//
#include <hip/hip_runtime.h>

// ---------------------------------------------------------------------------
// Problem constants (fixed by setup_inputs)
// ---------------------------------------------------------------------------
#define N_OP   50000
#define N_M    5000
#define N_A    2000
#define C_OP   256
#define C_M    128
#define C_A    128
#define E_OO   200000
#define E_OM   200000
#define E_MA   60000
#define E_DIM  8

#define OUT_OP_OFF 0
#define OUT_M_OFF  (N_OP * C_OP)
#define OUT_A_OFF  (N_OP * C_OP + N_M * C_M)

typedef short bf16x8 __attribute__((ext_vector_type(8)));
typedef float f32x4 __attribute__((ext_vector_type(4)));
typedef __attribute__((address_space(1))) const unsigned gu32;
typedef __attribute__((address_space(3))) unsigned lu32;

__device__ __forceinline__ unsigned short f2bf(float f) {
    unsigned u = __float_as_uint(f);
    unsigned r = (u + 0x7FFFu + ((u >> 16) & 1u)) >> 16;
    return (unsigned short)r;
}
__device__ __forceinline__ float bf2f(unsigned short h) {
    return __uint_as_float(((unsigned)h) << 16);
}

// ---------------------------------------------------------------------------
// Fused residual-init + bf16 conversion for all 3 node types (1 launch).
// ---------------------------------------------------------------------------
__device__ __forceinline__ void init_one(const float* __restrict__ x,
                                         const float* __restrict__ b1,
                                         const float* __restrict__ b2,
                                         float* __restrict__ out,
                                         unsigned short* __restrict__ xc,
                                         int i, int cmask) {
    float4 v = ((const float4*)x)[i];
    const int cb = i & cmask;
    float4 b = ((const float4*)b1)[cb];
    if (b2) {
        float4 t = ((const float4*)b2)[cb];
        b.x += t.x; b.y += t.y; b.z += t.z; b.w += t.w;
    }
    float4 o;
    o.x = v.x + b.x; o.y = v.y + b.y; o.z = v.z + b.z; o.w = v.w + b.w;
    ((float4*)out)[i] = o;
    ushort4 r;
    r.x = f2bf(v.x); r.y = f2bf(v.y); r.z = f2bf(v.z); r.w = f2bf(v.w);
    ((ushort4*)xc)[i] = r;
}

#define I3_OP (N_OP * C_OP / 4)                 // 3,200,000
#define I3_M  (I3_OP + N_M * C_M / 4)           // 3,360,000
#define I3_A  (I3_M + N_A * C_A / 4)            // 3,424,000

__global__ void init3(const float* __restrict__ x_op, const float* __restrict__ x_m,
                      const float* __restrict__ x_a,
                      const float* __restrict__ bP, const float* __restrict__ bS,
                      const float* __restrict__ bO, const float* __restrict__ bA,
                      float* __restrict__ out_op, float* __restrict__ out_m,
                      float* __restrict__ out_a,
                      unsigned short* __restrict__ xcop, unsigned short* __restrict__ xcm,
                      unsigned short* __restrict__ xca) {
    int i = blockIdx.x * blockDim.x + threadIdx.x;
    if (i < I3_OP)      init_one(x_op, bP, bS, out_op, xcop, i, 63);
    else if (i < I3_M)  init_one(x_m, bO, nullptr, out_m, xcm, i - I3_OP, 31);
    else if (i < I3_A)  init_one(x_a, bA, nullptr, out_a, xca, i - I3_M, 31);
}

// ---------------------------------------------------------------------------
// All weight/bias packing in one launch.
// ---------------------------------------------------------------------------
#define PK_P   131072
#define PK_S   262144
#define PK_OL  294912
#define PK_OR  311296
#define PK_ML  327680
#define PK_MR  344064
#define PK_BP  344576
#define PK_BS  345088

__global__ void pack_all(const float* __restrict__ WlP, const float* __restrict__ WrP,
                         const float* __restrict__ WlS, const float* __restrict__ WrS,
                         const float* __restrict__ WOl, const float* __restrict__ WOr,
                         const float* __restrict__ WMl, const float* __restrict__ WMr,
                         const float* __restrict__ blP, const float* __restrict__ brP,
                         const float* __restrict__ blS, const float* __restrict__ brS,
                         unsigned short* __restrict__ BtP, unsigned short* __restrict__ BtS,
                         unsigned short* __restrict__ BtOL, unsigned short* __restrict__ BtOR,
                         unsigned short* __restrict__ BtML, unsigned short* __restrict__ BtMR,
                         float* __restrict__ biasP, float* __restrict__ biasS) {
    int i = blockIdx.x * blockDim.x + threadIdx.x;
    if (i < PK_P) {
        int n = i >> 8, k = i & 255;
        BtP[i] = f2bf((n < 256) ? WlP[k * 256 + n] : WrP[k * 256 + (n - 256)]);
    } else if (i < PK_S) {
        int j = i - PK_P; int n = j >> 8, k = j & 255;
        BtS[j] = f2bf((n < 256) ? WlS[k * 256 + n] : WrS[k * 256 + (n - 256)]);
    } else if (i < PK_OL) {
        int j = i - PK_S; int n = j >> 8, k = j & 255;
        BtOL[j] = f2bf(WOl[k * 128 + n]);
    } else if (i < PK_OR) {
        int j = i - PK_OL; int n = j >> 7, k = j & 127;
        BtOR[j] = f2bf(WOr[k * 128 + n]);
    } else if (i < PK_ML) {
        int j = i - PK_OR; int n = j >> 7, k = j & 127;
        BtML[j] = f2bf(WMl[k * 128 + n]);
    } else if (i < PK_MR) {
        int j = i - PK_ML; int n = j >> 7, k = j & 127;
        BtMR[j] = f2bf(WMr[k * 128 + n]);
    } else if (i < PK_BP) {
        int j = i - PK_MR;
        biasP[j] = (j < 256) ? blP[j] : brP[j - 256];
    } else if (i < PK_BS) {
        int j = i - PK_BP;
        biasS[j] = (j < 256) ? blS[j] : brS[j - 256];
    }
}

// ---------------------------------------------------------------------------
// MFMA bf16 GEMM: 128x128 tile, BK=64, double-buffered, XOR-swizzled LDS
// (verified rounds 5-7).
// ---------------------------------------------------------------------------
__device__ __forceinline__ void gload_lds16(const void* g, void* l) {
    __builtin_amdgcn_global_load_lds((gu32*)g, (lu32*)l, 16, 0, 0);
}

__global__ __launch_bounds__(256) void mfma_gemm(
    const unsigned short* __restrict__ A, const unsigned short* __restrict__ Bt,
    const float* __restrict__ bias, unsigned short* __restrict__ C,
    int M, int K, int ldc) {
    __shared__ unsigned short As[2][128 * 64];
    __shared__ unsigned short Bs[2][128 * 64];

    const int tid  = threadIdx.x;
    const int lane = tid & 63;
    const int wid  = tid >> 6;
    const int m0   = blockIdx.x * 128;
    const int n0   = blockIdx.y * 128;

    f32x4 acc[4][4] = {};

    const int srow   = tid >> 3;
    const int scolb  = (tid & 7) * 16;
    const int scole  = (scolb ^ ((srow & 7) << 4)) >> 1;

    int grA[4], grB[4];
#pragma unroll
    for (int i = 0; i < 4; ++i) {
        int gr = m0 + i * 32 + srow;
        grA[i] = (gr < M) ? gr : M - 1;
        grB[i] = n0 + i * 32 + srow;
    }

    const int nt = K >> 6;
    int cur = 0;

#define STAGE(buf, k0)                                                          \
    {                                                                           \
        _Pragma("unroll")                                                       \
        for (int i = 0; i < 4; ++i)                                             \
            gload_lds16(A + (size_t)grA[i] * K + (k0) + scole,                  \
                        &As[buf][i * 2048 + tid * 8]);                          \
        _Pragma("unroll")                                                       \
        for (int i = 0; i < 4; ++i)                                             \
            gload_lds16(Bt + (size_t)grB[i] * K + (k0) + scole,                 \
                        &Bs[buf][i * 2048 + tid * 8]);                          \
    }

    STAGE(0, 0)
    asm volatile("s_waitcnt vmcnt(0)" ::: "memory");
    __syncthreads();

    const int wr = (wid >> 1) * 64;
    const int wc = (wid & 1) * 64;

    for (int t = 0; t < nt; ++t) {
        if (t + 1 < nt) STAGE(cur ^ 1, (t + 1) * 64)
#pragma unroll
        for (int kh = 0; kh < 2; ++kh) {
            const int kob = kh * 64 + (lane >> 4) * 16;
            bf16x8 a[4], b[4];
#pragma unroll
            for (int mi = 0; mi < 4; ++mi) {
                const int row = wr + mi * 16 + (lane & 15);
                a[mi] = *(const bf16x8*)((const char*)As[cur] + row * 128 +
                                         (kob ^ ((row & 7) << 4)));
            }
#pragma unroll
            for (int ni = 0; ni < 4; ++ni) {
                const int row = wc + ni * 16 + (lane & 15);
                b[ni] = *(const bf16x8*)((const char*)Bs[cur] + row * 128 +
                                         (kob ^ ((row & 7) << 4)));
            }
#pragma unroll
            for (int mi = 0; mi < 4; ++mi)
#pragma unroll
                for (int ni = 0; ni < 4; ++ni)
                    acc[mi][ni] = __builtin_amdgcn_mfma_f32_16x16x32_bf16(
                        a[mi], b[ni], acc[mi][ni], 0, 0, 0);
        }
        asm volatile("s_waitcnt vmcnt(0)" ::: "memory");
        __syncthreads();
        cur ^= 1;
    }
#undef STAGE

    const int crow = (lane >> 4) * 4;
    const int ccol = lane & 15;
    float bcol[4];
#pragma unroll
    for (int ni = 0; ni < 4; ++ni) bcol[ni] = bias[n0 + wc + ni * 16 + ccol];
#pragma unroll
    for (int mi = 0; mi < 4; ++mi) {
#pragma unroll
        for (int j = 0; j < 4; ++j) {
            const int row = m0 + wr + mi * 16 + crow + j;
            if (row < M) {
                unsigned short* pc = C + (size_t)row * ldc + n0 + wc + ccol;
#pragma unroll
                for (int ni = 0; ni < 4; ++ni)
                    pc[ni * 16] = f2bf(acc[mi][ni][j] + bcol[ni]);
            }
        }
    }
}

// ---------------------------------------------------------------------------
// Small fp32 GEMM for edge features (K=8), rows permuted by eid (CSR order)
// ---------------------------------------------------------------------------
template <int K, int N, int TM>
__global__ void gemm_ef(const float* __restrict__ A, const float* __restrict__ W,
                        const int* __restrict__ eid, unsigned short* __restrict__ out) {
    __shared__ float As[TM][K];
    const int m0 = blockIdx.x * TM;
    const int tid = threadIdx.x;
    for (int idx = tid; idx < TM * K; idx += N) {
        int r = idx / K, k = idx - r * K;
        As[r][k] = A[(size_t)eid[m0 + r] * K + k];
    }
    __syncthreads();
    float acc[TM] = {};
    for (int k = 0; k < K; ++k) {
        const float w = W[k * N + tid];
#pragma unroll
        for (int r = 0; r < TM; ++r) acc[r] += As[r][k] * w;
    }
#pragma unroll
    for (int r = 0; r < TM; ++r) out[(size_t)(m0 + r) * N + tid] = f2bf(acc[r]);
}

// ---------------------------------------------------------------------------
// Batched CSR build for all 4 relations (6 launches total).
// ---------------------------------------------------------------------------
#define NB_P 49
#define NB_S 49
#define NB_O 5
#define NB_A 2
#define NTOT 107000          // 50000+50000+5000+2000
#define ETOT 660000

__global__ void zero4(int* __restrict__ p, int n) {
    int i = blockIdx.x * blockDim.x + threadIdx.x;
    if (i < n) p[i] = 0;
}

__global__ void hist4(const int* __restrict__ dP, const int* __restrict__ dS,
                      const int* __restrict__ dO, const int* __restrict__ dA,
                      int* __restrict__ cP, int* __restrict__ cS,
                      int* __restrict__ cO, int* __restrict__ cA) {
    int i = blockIdx.x * blockDim.x + threadIdx.x;
    if (i < 200000)      atomicAdd(&cP[dP[i]], 1);
    else if (i < 400000) atomicAdd(&cS[dS[i - 200000]], 1);
    else if (i < 600000) atomicAdd(&cO[dO[i - 400000]], 1);
    else if (i < ETOT)   atomicAdd(&cA[dA[i - 600000]], 1);
}

__global__ void scan_blk4(const int* __restrict__ cP, const int* __restrict__ cS,
                          const int* __restrict__ cO, const int* __restrict__ cA,
                          int* __restrict__ pP, int* __restrict__ pS,
                          int* __restrict__ pO, int* __restrict__ pA,
                          int* __restrict__ bsum) {
    __shared__ int smem[1024];
    int b = blockIdx.x;
    const int* cnt; int* ptr; int n; int bo;
    if (b < NB_P)                { cnt = cP; ptr = pP; n = 50000; bo = 0; }
    else if (b < NB_P + NB_S)    { cnt = cS; ptr = pS; n = 50000; bo = 64;  b -= NB_P; }
    else if (b < NB_P + NB_S + NB_O) { cnt = cO; ptr = pO; n = 5000; bo = 128; b -= NB_P + NB_S; }
    else                         { cnt = cA; ptr = pA; n = 2000; bo = 192; b -= NB_P + NB_S + NB_O; }
    const int tid = threadIdx.x;
    const int i = b * 1024 + tid;
    const int v = (i < n) ? cnt[i] : 0;
    smem[tid] = v;
    __syncthreads();
    for (int o = 1; o < 1024; o <<= 1) {
        int t = (tid >= o) ? smem[tid - o] : 0;
        __syncthreads();
        smem[tid] += t;
        __syncthreads();
    }
    if (i < n) ptr[i] = smem[tid] - v;
    if (tid == 1023) bsum[bo + b] = smem[1023];
}

__global__ void scan_tops4(const int* __restrict__ bsum, int* __restrict__ boff,
                           int* __restrict__ pP, int* __restrict__ pS,
                           int* __restrict__ pO, int* __restrict__ pA) {
    __shared__ int smem[1024];
    const int seg = blockIdx.x;
    const int nb = (seg < 2) ? 49 : (seg == 2 ? 5 : 2);
    const int off = seg * 64;
    int* ptr_n = (seg == 0) ? pP + 50000 : (seg == 1) ? pS + 50000
               : (seg == 2) ? pO + 5000 : pA + 2000;
    const int tid = threadIdx.x;
    const int v = (tid < nb) ? bsum[off + tid] : 0;
    smem[tid] = v;
    __syncthreads();
    for (int o = 1; o < 1024; o <<= 1) {
        int t = (tid >= o) ? smem[tid - o] : 0;
        __syncthreads();
        smem[tid] += t;
        __syncthreads();
    }
    if (tid < nb) boff[off + tid] = smem[tid] - v;
    if (tid == 1023) *ptr_n = smem[1023];
}

__global__ void scan_add4(int* __restrict__ pP, int* __restrict__ pS,
                          int* __restrict__ pO, int* __restrict__ pA,
                          const int* __restrict__ boff) {
    int i = blockIdx.x * blockDim.x + threadIdx.x;
    int* ptr; int loc; int off;
    if (i < 50000)       { ptr = pP; loc = i;          off = 0; }
    else if (i < 100000) { ptr = pS; loc = i - 50000;  off = 64; }
    else if (i < 105000) { ptr = pO; loc = i - 100000; off = 128; }
    else if (i < NTOT)   { ptr = pA; loc = i - 105000; off = 192; }
    else return;
    ptr[loc] += boff[off + (loc >> 10)];
}

__global__ void scatter4(const int* __restrict__ sP, const int* __restrict__ dP,
                         const int* __restrict__ sS, const int* __restrict__ dS,
                         const int* __restrict__ sO, const int* __restrict__ dO,
                         const int* __restrict__ sA, const int* __restrict__ dA,
                         const int* __restrict__ pP, const int* __restrict__ pS,
                         const int* __restrict__ pO, const int* __restrict__ pA,
                         int* __restrict__ uP, int* __restrict__ uS,
                         int* __restrict__ uO, int* __restrict__ uA,
                         int* __restrict__ srP, int* __restrict__ srS,
                         int* __restrict__ srO, int* __restrict__ srA,
                         int* __restrict__ eiA) {
    int i = blockIdx.x * blockDim.x + threadIdx.x;
    if (i < 200000) {
        const int d = dP[i];
        srP[pP[d] + atomicAdd(&uP[d], 1)] = sP[i];
    } else if (i < 400000) {
        const int j = i - 200000; const int d = dS[j];
        srS[pS[d] + atomicAdd(&uS[d], 1)] = sS[j];
    } else if (i < 600000) {
        const int j = i - 400000; const int d = dO[j];
        srO[pO[d] + atomicAdd(&uO[d], 1)] = sO[j];
    } else if (i < ETOT) {
        const int j = i - 600000; const int d = dA[j];
        const int pos = pA[d] + atomicAdd(&uA[d], 1);
        srA[pos] = sA[j];
        eiA[pos] = j;
    }
}

// ---------------------------------------------------------------------------
// Fused GATv2 edge pipeline, 16-lane-group version: one wave per node.
// The wave splits into 4 groups of 16 lanes; each group owns one edge of a
// 4-edge chunk (4x memory ILP), each lane owns C/16 channels.  Dot reduce =
// 4 cheap intra-row shfls (xor 1/2/4/8, DPP); chunk max/sum = 2+2 cross-group
// shfls.  Online softmax is chunked (round-6-verified math).  Group-local
// accumulators are combined once per node; group 0 does the output RMW.
// ---------------------------------------------------------------------------
template <int C, bool HAS_EF>
__global__ void csr_fused(const unsigned short* __restrict__ xl, int ldl,
                          const unsigned short* __restrict__ xr, int ldr,
                          const unsigned short* __restrict__ ef,
                          const float* __restrict__ att,
                          const int* __restrict__ ptr, const int* __restrict__ srcs,
                          float* __restrict__ out, int n) {
    const int node = blockIdx.x * (blockDim.x >> 6) + (threadIdx.x >> 6);
    if (node >= n) return;
    const int lane = threadIdx.x & 63;
    const int grp  = lane >> 4;          // edge slot within chunk (0..3)
    const int sl   = lane & 15;          // channel-group lane
    const int beg = ptr[node], end = ptr[node + 1];
    if (beg == end) return;

    constexpr int W = C / 16;            // channels per lane (16 or 8)
    const int c0 = sl * W;

    float av[W], rvf[W];
    {
        const unsigned short* pr = xr + (size_t)node * ldr + c0;
        unsigned short rv[W];
        *(uint4*)rv = *(const uint4*)pr;
        if constexpr (W == 16) *(uint4*)(rv + 8) = *(const uint4*)(pr + 8);
#pragma unroll
        for (int v4 = 0; v4 < W / 4; ++v4)
            *(float4*)(av + v4 * 4) = ((const float4*)(att + c0))[v4];
#pragma unroll
        for (int v = 0; v < W; ++v) rvf[v] = bf2f(rv[v]);
    }

    float runM = -3.0e38f, runS = 0.0f;
    float acc[W] = {};

    for (int cb = beg; cb < end; cb += 4) {
        const int j = cb + grp;
        const bool act = (j < end);
        const int js = act ? j : end - 1;
        const int s = srcs[js];

        const unsigned short* pl = xl + (size_t)s * ldl + c0;
        unsigned short lv[W];
        *(uint4*)lv = *(const uint4*)pl;
        if constexpr (W == 16) *(uint4*)(lv + 8) = *(const uint4*)(pl + 8);
        float cf[W];
#pragma unroll
        for (int v = 0; v < W; ++v) cf[v] = bf2f(lv[v]);

        float part = 0.0f;
        if constexpr (HAS_EF) {
            unsigned short efv[W];
            const unsigned short* pe = ef + (size_t)js * C + c0;
            *(uint4*)efv = *(const uint4*)pe;
            if constexpr (W == 16) *(uint4*)(efv + 8) = *(const uint4*)(pe + 8);
#pragma unroll
            for (int v = 0; v < W; ++v) {
                float m = cf[v] + rvf[v] + bf2f(efv[v]);
                m = (m >= 0.0f) ? m : 0.2f * m;
                part += m * av[v];
            }
        } else {
#pragma unroll
            for (int v = 0; v < W; ++v) {
                float m = cf[v] + rvf[v];
                m = (m >= 0.0f) ? m : 0.2f * m;
                part += m * av[v];
            }
        }
        // intra-group reduce (16 lanes): xor 1/2/4/8 -> DPP, cheap
        part += __shfl_xor(part, 1, 64);
        part += __shfl_xor(part, 2, 64);
        part += __shfl_xor(part, 4, 64);
        part += __shfl_xor(part, 8, 64);
        if (!act) part = -3.0e38f;

        // chunk max across 4 groups (wave-uniform after 2 steps)
        float cm = fmaxf(part, __shfl_xor(part, 16, 64));
        cm = fmaxf(cm, __shfl_xor(cm, 32, 64));

        if (cm > runM) {                 // wave-uniform branch
            const float sc = __expf(runM - cm);
            runS *= sc;
#pragma unroll
            for (int v = 0; v < W; ++v) acc[v] *= sc;
            runM = cm;
        }
        const float w = act ? __expf(part - runM) : 0.0f;
        float cs = w + __shfl_xor(w, 16, 64);
        cs += __shfl_xor(cs, 32, 64);
        runS += cs;
#pragma unroll
        for (int v = 0; v < W; ++v) acc[v] += w * cf[v];
    }

    // combine group accumulators (channel layout identical across groups)
#pragma unroll
    for (int v = 0; v < W; ++v) acc[v] += __shfl_xor(acc[v], 16, 64);
#pragma unroll
    for (int v = 0; v < W; ++v) acc[v] += __shfl_xor(acc[v], 32, 64);

    const float inv = 1.0f / fmaxf(runS, 1e-16f);
    if (grp == 0) {
        float* po = out + (size_t)node * C + c0;
#pragma unroll
        for (int v4 = 0; v4 < W / 4; ++v4) {
            float4 o = ((float4*)po)[v4];
            o.x += acc[v4 * 4 + 0] * inv;
            o.y += acc[v4 * 4 + 1] * inv;
            o.z += acc[v4 * 4 + 2] * inv;
            o.w += acc[v4 * 4 + 3] * inv;
            ((float4*)po)[v4] = o;
        }
    }
}

// ---------------------------------------------------------------------------
// Workspace layout (float slots).  Ends ~83.5 MB (ws >= 103.6 MB proven).
// ---------------------------------------------------------------------------
#define F_H      0
#define F_XCOP   12800000
#define F_XCM    19200000
#define F_XCA    19520000
#define F_BTP    19648000
#define F_BTS    19713536
#define F_BTOL   19779072
#define F_BTOR   19795456
#define F_BTML   19803648
#define F_BTMR   19811840
#define F_BIASP  19820032
#define F_BIASS  19820544
#define F_CNT4   19821056    // int[107000]
#define F_CUR4   19928056    // int[107000]
#define F_BSUM   20035056    // int[256]
#define F_BOFF   20035312    // int[256]
#define F_PTR_P  20035568    // int[50001]
#define F_SRC_P  20085569    // int[200000]
#define F_PTR_S  20285569    // int[50001]
#define F_SRC_S  20335570    // int[200000]
#define F_PTR_O  20535570    // int[5001]
#define F_SRC_O  20540571    // int[200000]
#define F_PTR_A  20740571    // int[2001]
#define F_SRC_A  20742572    // int[60000]
#define F_EID_A  20802572    // int[60000]  -> ends 20,862,572 floats = 83.5 MB

extern "C" void kernel_launch(void* const* d_in, const int* in_sizes, int n_in,
                              void* d_out, int out_size, void* d_ws, size_t ws_size,
                              hipStream_t stream) {
    const float* x_op    = (const float*)d_in[0];
    const float* x_m     = (const float*)d_in[1];
    const float* x_a     = (const float*)d_in[2];
    const int*   ei_pred = (const int*)d_in[3];
    const int*   ei_succ = (const int*)d_in[4];
    const int*   src_o2m = (const int*)d_in[5];
    const int*   dst_o2m = (const int*)d_in[6];
    const int*   src_m2a = (const int*)d_in[7];
    const int*   dst_m2a = (const int*)d_in[8];
    const float* ea_m2a  = (const float*)d_in[9];

    const float* Wl_pred = (const float*)d_in[10];
    const float* bl_pred = (const float*)d_in[11];
    const float* Wr_pred = (const float*)d_in[12];
    const float* br_pred = (const float*)d_in[13];
    const float* att_pred= (const float*)d_in[14];
    const float* b_pred  = (const float*)d_in[15];

    const float* Wl_succ = (const float*)d_in[16];
    const float* bl_succ = (const float*)d_in[17];
    const float* Wr_succ = (const float*)d_in[18];
    const float* br_succ = (const float*)d_in[19];
    const float* att_succ= (const float*)d_in[20];
    const float* b_succ  = (const float*)d_in[21];

    const float* Wl_o2m  = (const float*)d_in[22];
    const float* bl_o2m  = (const float*)d_in[23];
    const float* Wr_o2m  = (const float*)d_in[24];
    const float* br_o2m  = (const float*)d_in[25];
    const float* att_o2m = (const float*)d_in[26];
    const float* b_o2m   = (const float*)d_in[27];

    const float* Wl_m2a  = (const float*)d_in[28];
    const float* bl_m2a  = (const float*)d_in[29];
    const float* Wr_m2a  = (const float*)d_in[30];
    const float* br_m2a  = (const float*)d_in[31];
    const float* att_m2a = (const float*)d_in[32];
    const float* b_m2a   = (const float*)d_in[33];
    const float* We_m2a  = (const float*)d_in[34];

    float* ws = (float*)d_ws;
    unsigned short* H     = (unsigned short*)(ws + F_H);
    unsigned short* xc_op = (unsigned short*)(ws + F_XCOP);
    unsigned short* xc_m  = (unsigned short*)(ws + F_XCM);
    unsigned short* xc_a  = (unsigned short*)(ws + F_XCA);
    unsigned short* BtP   = (unsigned short*)(ws + F_BTP);
    unsigned short* BtS   = (unsigned short*)(ws + F_BTS);
    unsigned short* BtOL  = (unsigned short*)(ws + F_BTOL);
    unsigned short* BtOR  = (unsigned short*)(ws + F_BTOR);
    unsigned short* BtML  = (unsigned short*)(ws + F_BTML);
    unsigned short* BtMR  = (unsigned short*)(ws + F_BTMR);
    float* biasP = ws + F_BIASP;
    float* biasS = ws + F_BIASS;
    int* cntP = (int*)(ws + F_CNT4);
    int* cntS = cntP + 50000;
    int* cntO = cntP + 100000;
    int* cntA = cntP + 105000;
    int* curP = (int*)(ws + F_CUR4);
    int* curS = curP + 50000;
    int* curO = curP + 100000;
    int* curA = curP + 105000;
    int* bsum = (int*)(ws + F_BSUM);
    int* boff = (int*)(ws + F_BOFF);
    int* ptrP = (int*)(ws + F_PTR_P); int* srcP = (int*)(ws + F_SRC_P);
    int* ptrS = (int*)(ws + F_PTR_S); int* srcS = (int*)(ws + F_SRC_S);
    int* ptrO = (int*)(ws + F_PTR_O); int* srcO = (int*)(ws + F_SRC_O);
    int* ptrA = (int*)(ws + F_PTR_A); int* srcA = (int*)(ws + F_SRC_A);
    int* eidA = (int*)(ws + F_EID_A);

    float* out_op = (float*)d_out + OUT_OP_OFF;
    float* out_m  = (float*)d_out + OUT_M_OFF;
    float* out_a  = (float*)d_out + OUT_A_OFF;

    // ---- batched CSR build (6 launches) ----
    zero4<<<(2 * NTOT + 255) / 256, 256, 0, stream>>>(cntP, 2 * NTOT);
    hist4<<<(ETOT + 255) / 256, 256, 0, stream>>>(ei_pred + E_OO, ei_succ + E_OO,
                                                  dst_o2m, dst_m2a, cntP, cntS, cntO, cntA);
    scan_blk4<<<NB_P + NB_S + NB_O + NB_A, 1024, 0, stream>>>(cntP, cntS, cntO, cntA,
                                                              ptrP, ptrS, ptrO, ptrA, bsum);
    scan_tops4<<<4, 1024, 0, stream>>>(bsum, boff, ptrP, ptrS, ptrO, ptrA);
    scan_add4<<<(NTOT + 255) / 256, 256, 0, stream>>>(ptrP, ptrS, ptrO, ptrA, boff);
    scatter4<<<(ETOT + 255) / 256, 256, 0, stream>>>(
        ei_pred, ei_pred + E_OO, ei_succ, ei_succ + E_OO,
        src_o2m, dst_o2m, src_m2a, dst_m2a,
        ptrP, ptrS, ptrO, ptrA, curP, curS, curO, curA,
        srcP, srcS, srcO, srcA, eidA);

    // ---- fused init + pack (2 launches) ----
    init3<<<(I3_A + 255) / 256, 256, 0, stream>>>(x_op, x_m, x_a, b_pred, b_succ, b_o2m, b_m2a,
                                                  out_op, out_m, out_a, xc_op, xc_m, xc_a);
    pack_all<<<(PK_BS + 255) / 256, 256, 0, stream>>>(
        Wl_pred, Wr_pred, Wl_succ, Wr_succ, Wl_o2m, Wr_o2m, Wl_m2a, Wr_m2a,
        bl_pred, br_pred, bl_succ, br_succ,
        BtP, BtS, BtOL, BtOR, BtML, BtMR, biasP, biasS);

    const int MT_OP = (N_OP + 127) / 128;
    const int MT_M  = (N_M + 127) / 128;
    const int MT_A  = (N_A + 127) / 128;

    // ---------------- conv 1: pred (op->op, C=256), H = [50000][512] ----------------
    mfma_gemm<<<dim3(MT_OP, 4), 256, 0, stream>>>(xc_op, BtP, biasP, H, N_OP, 256, 512);
    csr_fused<256, false><<<(N_OP + 3) / 4, 256, 0, stream>>>(H, 512, H + 256, 512, nullptr,
                                                              att_pred, ptrP, srcP, out_op, N_OP);

    // ---------------- conv 2: succ ----------------
    mfma_gemm<<<dim3(MT_OP, 4), 256, 0, stream>>>(xc_op, BtS, biasS, H, N_OP, 256, 512);
    csr_fused<256, false><<<(N_OP + 3) / 4, 256, 0, stream>>>(H, 512, H + 256, 512, nullptr,
                                                              att_succ, ptrS, srcS, out_op, N_OP);

    // ---------------- conv 3: o2m (op->machine, C=128) ----------------
    {
        unsigned short* xlb = H;                 // [50000][128]
        unsigned short* xrb = H + 6400000;       // [5000][128]
        mfma_gemm<<<dim3(MT_OP, 1), 256, 0, stream>>>(xc_op, BtOL, bl_o2m, xlb, N_OP, 256, 128);
        mfma_gemm<<<dim3(MT_M, 1), 256, 0, stream>>>(xc_m, BtOR, br_o2m, xrb, N_M, 128, 128);
        csr_fused<128, false><<<(N_M + 3) / 4, 256, 0, stream>>>(xlb, 128, xrb, 128, nullptr,
                                                                 att_o2m, ptrO, srcO, out_m, N_M);
    }

    // ---------------- conv 4: m2a (machine->agv, C=128, edge feats) ----------------
    {
        unsigned short* xlb = H;                 // [5000][128]
        unsigned short* xrb = H + 1000000;       // [2000][128]
        unsigned short* efb = H + 2000000;       // [60000][128] CSR-slot order
        mfma_gemm<<<dim3(MT_M, 1), 256, 0, stream>>>(xc_m, BtML, bl_m2a, xlb, N_M, 128, 128);
        mfma_gemm<<<dim3(MT_A, 1), 256, 0, stream>>>(xc_a, BtMR, br_m2a, xrb, N_A, 128, 128);
        gemm_ef<8, 128, 4><<<E_MA / 4, 128, 0, stream>>>(ea_m2a, We_m2a, eidA, efb);
        csr_fused<128, true><<<(N_A + 3) / 4, 256, 0, stream>>>(xlb, 128, xrb, 128, efb,
                                                                att_m2a, ptrA, srcA, out_a, N_A);
    }
}

// Round 9
// 352.980 us; speedup vs baseline: 5.6914x; 1.0737x over previous
//
#include <hip/hip_runtime.h>

// ---------------------------------------------------------------------------
// Problem constants (fixed by setup_inputs)
// ---------------------------------------------------------------------------
#define N_OP   50000
#define N_M    5000
#define N_A    2000
#define C_OP   256
#define C_M    128
#define C_A    128
#define E_OO   200000
#define E_OM   200000
#define E_MA   60000
#define E_DIM  8

#define OUT_OP_OFF 0
#define OUT_M_OFF  (N_OP * C_OP)
#define OUT_A_OFF  (N_OP * C_OP + N_M * C_M)

typedef short bf16x8 __attribute__((ext_vector_type(8)));
typedef float f32x4 __attribute__((ext_vector_type(4)));
typedef __attribute__((address_space(1))) const unsigned gu32;
typedef __attribute__((address_space(3))) unsigned lu32;

__device__ __forceinline__ unsigned short f2bf(float f) {
    unsigned u = __float_as_uint(f);
    unsigned r = (u + 0x7FFFu + ((u >> 16) & 1u)) >> 16;
    return (unsigned short)r;
}
__device__ __forceinline__ float bf2f(unsigned short h) {
    return __uint_as_float(((unsigned)h) << 16);
}

// ---------------------------------------------------------------------------
// Fused residual-init + bf16 conversion for all 3 node types (1 launch).
// ---------------------------------------------------------------------------
__device__ __forceinline__ void init_one(const float* __restrict__ x,
                                         const float* __restrict__ b1,
                                         const float* __restrict__ b2,
                                         float* __restrict__ out,
                                         unsigned short* __restrict__ xc,
                                         int i, int cmask) {
    float4 v = ((const float4*)x)[i];
    const int cb = i & cmask;
    float4 b = ((const float4*)b1)[cb];
    if (b2) {
        float4 t = ((const float4*)b2)[cb];
        b.x += t.x; b.y += t.y; b.z += t.z; b.w += t.w;
    }
    float4 o;
    o.x = v.x + b.x; o.y = v.y + b.y; o.z = v.z + b.z; o.w = v.w + b.w;
    ((float4*)out)[i] = o;
    ushort4 r;
    r.x = f2bf(v.x); r.y = f2bf(v.y); r.z = f2bf(v.z); r.w = f2bf(v.w);
    ((ushort4*)xc)[i] = r;
}

#define I3_OP (N_OP * C_OP / 4)                 // 3,200,000
#define I3_M  (I3_OP + N_M * C_M / 4)           // 3,360,000
#define I3_A  (I3_M + N_A * C_A / 4)            // 3,424,000

__global__ void init3(const float* __restrict__ x_op, const float* __restrict__ x_m,
                      const float* __restrict__ x_a,
                      const float* __restrict__ bP, const float* __restrict__ bS,
                      const float* __restrict__ bO, const float* __restrict__ bA,
                      float* __restrict__ out_op, float* __restrict__ out_m,
                      float* __restrict__ out_a,
                      unsigned short* __restrict__ xcop, unsigned short* __restrict__ xcm,
                      unsigned short* __restrict__ xca) {
    int i = blockIdx.x * blockDim.x + threadIdx.x;
    if (i < I3_OP)      init_one(x_op, bP, bS, out_op, xcop, i, 63);
    else if (i < I3_M)  init_one(x_m, bO, nullptr, out_m, xcm, i - I3_OP, 31);
    else if (i < I3_A)  init_one(x_a, bA, nullptr, out_a, xca, i - I3_M, 31);
}

// ---------------------------------------------------------------------------
// All weight/bias packing in one launch.
// ---------------------------------------------------------------------------
#define PK_P   131072
#define PK_S   262144
#define PK_OL  294912
#define PK_OR  311296
#define PK_ML  327680
#define PK_MR  344064
#define PK_BP  344576
#define PK_BS  345088

__global__ void pack_all(const float* __restrict__ WlP, const float* __restrict__ WrP,
                         const float* __restrict__ WlS, const float* __restrict__ WrS,
                         const float* __restrict__ WOl, const float* __restrict__ WOr,
                         const float* __restrict__ WMl, const float* __restrict__ WMr,
                         const float* __restrict__ blP, const float* __restrict__ brP,
                         const float* __restrict__ blS, const float* __restrict__ brS,
                         unsigned short* __restrict__ BtP, unsigned short* __restrict__ BtS,
                         unsigned short* __restrict__ BtOL, unsigned short* __restrict__ BtOR,
                         unsigned short* __restrict__ BtML, unsigned short* __restrict__ BtMR,
                         float* __restrict__ biasP, float* __restrict__ biasS) {
    int i = blockIdx.x * blockDim.x + threadIdx.x;
    if (i < PK_P) {
        int n = i >> 8, k = i & 255;
        BtP[i] = f2bf((n < 256) ? WlP[k * 256 + n] : WrP[k * 256 + (n - 256)]);
    } else if (i < PK_S) {
        int j = i - PK_P; int n = j >> 8, k = j & 255;
        BtS[j] = f2bf((n < 256) ? WlS[k * 256 + n] : WrS[k * 256 + (n - 256)]);
    } else if (i < PK_OL) {
        int j = i - PK_S; int n = j >> 8, k = j & 255;
        BtOL[j] = f2bf(WOl[k * 128 + n]);
    } else if (i < PK_OR) {
        int j = i - PK_OL; int n = j >> 7, k = j & 127;
        BtOR[j] = f2bf(WOr[k * 128 + n]);
    } else if (i < PK_ML) {
        int j = i - PK_OR; int n = j >> 7, k = j & 127;
        BtML[j] = f2bf(WMl[k * 128 + n]);
    } else if (i < PK_MR) {
        int j = i - PK_ML; int n = j >> 7, k = j & 127;
        BtMR[j] = f2bf(WMr[k * 128 + n]);
    } else if (i < PK_BP) {
        int j = i - PK_MR;
        biasP[j] = (j < 256) ? blP[j] : brP[j - 256];
    } else if (i < PK_BS) {
        int j = i - PK_BP;
        biasS[j] = (j < 256) ? blS[j] : brS[j - 256];
    }
}

// ---------------------------------------------------------------------------
// MFMA bf16 GEMM: 128x128 tile, BK=64, double-buffered, XOR-swizzled LDS
// (verified rounds 5-8).
// ---------------------------------------------------------------------------
__device__ __forceinline__ void gload_lds16(const void* g, void* l) {
    __builtin_amdgcn_global_load_lds((gu32*)g, (lu32*)l, 16, 0, 0);
}

__global__ __launch_bounds__(256) void mfma_gemm(
    const unsigned short* __restrict__ A, const unsigned short* __restrict__ Bt,
    const float* __restrict__ bias, unsigned short* __restrict__ C,
    int M, int K, int ldc) {
    __shared__ unsigned short As[2][128 * 64];
    __shared__ unsigned short Bs[2][128 * 64];

    const int tid  = threadIdx.x;
    const int lane = tid & 63;
    const int wid  = tid >> 6;
    const int m0   = blockIdx.x * 128;
    const int n0   = blockIdx.y * 128;

    f32x4 acc[4][4] = {};

    const int srow   = tid >> 3;
    const int scolb  = (tid & 7) * 16;
    const int scole  = (scolb ^ ((srow & 7) << 4)) >> 1;

    int grA[4], grB[4];
#pragma unroll
    for (int i = 0; i < 4; ++i) {
        int gr = m0 + i * 32 + srow;
        grA[i] = (gr < M) ? gr : M - 1;
        grB[i] = n0 + i * 32 + srow;
    }

    const int nt = K >> 6;
    int cur = 0;

#define STAGE(buf, k0)                                                          \
    {                                                                           \
        _Pragma("unroll")                                                       \
        for (int i = 0; i < 4; ++i)                                             \
            gload_lds16(A + (size_t)grA[i] * K + (k0) + scole,                  \
                        &As[buf][i * 2048 + tid * 8]);                          \
        _Pragma("unroll")                                                       \
        for (int i = 0; i < 4; ++i)                                             \
            gload_lds16(Bt + (size_t)grB[i] * K + (k0) + scole,                 \
                        &Bs[buf][i * 2048 + tid * 8]);                          \
    }

    STAGE(0, 0)
    asm volatile("s_waitcnt vmcnt(0)" ::: "memory");
    __syncthreads();

    const int wr = (wid >> 1) * 64;
    const int wc = (wid & 1) * 64;

    for (int t = 0; t < nt; ++t) {
        if (t + 1 < nt) STAGE(cur ^ 1, (t + 1) * 64)
#pragma unroll
        for (int kh = 0; kh < 2; ++kh) {
            const int kob = kh * 64 + (lane >> 4) * 16;
            bf16x8 a[4], b[4];
#pragma unroll
            for (int mi = 0; mi < 4; ++mi) {
                const int row = wr + mi * 16 + (lane & 15);
                a[mi] = *(const bf16x8*)((const char*)As[cur] + row * 128 +
                                         (kob ^ ((row & 7) << 4)));
            }
#pragma unroll
            for (int ni = 0; ni < 4; ++ni) {
                const int row = wc + ni * 16 + (lane & 15);
                b[ni] = *(const bf16x8*)((const char*)Bs[cur] + row * 128 +
                                         (kob ^ ((row & 7) << 4)));
            }
#pragma unroll
            for (int mi = 0; mi < 4; ++mi)
#pragma unroll
                for (int ni = 0; ni < 4; ++ni)
                    acc[mi][ni] = __builtin_amdgcn_mfma_f32_16x16x32_bf16(
                        a[mi], b[ni], acc[mi][ni], 0, 0, 0);
        }
        asm volatile("s_waitcnt vmcnt(0)" ::: "memory");
        __syncthreads();
        cur ^= 1;
    }
#undef STAGE

    const int crow = (lane >> 4) * 4;
    const int ccol = lane & 15;
    float bcol[4];
#pragma unroll
    for (int ni = 0; ni < 4; ++ni) bcol[ni] = bias[n0 + wc + ni * 16 + ccol];
#pragma unroll
    for (int mi = 0; mi < 4; ++mi) {
#pragma unroll
        for (int j = 0; j < 4; ++j) {
            const int row = m0 + wr + mi * 16 + crow + j;
            if (row < M) {
                unsigned short* pc = C + (size_t)row * ldc + n0 + wc + ccol;
#pragma unroll
                for (int ni = 0; ni < 4; ++ni)
                    pc[ni * 16] = f2bf(acc[mi][ni][j] + bcol[ni]);
            }
        }
    }
}

// ---------------------------------------------------------------------------
// Small fp32 GEMM for edge features (K=8), rows permuted by eid (CSR order)
// ---------------------------------------------------------------------------
template <int K, int N, int TM>
__global__ void gemm_ef(const float* __restrict__ A, const float* __restrict__ W,
                        const int* __restrict__ eid, unsigned short* __restrict__ out) {
    __shared__ float As[TM][K];
    const int m0 = blockIdx.x * TM;
    const int tid = threadIdx.x;
    for (int idx = tid; idx < TM * K; idx += N) {
        int r = idx / K, k = idx - r * K;
        As[r][k] = A[(size_t)eid[m0 + r] * K + k];
    }
    __syncthreads();
    float acc[TM] = {};
    for (int k = 0; k < K; ++k) {
        const float w = W[k * N + tid];
#pragma unroll
        for (int r = 0; r < TM; ++r) acc[r] += As[r][k] * w;
    }
#pragma unroll
    for (int r = 0; r < TM; ++r) out[(size_t)(m0 + r) * N + tid] = f2bf(acc[r]);
}

// ---------------------------------------------------------------------------
// Batched CSR build for all 4 relations (6 launches total).
// ---------------------------------------------------------------------------
#define NB_P 49
#define NB_S 49
#define NB_O 5
#define NB_A 2
#define NTOT 107000          // 50000+50000+5000+2000
#define ETOT 660000

__global__ void zero4(int* __restrict__ p, int n) {
    int i = blockIdx.x * blockDim.x + threadIdx.x;
    if (i < n) p[i] = 0;
}

__global__ void hist4(const int* __restrict__ dP, const int* __restrict__ dS,
                      const int* __restrict__ dO, const int* __restrict__ dA,
                      int* __restrict__ cP, int* __restrict__ cS,
                      int* __restrict__ cO, int* __restrict__ cA) {
    int i = blockIdx.x * blockDim.x + threadIdx.x;
    if (i < 200000)      atomicAdd(&cP[dP[i]], 1);
    else if (i < 400000) atomicAdd(&cS[dS[i - 200000]], 1);
    else if (i < 600000) atomicAdd(&cO[dO[i - 400000]], 1);
    else if (i < ETOT)   atomicAdd(&cA[dA[i - 600000]], 1);
}

__global__ void scan_blk4(const int* __restrict__ cP, const int* __restrict__ cS,
                          const int* __restrict__ cO, const int* __restrict__ cA,
                          int* __restrict__ pP, int* __restrict__ pS,
                          int* __restrict__ pO, int* __restrict__ pA,
                          int* __restrict__ bsum) {
    __shared__ int smem[1024];
    int b = blockIdx.x;
    const int* cnt; int* ptr; int n; int bo;
    if (b < NB_P)                { cnt = cP; ptr = pP; n = 50000; bo = 0; }
    else if (b < NB_P + NB_S)    { cnt = cS; ptr = pS; n = 50000; bo = 64;  b -= NB_P; }
    else if (b < NB_P + NB_S + NB_O) { cnt = cO; ptr = pO; n = 5000; bo = 128; b -= NB_P + NB_S; }
    else                         { cnt = cA; ptr = pA; n = 2000; bo = 192; b -= NB_P + NB_S + NB_O; }
    const int tid = threadIdx.x;
    const int i = b * 1024 + tid;
    const int v = (i < n) ? cnt[i] : 0;
    smem[tid] = v;
    __syncthreads();
    for (int o = 1; o < 1024; o <<= 1) {
        int t = (tid >= o) ? smem[tid - o] : 0;
        __syncthreads();
        smem[tid] += t;
        __syncthreads();
    }
    if (i < n) ptr[i] = smem[tid] - v;
    if (tid == 1023) bsum[bo + b] = smem[1023];
}

__global__ void scan_tops4(const int* __restrict__ bsum, int* __restrict__ boff,
                           int* __restrict__ pP, int* __restrict__ pS,
                           int* __restrict__ pO, int* __restrict__ pA) {
    __shared__ int smem[1024];
    const int seg = blockIdx.x;
    const int nb = (seg < 2) ? 49 : (seg == 2 ? 5 : 2);
    const int off = seg * 64;
    int* ptr_n = (seg == 0) ? pP + 50000 : (seg == 1) ? pS + 50000
               : (seg == 2) ? pO + 5000 : pA + 2000;
    const int tid = threadIdx.x;
    const int v = (tid < nb) ? bsum[off + tid] : 0;
    smem[tid] = v;
    __syncthreads();
    for (int o = 1; o < 1024; o <<= 1) {
        int t = (tid >= o) ? smem[tid - o] : 0;
        __syncthreads();
        smem[tid] += t;
        __syncthreads();
    }
    if (tid < nb) boff[off + tid] = smem[tid] - v;
    if (tid == 1023) *ptr_n = smem[1023];
}

__global__ void scan_add4(int* __restrict__ pP, int* __restrict__ pS,
                          int* __restrict__ pO, int* __restrict__ pA,
                          const int* __restrict__ boff) {
    int i = blockIdx.x * blockDim.x + threadIdx.x;
    int* ptr; int loc; int off;
    if (i < 50000)       { ptr = pP; loc = i;          off = 0; }
    else if (i < 100000) { ptr = pS; loc = i - 50000;  off = 64; }
    else if (i < 105000) { ptr = pO; loc = i - 100000; off = 128; }
    else if (i < NTOT)   { ptr = pA; loc = i - 105000; off = 192; }
    else return;
    ptr[loc] += boff[off + (loc >> 10)];
}

__global__ void scatter4(const int* __restrict__ sP, const int* __restrict__ dP,
                         const int* __restrict__ sS, const int* __restrict__ dS,
                         const int* __restrict__ sO, const int* __restrict__ dO,
                         const int* __restrict__ sA, const int* __restrict__ dA,
                         const int* __restrict__ pP, const int* __restrict__ pS,
                         const int* __restrict__ pO, const int* __restrict__ pA,
                         int* __restrict__ uP, int* __restrict__ uS,
                         int* __restrict__ uO, int* __restrict__ uA,
                         int* __restrict__ srP, int* __restrict__ srS,
                         int* __restrict__ srO, int* __restrict__ srA,
                         int* __restrict__ eiA) {
    int i = blockIdx.x * blockDim.x + threadIdx.x;
    if (i < 200000) {
        const int d = dP[i];
        srP[pP[d] + atomicAdd(&uP[d], 1)] = sP[i];
    } else if (i < 400000) {
        const int j = i - 200000; const int d = dS[j];
        srS[pS[d] + atomicAdd(&uS[d], 1)] = sS[j];
    } else if (i < 600000) {
        const int j = i - 400000; const int d = dO[j];
        srO[pO[d] + atomicAdd(&uO[d], 1)] = sO[j];
    } else if (i < ETOT) {
        const int j = i - 600000; const int d = dA[j];
        const int pos = pA[d] + atomicAdd(&uA[d], 1);
        srA[pos] = sA[j];
        eiA[pos] = j;
    }
}

// ---------------------------------------------------------------------------
// csr_serial: round-7-verified single-pass online softmax, one wave per node,
// one edge at a time with next-row prefetch.  Best for LOW degree (op->op
// convs, mean deg 4): VGPR 20, minimal per-edge footprint.
// ---------------------------------------------------------------------------
template <int C, bool HAS_EF>
__global__ void csr_serial(const unsigned short* __restrict__ xl, int ldl,
                           const unsigned short* __restrict__ xr, int ldr,
                           const unsigned short* __restrict__ ef,
                           const float* __restrict__ att,
                           const int* __restrict__ ptr, const int* __restrict__ srcs,
                           float* __restrict__ out, int n) {
    const int node = blockIdx.x * (blockDim.x >> 6) + (threadIdx.x >> 6);
    if (node >= n) return;
    const int lane = threadIdx.x & 63;
    const int beg = ptr[node], end = ptr[node + 1];
    if (beg == end) return;

    constexpr int V = C / 64;
    const int c0 = lane * V;

    float av[V], rvf[V];
    {
        const unsigned short* pr = xr + (size_t)node * ldr + c0;
        unsigned short rv[V];
        if constexpr (V == 4) *(uint2*)rv = *(const uint2*)pr;
        else                  *(unsigned*)rv = *(const unsigned*)pr;
#pragma unroll
        for (int v = 0; v < V; ++v) { rvf[v] = bf2f(rv[v]); av[v] = att[c0 + v]; }
    }

    float runM = -3.0e38f, runS = 0.0f;
    float acc[V] = {};

    unsigned short lv[V];
    {
        const unsigned short* pl = xl + (size_t)srcs[beg] * ldl + c0;
        if constexpr (V == 4) *(uint2*)lv = *(const uint2*)pl;
        else                  *(unsigned*)lv = *(const unsigned*)pl;
    }

    for (int j = beg; j < end; ++j) {
        float cf[V];
#pragma unroll
        for (int v = 0; v < V; ++v) cf[v] = bf2f(lv[v]);
        if (j + 1 < end) {                      // prefetch next row
            const unsigned short* pl = xl + (size_t)srcs[j + 1] * ldl + c0;
            if constexpr (V == 4) *(uint2*)lv = *(const uint2*)pl;
            else                  *(unsigned*)lv = *(const unsigned*)pl;
        }

        float part = 0.0f;
        if constexpr (HAS_EF) {
            unsigned short efv[V];
            const unsigned short* pe = ef + (size_t)j * C + c0;
            if constexpr (V == 4) *(uint2*)efv = *(const uint2*)pe;
            else                  *(unsigned*)efv = *(const unsigned*)pe;
#pragma unroll
            for (int v = 0; v < V; ++v) {
                float m = cf[v] + rvf[v] + bf2f(efv[v]);
                m = (m >= 0.0f) ? m : 0.2f * m;
                part += m * av[v];
            }
        } else {
#pragma unroll
            for (int v = 0; v < V; ++v) {
                float m = cf[v] + rvf[v];
                m = (m >= 0.0f) ? m : 0.2f * m;
                part += m * av[v];
            }
        }
#pragma unroll
        for (int o = 32; o > 0; o >>= 1) part += __shfl_xor(part, o, 64);

        float w;
        if (part > runM) {                      // wave-uniform branch
            const float sc = __expf(runM - part);
            runS *= sc;
#pragma unroll
            for (int v = 0; v < V; ++v) acc[v] *= sc;
            runM = part;
            w = 1.0f;
        } else {
            w = __expf(part - runM);
        }
        runS += w;
#pragma unroll
        for (int v = 0; v < V; ++v) acc[v] += w * cf[v];
    }

    const float inv = 1.0f / fmaxf(runS, 1e-16f);
    float* po = out + (size_t)node * C + c0;
    if constexpr (V == 4) {
        float4 o = *(float4*)po;
        o.x += acc[0] * inv; o.y += acc[1] * inv;
        o.z += acc[2] * inv; o.w += acc[3] * inv;
        *(float4*)po = o;
    } else {
        float2 o = *(float2*)po;
        o.x += acc[0] * inv; o.y += acc[1] * inv;
        *(float2*)po = o;
    }
}

// ---------------------------------------------------------------------------
// csr_grp: round-8-verified 16-lane-group version (4 edges in flight), one
// wave per node.  Best for HIGH degree (o2m deg~40, m2a deg~30): cuts the
// serial per-edge chain 4x.
// ---------------------------------------------------------------------------
template <int C, bool HAS_EF>
__global__ void csr_grp(const unsigned short* __restrict__ xl, int ldl,
                        const unsigned short* __restrict__ xr, int ldr,
                        const unsigned short* __restrict__ ef,
                        const float* __restrict__ att,
                        const int* __restrict__ ptr, const int* __restrict__ srcs,
                        float* __restrict__ out, int n) {
    const int node = blockIdx.x * (blockDim.x >> 6) + (threadIdx.x >> 6);
    if (node >= n) return;
    const int lane = threadIdx.x & 63;
    const int grp  = lane >> 4;          // edge slot within chunk (0..3)
    const int sl   = lane & 15;          // channel-group lane
    const int beg = ptr[node], end = ptr[node + 1];
    if (beg == end) return;

    constexpr int W = C / 16;            // channels per lane (8 for C=128)
    const int c0 = sl * W;

    float av[W], rvf[W];
    {
        const unsigned short* pr = xr + (size_t)node * ldr + c0;
        unsigned short rv[W];
        *(uint4*)rv = *(const uint4*)pr;
        if constexpr (W == 16) *(uint4*)(rv + 8) = *(const uint4*)(pr + 8);
#pragma unroll
        for (int v4 = 0; v4 < W / 4; ++v4)
            *(float4*)(av + v4 * 4) = ((const float4*)(att + c0))[v4];
#pragma unroll
        for (int v = 0; v < W; ++v) rvf[v] = bf2f(rv[v]);
    }

    float runM = -3.0e38f, runS = 0.0f;
    float acc[W] = {};

    for (int cb = beg; cb < end; cb += 4) {
        const int j = cb + grp;
        const bool act = (j < end);
        const int js = act ? j : end - 1;
        const int s = srcs[js];

        const unsigned short* pl = xl + (size_t)s * ldl + c0;
        unsigned short lv[W];
        *(uint4*)lv = *(const uint4*)pl;
        if constexpr (W == 16) *(uint4*)(lv + 8) = *(const uint4*)(pl + 8);
        float cf[W];
#pragma unroll
        for (int v = 0; v < W; ++v) cf[v] = bf2f(lv[v]);

        float part = 0.0f;
        if constexpr (HAS_EF) {
            unsigned short efv[W];
            const unsigned short* pe = ef + (size_t)js * C + c0;
            *(uint4*)efv = *(const uint4*)pe;
            if constexpr (W == 16) *(uint4*)(efv + 8) = *(const uint4*)(pe + 8);
#pragma unroll
            for (int v = 0; v < W; ++v) {
                float m = cf[v] + rvf[v] + bf2f(efv[v]);
                m = (m >= 0.0f) ? m : 0.2f * m;
                part += m * av[v];
            }
        } else {
#pragma unroll
            for (int v = 0; v < W; ++v) {
                float m = cf[v] + rvf[v];
                m = (m >= 0.0f) ? m : 0.2f * m;
                part += m * av[v];
            }
        }
        part += __shfl_xor(part, 1, 64);
        part += __shfl_xor(part, 2, 64);
        part += __shfl_xor(part, 4, 64);
        part += __shfl_xor(part, 8, 64);
        if (!act) part = -3.0e38f;

        float cm = fmaxf(part, __shfl_xor(part, 16, 64));
        cm = fmaxf(cm, __shfl_xor(cm, 32, 64));

        if (cm > runM) {                 // wave-uniform branch
            const float sc = __expf(runM - cm);
            runS *= sc;
#pragma unroll
            for (int v = 0; v < W; ++v) acc[v] *= sc;
            runM = cm;
        }
        const float w = act ? __expf(part - runM) : 0.0f;
        float cs = w + __shfl_xor(w, 16, 64);
        cs += __shfl_xor(cs, 32, 64);
        runS += cs;
#pragma unroll
        for (int v = 0; v < W; ++v) acc[v] += w * cf[v];
    }

#pragma unroll
    for (int v = 0; v < W; ++v) acc[v] += __shfl_xor(acc[v], 16, 64);
#pragma unroll
    for (int v = 0; v < W; ++v) acc[v] += __shfl_xor(acc[v], 32, 64);

    const float inv = 1.0f / fmaxf(runS, 1e-16f);
    if (grp == 0) {
        float* po = out + (size_t)node * C + c0;
#pragma unroll
        for (int v4 = 0; v4 < W / 4; ++v4) {
            float4 o = ((float4*)po)[v4];
            o.x += acc[v4 * 4 + 0] * inv;
            o.y += acc[v4 * 4 + 1] * inv;
            o.z += acc[v4 * 4 + 2] * inv;
            o.w += acc[v4 * 4 + 3] * inv;
            ((float4*)po)[v4] = o;
        }
    }
}

// ---------------------------------------------------------------------------
// Workspace layout (float slots).  Ends ~83.5 MB (ws >= 103.6 MB proven).
// ---------------------------------------------------------------------------
#define F_H      0
#define F_XCOP   12800000
#define F_XCM    19200000
#define F_XCA    19520000
#define F_BTP    19648000
#define F_BTS    19713536
#define F_BTOL   19779072
#define F_BTOR   19795456
#define F_BTML   19803648
#define F_BTMR   19811840
#define F_BIASP  19820032
#define F_BIASS  19820544
#define F_CNT4   19821056    // int[107000]
#define F_CUR4   19928056    // int[107000]
#define F_BSUM   20035056    // int[256]
#define F_BOFF   20035312    // int[256]
#define F_PTR_P  20035568    // int[50001]
#define F_SRC_P  20085569    // int[200000]
#define F_PTR_S  20285569    // int[50001]
#define F_SRC_S  20335570    // int[200000]
#define F_PTR_O  20535570    // int[5001]
#define F_SRC_O  20540571    // int[200000]
#define F_PTR_A  20740571    // int[2001]
#define F_SRC_A  20742572    // int[60000]
#define F_EID_A  20802572    // int[60000]  -> ends 20,862,572 floats = 83.5 MB

extern "C" void kernel_launch(void* const* d_in, const int* in_sizes, int n_in,
                              void* d_out, int out_size, void* d_ws, size_t ws_size,
                              hipStream_t stream) {
    const float* x_op    = (const float*)d_in[0];
    const float* x_m     = (const float*)d_in[1];
    const float* x_a     = (const float*)d_in[2];
    const int*   ei_pred = (const int*)d_in[3];
    const int*   ei_succ = (const int*)d_in[4];
    const int*   src_o2m = (const int*)d_in[5];
    const int*   dst_o2m = (const int*)d_in[6];
    const int*   src_m2a = (const int*)d_in[7];
    const int*   dst_m2a = (const int*)d_in[8];
    const float* ea_m2a  = (const float*)d_in[9];

    const float* Wl_pred = (const float*)d_in[10];
    const float* bl_pred = (const float*)d_in[11];
    const float* Wr_pred = (const float*)d_in[12];
    const float* br_pred = (const float*)d_in[13];
    const float* att_pred= (const float*)d_in[14];
    const float* b_pred  = (const float*)d_in[15];

    const float* Wl_succ = (const float*)d_in[16];
    const float* bl_succ = (const float*)d_in[17];
    const float* Wr_succ = (const float*)d_in[18];
    const float* br_succ = (const float*)d_in[19];
    const float* att_succ= (const float*)d_in[20];
    const float* b_succ  = (const float*)d_in[21];

    const float* Wl_o2m  = (const float*)d_in[22];
    const float* bl_o2m  = (const float*)d_in[23];
    const float* Wr_o2m  = (const float*)d_in[24];
    const float* br_o2m  = (const float*)d_in[25];
    const float* att_o2m = (const float*)d_in[26];
    const float* b_o2m   = (const float*)d_in[27];

    const float* Wl_m2a  = (const float*)d_in[28];
    const float* bl_m2a  = (const float*)d_in[29];
    const float* Wr_m2a  = (const float*)d_in[30];
    const float* br_m2a  = (const float*)d_in[31];
    const float* att_m2a = (const float*)d_in[32];
    const float* b_m2a   = (const float*)d_in[33];
    const float* We_m2a  = (const float*)d_in[34];

    float* ws = (float*)d_ws;
    unsigned short* H     = (unsigned short*)(ws + F_H);
    unsigned short* xc_op = (unsigned short*)(ws + F_XCOP);
    unsigned short* xc_m  = (unsigned short*)(ws + F_XCM);
    unsigned short* xc_a  = (unsigned short*)(ws + F_XCA);
    unsigned short* BtP   = (unsigned short*)(ws + F_BTP);
    unsigned short* BtS   = (unsigned short*)(ws + F_BTS);
    unsigned short* BtOL  = (unsigned short*)(ws + F_BTOL);
    unsigned short* BtOR  = (unsigned short*)(ws + F_BTOR);
    unsigned short* BtML  = (unsigned short*)(ws + F_BTML);
    unsigned short* BtMR  = (unsigned short*)(ws + F_BTMR);
    float* biasP = ws + F_BIASP;
    float* biasS = ws + F_BIASS;
    int* cntP = (int*)(ws + F_CNT4);
    int* cntS = cntP + 50000;
    int* cntO = cntP + 100000;
    int* cntA = cntP + 105000;
    int* curP = (int*)(ws + F_CUR4);
    int* curS = curP + 50000;
    int* curO = curP + 100000;
    int* curA = curP + 105000;
    int* bsum = (int*)(ws + F_BSUM);
    int* boff = (int*)(ws + F_BOFF);
    int* ptrP = (int*)(ws + F_PTR_P); int* srcP = (int*)(ws + F_SRC_P);
    int* ptrS = (int*)(ws + F_PTR_S); int* srcS = (int*)(ws + F_SRC_S);
    int* ptrO = (int*)(ws + F_PTR_O); int* srcO = (int*)(ws + F_SRC_O);
    int* ptrA = (int*)(ws + F_PTR_A); int* srcA = (int*)(ws + F_SRC_A);
    int* eidA = (int*)(ws + F_EID_A);

    float* out_op = (float*)d_out + OUT_OP_OFF;
    float* out_m  = (float*)d_out + OUT_M_OFF;
    float* out_a  = (float*)d_out + OUT_A_OFF;

    // ---- batched CSR build (6 launches) ----
    zero4<<<(2 * NTOT + 255) / 256, 256, 0, stream>>>(cntP, 2 * NTOT);
    hist4<<<(ETOT + 255) / 256, 256, 0, stream>>>(ei_pred + E_OO, ei_succ + E_OO,
                                                  dst_o2m, dst_m2a, cntP, cntS, cntO, cntA);
    scan_blk4<<<NB_P + NB_S + NB_O + NB_A, 1024, 0, stream>>>(cntP, cntS, cntO, cntA,
                                                              ptrP, ptrS, ptrO, ptrA, bsum);
    scan_tops4<<<4, 1024, 0, stream>>>(bsum, boff, ptrP, ptrS, ptrO, ptrA);
    scan_add4<<<(NTOT + 255) / 256, 256, 0, stream>>>(ptrP, ptrS, ptrO, ptrA, boff);
    scatter4<<<(ETOT + 255) / 256, 256, 0, stream>>>(
        ei_pred, ei_pred + E_OO, ei_succ, ei_succ + E_OO,
        src_o2m, dst_o2m, src_m2a, dst_m2a,
        ptrP, ptrS, ptrO, ptrA, curP, curS, curO, curA,
        srcP, srcS, srcO, srcA, eidA);

    // ---- fused init + pack (2 launches) ----
    init3<<<(I3_A + 255) / 256, 256, 0, stream>>>(x_op, x_m, x_a, b_pred, b_succ, b_o2m, b_m2a,
                                                  out_op, out_m, out_a, xc_op, xc_m, xc_a);
    pack_all<<<(PK_BS + 255) / 256, 256, 0, stream>>>(
        Wl_pred, Wr_pred, Wl_succ, Wr_succ, Wl_o2m, Wr_o2m, Wl_m2a, Wr_m2a,
        bl_pred, br_pred, bl_succ, br_succ,
        BtP, BtS, BtOL, BtOR, BtML, BtMR, biasP, biasS);

    const int MT_OP = (N_OP + 127) / 128;
    const int MT_M  = (N_M + 127) / 128;
    const int MT_A  = (N_A + 127) / 128;

    // ---------------- conv 1: pred (op->op, C=256), H = [50000][512] ----------------
    mfma_gemm<<<dim3(MT_OP, 4), 256, 0, stream>>>(xc_op, BtP, biasP, H, N_OP, 256, 512);
    csr_serial<256, false><<<(N_OP + 3) / 4, 256, 0, stream>>>(H, 512, H + 256, 512, nullptr,
                                                               att_pred, ptrP, srcP, out_op, N_OP);

    // ---------------- conv 2: succ ----------------
    mfma_gemm<<<dim3(MT_OP, 4), 256, 0, stream>>>(xc_op, BtS, biasS, H, N_OP, 256, 512);
    csr_serial<256, false><<<(N_OP + 3) / 4, 256, 0, stream>>>(H, 512, H + 256, 512, nullptr,
                                                               att_succ, ptrS, srcS, out_op, N_OP);

    // ---------------- conv 3: o2m (op->machine, C=128, deg~40) ----------------
    {
        unsigned short* xlb = H;                 // [50000][128]
        unsigned short* xrb = H + 6400000;       // [5000][128]
        mfma_gemm<<<dim3(MT_OP, 1), 256, 0, stream>>>(xc_op, BtOL, bl_o2m, xlb, N_OP, 256, 128);
        mfma_gemm<<<dim3(MT_M, 1), 256, 0, stream>>>(xc_m, BtOR, br_o2m, xrb, N_M, 128, 128);
        csr_grp<128, false><<<(N_M + 3) / 4, 256, 0, stream>>>(xlb, 128, xrb, 128, nullptr,
                                                               att_o2m, ptrO, srcO, out_m, N_M);
    }

    // ---------------- conv 4: m2a (machine->agv, C=128, deg~30, edge feats) ----------------
    {
        unsigned short* xlb = H;                 // [5000][128]
        unsigned short* xrb = H + 1000000;       // [2000][128]
        unsigned short* efb = H + 2000000;       // [60000][128] CSR-slot order
        mfma_gemm<<<dim3(MT_M, 1), 256, 0, stream>>>(xc_m, BtML, bl_m2a, xlb, N_M, 128, 128);
        mfma_gemm<<<dim3(MT_A, 1), 256, 0, stream>>>(xc_a, BtMR, br_m2a, xrb, N_A, 128, 128);
        gemm_ef<8, 128, 4><<<E_MA / 4, 128, 0, stream>>>(ea_m2a, We_m2a, eidA, efb);
        csr_grp<128, true><<<(N_A + 3) / 4, 256, 0, stream>>>(xlb, 128, xrb, 128, efb,
                                                              att_m2a, ptrA, srcA, out_a, N_A);
    }
}

// Round 10
// 333.300 us; speedup vs baseline: 6.0275x; 1.0590x over previous
//
#include <hip/hip_runtime.h>

// ---------------------------------------------------------------------------
// Problem constants (fixed by setup_inputs)
// ---------------------------------------------------------------------------
#define N_OP   50000
#define N_M    5000
#define N_A    2000
#define C_OP   256
#define C_M    128
#define C_A    128
#define E_OO   200000
#define E_OM   200000
#define E_MA   60000
#define E_DIM  8

#define OUT_OP_OFF 0
#define OUT_M_OFF  (N_OP * C_OP)
#define OUT_A_OFF  (N_OP * C_OP + N_M * C_M)

typedef short bf16x8 __attribute__((ext_vector_type(8)));
typedef float f32x4 __attribute__((ext_vector_type(4)));
typedef __attribute__((address_space(1))) const unsigned gu32;
typedef __attribute__((address_space(3))) unsigned lu32;

__device__ __forceinline__ unsigned short f2bf(float f) {
    unsigned u = __float_as_uint(f);
    unsigned r = (u + 0x7FFFu + ((u >> 16) & 1u)) >> 16;
    return (unsigned short)r;
}
__device__ __forceinline__ float bf2f(unsigned short h) {
    return __uint_as_float(((unsigned)h) << 16);
}

// ---------------------------------------------------------------------------
// Fused residual-init + bf16 conversion for all 3 node types (1 launch).
// ---------------------------------------------------------------------------
__device__ __forceinline__ void init_one(const float* __restrict__ x,
                                         const float* __restrict__ b1,
                                         const float* __restrict__ b2,
                                         float* __restrict__ out,
                                         unsigned short* __restrict__ xc,
                                         int i, int cmask) {
    float4 v = ((const float4*)x)[i];
    const int cb = i & cmask;
    float4 b = ((const float4*)b1)[cb];
    if (b2) {
        float4 t = ((const float4*)b2)[cb];
        b.x += t.x; b.y += t.y; b.z += t.z; b.w += t.w;
    }
    float4 o;
    o.x = v.x + b.x; o.y = v.y + b.y; o.z = v.z + b.z; o.w = v.w + b.w;
    ((float4*)out)[i] = o;
    ushort4 r;
    r.x = f2bf(v.x); r.y = f2bf(v.y); r.z = f2bf(v.z); r.w = f2bf(v.w);
    ((ushort4*)xc)[i] = r;
}

#define I3_OP (N_OP * C_OP / 4)                 // 3,200,000
#define I3_M  (I3_OP + N_M * C_M / 4)           // 3,360,000
#define I3_A  (I3_M + N_A * C_A / 4)            // 3,424,000

__global__ void init3(const float* __restrict__ x_op, const float* __restrict__ x_m,
                      const float* __restrict__ x_a,
                      const float* __restrict__ bP, const float* __restrict__ bS,
                      const float* __restrict__ bO, const float* __restrict__ bA,
                      float* __restrict__ out_op, float* __restrict__ out_m,
                      float* __restrict__ out_a,
                      unsigned short* __restrict__ xcop, unsigned short* __restrict__ xcm,
                      unsigned short* __restrict__ xca) {
    int i = blockIdx.x * blockDim.x + threadIdx.x;
    if (i < I3_OP)      init_one(x_op, bP, bS, out_op, xcop, i, 63);
    else if (i < I3_M)  init_one(x_m, bO, nullptr, out_m, xcm, i - I3_OP, 31);
    else if (i < I3_A)  init_one(x_a, bA, nullptr, out_a, xca, i - I3_M, 31);
}

// ---------------------------------------------------------------------------
// All weight/bias packing in one launch.
// ---------------------------------------------------------------------------
#define PK_P   131072
#define PK_S   262144
#define PK_OL  294912
#define PK_OR  311296
#define PK_ML  327680
#define PK_MR  344064
#define PK_BP  344576
#define PK_BS  345088

__global__ void pack_all(const float* __restrict__ WlP, const float* __restrict__ WrP,
                         const float* __restrict__ WlS, const float* __restrict__ WrS,
                         const float* __restrict__ WOl, const float* __restrict__ WOr,
                         const float* __restrict__ WMl, const float* __restrict__ WMr,
                         const float* __restrict__ blP, const float* __restrict__ brP,
                         const float* __restrict__ blS, const float* __restrict__ brS,
                         unsigned short* __restrict__ BtP, unsigned short* __restrict__ BtS,
                         unsigned short* __restrict__ BtOL, unsigned short* __restrict__ BtOR,
                         unsigned short* __restrict__ BtML, unsigned short* __restrict__ BtMR,
                         float* __restrict__ biasP, float* __restrict__ biasS) {
    int i = blockIdx.x * blockDim.x + threadIdx.x;
    if (i < PK_P) {
        int n = i >> 8, k = i & 255;
        BtP[i] = f2bf((n < 256) ? WlP[k * 256 + n] : WrP[k * 256 + (n - 256)]);
    } else if (i < PK_S) {
        int j = i - PK_P; int n = j >> 8, k = j & 255;
        BtS[j] = f2bf((n < 256) ? WlS[k * 256 + n] : WrS[k * 256 + (n - 256)]);
    } else if (i < PK_OL) {
        int j = i - PK_S; int n = j >> 8, k = j & 255;
        BtOL[j] = f2bf(WOl[k * 128 + n]);
    } else if (i < PK_OR) {
        int j = i - PK_OL; int n = j >> 7, k = j & 127;
        BtOR[j] = f2bf(WOr[k * 128 + n]);
    } else if (i < PK_ML) {
        int j = i - PK_OR; int n = j >> 7, k = j & 127;
        BtML[j] = f2bf(WMl[k * 128 + n]);
    } else if (i < PK_MR) {
        int j = i - PK_ML; int n = j >> 7, k = j & 127;
        BtMR[j] = f2bf(WMr[k * 128 + n]);
    } else if (i < PK_BP) {
        int j = i - PK_MR;
        biasP[j] = (j < 256) ? blP[j] : brP[j - 256];
    } else if (i < PK_BS) {
        int j = i - PK_BP;
        biasS[j] = (j < 256) ? blS[j] : brS[j - 256];
    }
}

// ---------------------------------------------------------------------------
// MFMA bf16 GEMM: 128x128 tile, BK=64, double-buffered, XOR-swizzled LDS
// (verified rounds 5-9).
// ---------------------------------------------------------------------------
__device__ __forceinline__ void gload_lds16(const void* g, void* l) {
    __builtin_amdgcn_global_load_lds((gu32*)g, (lu32*)l, 16, 0, 0);
}

__global__ __launch_bounds__(256) void mfma_gemm(
    const unsigned short* __restrict__ A, const unsigned short* __restrict__ Bt,
    const float* __restrict__ bias, unsigned short* __restrict__ C,
    int M, int K, int ldc) {
    __shared__ unsigned short As[2][128 * 64];
    __shared__ unsigned short Bs[2][128 * 64];

    const int tid  = threadIdx.x;
    const int lane = tid & 63;
    const int wid  = tid >> 6;
    const int m0   = blockIdx.x * 128;
    const int n0   = blockIdx.y * 128;

    f32x4 acc[4][4] = {};

    const int srow   = tid >> 3;
    const int scolb  = (tid & 7) * 16;
    const int scole  = (scolb ^ ((srow & 7) << 4)) >> 1;

    int grA[4], grB[4];
#pragma unroll
    for (int i = 0; i < 4; ++i) {
        int gr = m0 + i * 32 + srow;
        grA[i] = (gr < M) ? gr : M - 1;
        grB[i] = n0 + i * 32 + srow;
    }

    const int nt = K >> 6;
    int cur = 0;

#define STAGE(buf, k0)                                                          \
    {                                                                           \
        _Pragma("unroll")                                                       \
        for (int i = 0; i < 4; ++i)                                             \
            gload_lds16(A + (size_t)grA[i] * K + (k0) + scole,                  \
                        &As[buf][i * 2048 + tid * 8]);                          \
        _Pragma("unroll")                                                       \
        for (int i = 0; i < 4; ++i)                                             \
            gload_lds16(Bt + (size_t)grB[i] * K + (k0) + scole,                 \
                        &Bs[buf][i * 2048 + tid * 8]);                          \
    }

    STAGE(0, 0)
    asm volatile("s_waitcnt vmcnt(0)" ::: "memory");
    __syncthreads();

    const int wr = (wid >> 1) * 64;
    const int wc = (wid & 1) * 64;

    for (int t = 0; t < nt; ++t) {
        if (t + 1 < nt) STAGE(cur ^ 1, (t + 1) * 64)
#pragma unroll
        for (int kh = 0; kh < 2; ++kh) {
            const int kob = kh * 64 + (lane >> 4) * 16;
            bf16x8 a[4], b[4];
#pragma unroll
            for (int mi = 0; mi < 4; ++mi) {
                const int row = wr + mi * 16 + (lane & 15);
                a[mi] = *(const bf16x8*)((const char*)As[cur] + row * 128 +
                                         (kob ^ ((row & 7) << 4)));
            }
#pragma unroll
            for (int ni = 0; ni < 4; ++ni) {
                const int row = wc + ni * 16 + (lane & 15);
                b[ni] = *(const bf16x8*)((const char*)Bs[cur] + row * 128 +
                                         (kob ^ ((row & 7) << 4)));
            }
#pragma unroll
            for (int mi = 0; mi < 4; ++mi)
#pragma unroll
                for (int ni = 0; ni < 4; ++ni)
                    acc[mi][ni] = __builtin_amdgcn_mfma_f32_16x16x32_bf16(
                        a[mi], b[ni], acc[mi][ni], 0, 0, 0);
        }
        asm volatile("s_waitcnt vmcnt(0)" ::: "memory");
        __syncthreads();
        cur ^= 1;
    }
#undef STAGE

    const int crow = (lane >> 4) * 4;
    const int ccol = lane & 15;
    float bcol[4];
#pragma unroll
    for (int ni = 0; ni < 4; ++ni) bcol[ni] = bias[n0 + wc + ni * 16 + ccol];
#pragma unroll
    for (int mi = 0; mi < 4; ++mi) {
#pragma unroll
        for (int j = 0; j < 4; ++j) {
            const int row = m0 + wr + mi * 16 + crow + j;
            if (row < M) {
                unsigned short* pc = C + (size_t)row * ldc + n0 + wc + ccol;
#pragma unroll
                for (int ni = 0; ni < 4; ++ni)
                    pc[ni * 16] = f2bf(acc[mi][ni][j] + bcol[ni]);
            }
        }
    }
}

// ---------------------------------------------------------------------------
// Small fp32 GEMM for edge features (K=8), rows permuted by eid (CSR order)
// ---------------------------------------------------------------------------
template <int K, int N, int TM>
__global__ void gemm_ef(const float* __restrict__ A, const float* __restrict__ W,
                        const int* __restrict__ eid, unsigned short* __restrict__ out) {
    __shared__ float As[TM][K];
    const int m0 = blockIdx.x * TM;
    const int tid = threadIdx.x;
    for (int idx = tid; idx < TM * K; idx += N) {
        int r = idx / K, k = idx - r * K;
        As[r][k] = A[(size_t)eid[m0 + r] * K + k];
    }
    __syncthreads();
    float acc[TM] = {};
    for (int k = 0; k < K; ++k) {
        const float w = W[k * N + tid];
#pragma unroll
        for (int r = 0; r < TM; ++r) acc[r] += As[r][k] * w;
    }
#pragma unroll
    for (int r = 0; r < TM; ++r) out[(size_t)(m0 + r) * N + tid] = f2bf(acc[r]);
}

// ---------------------------------------------------------------------------
// Batched CSR build for all 4 relations (6 launches total).
// ---------------------------------------------------------------------------
#define NB_P 49
#define NB_S 49
#define NB_O 5
#define NB_A 2
#define NTOT 107000          // 50000+50000+5000+2000
#define ETOT 660000

__global__ void zero4(int* __restrict__ p, int n) {
    int i = blockIdx.x * blockDim.x + threadIdx.x;
    if (i < n) p[i] = 0;
}

__global__ void hist4(const int* __restrict__ dP, const int* __restrict__ dS,
                      const int* __restrict__ dO, const int* __restrict__ dA,
                      int* __restrict__ cP, int* __restrict__ cS,
                      int* __restrict__ cO, int* __restrict__ cA) {
    int i = blockIdx.x * blockDim.x + threadIdx.x;
    if (i < 200000)      atomicAdd(&cP[dP[i]], 1);
    else if (i < 400000) atomicAdd(&cS[dS[i - 200000]], 1);
    else if (i < 600000) atomicAdd(&cO[dO[i - 400000]], 1);
    else if (i < ETOT)   atomicAdd(&cA[dA[i - 600000]], 1);
}

__global__ void scan_blk4(const int* __restrict__ cP, const int* __restrict__ cS,
                          const int* __restrict__ cO, const int* __restrict__ cA,
                          int* __restrict__ pP, int* __restrict__ pS,
                          int* __restrict__ pO, int* __restrict__ pA,
                          int* __restrict__ bsum) {
    __shared__ int smem[1024];
    int b = blockIdx.x;
    const int* cnt; int* ptr; int n; int bo;
    if (b < NB_P)                { cnt = cP; ptr = pP; n = 50000; bo = 0; }
    else if (b < NB_P + NB_S)    { cnt = cS; ptr = pS; n = 50000; bo = 64;  b -= NB_P; }
    else if (b < NB_P + NB_S + NB_O) { cnt = cO; ptr = pO; n = 5000; bo = 128; b -= NB_P + NB_S; }
    else                         { cnt = cA; ptr = pA; n = 2000; bo = 192; b -= NB_P + NB_S + NB_O; }
    const int tid = threadIdx.x;
    const int i = b * 1024 + tid;
    const int v = (i < n) ? cnt[i] : 0;
    smem[tid] = v;
    __syncthreads();
    for (int o = 1; o < 1024; o <<= 1) {
        int t = (tid >= o) ? smem[tid - o] : 0;
        __syncthreads();
        smem[tid] += t;
        __syncthreads();
    }
    if (i < n) ptr[i] = smem[tid] - v;
    if (tid == 1023) bsum[bo + b] = smem[1023];
}

__global__ void scan_tops4(const int* __restrict__ bsum, int* __restrict__ boff,
                           int* __restrict__ pP, int* __restrict__ pS,
                           int* __restrict__ pO, int* __restrict__ pA) {
    __shared__ int smem[1024];
    const int seg = blockIdx.x;
    const int nb = (seg < 2) ? 49 : (seg == 2 ? 5 : 2);
    const int off = seg * 64;
    int* ptr_n = (seg == 0) ? pP + 50000 : (seg == 1) ? pS + 50000
               : (seg == 2) ? pO + 5000 : pA + 2000;
    const int tid = threadIdx.x;
    const int v = (tid < nb) ? bsum[off + tid] : 0;
    smem[tid] = v;
    __syncthreads();
    for (int o = 1; o < 1024; o <<= 1) {
        int t = (tid >= o) ? smem[tid - o] : 0;
        __syncthreads();
        smem[tid] += t;
        __syncthreads();
    }
    if (tid < nb) boff[off + tid] = smem[tid] - v;
    if (tid == 1023) *ptr_n = smem[1023];
}

__global__ void scan_add4(int* __restrict__ pP, int* __restrict__ pS,
                          int* __restrict__ pO, int* __restrict__ pA,
                          const int* __restrict__ boff) {
    int i = blockIdx.x * blockDim.x + threadIdx.x;
    int* ptr; int loc; int off;
    if (i < 50000)       { ptr = pP; loc = i;          off = 0; }
    else if (i < 100000) { ptr = pS; loc = i - 50000;  off = 64; }
    else if (i < 105000) { ptr = pO; loc = i - 100000; off = 128; }
    else if (i < NTOT)   { ptr = pA; loc = i - 105000; off = 192; }
    else return;
    ptr[loc] += boff[off + (loc >> 10)];
}

__global__ void scatter4(const int* __restrict__ sP, const int* __restrict__ dP,
                         const int* __restrict__ sS, const int* __restrict__ dS,
                         const int* __restrict__ sO, const int* __restrict__ dO,
                         const int* __restrict__ sA, const int* __restrict__ dA,
                         const int* __restrict__ pP, const int* __restrict__ pS,
                         const int* __restrict__ pO, const int* __restrict__ pA,
                         int* __restrict__ uP, int* __restrict__ uS,
                         int* __restrict__ uO, int* __restrict__ uA,
                         int* __restrict__ srP, int* __restrict__ srS,
                         int* __restrict__ srO, int* __restrict__ srA,
                         int* __restrict__ eiA) {
    int i = blockIdx.x * blockDim.x + threadIdx.x;
    if (i < 200000) {
        const int d = dP[i];
        srP[pP[d] + atomicAdd(&uP[d], 1)] = sP[i];
    } else if (i < 400000) {
        const int j = i - 200000; const int d = dS[j];
        srS[pS[d] + atomicAdd(&uS[d], 1)] = sS[j];
    } else if (i < 600000) {
        const int j = i - 400000; const int d = dO[j];
        srO[pO[d] + atomicAdd(&uO[d], 1)] = sO[j];
    } else if (i < ETOT) {
        const int j = i - 600000; const int d = dA[j];
        const int pos = pA[d] + atomicAdd(&uA[d], 1);
        srA[pos] = sA[j];
        eiA[pos] = j;
    }
}

// ---------------------------------------------------------------------------
// csr_serial2: TWO nodes per wave (32 lanes each), single-pass online softmax,
// one edge at a time per node with next-row prefetch.  The two independent
// per-node chains interleave in one wave (2x ILP on the latency-bound
// shfl/exp chain), reduce is 5 steps (xor 1..16, stays within each half),
// and the softmax update is branch-free (no half-wave divergence).
// For LOW degree C=256 convs.
// ---------------------------------------------------------------------------
template <int C>
__global__ void csr_serial2(const unsigned short* __restrict__ xl, int ldl,
                            const unsigned short* __restrict__ xr, int ldr,
                            const float* __restrict__ att,
                            const int* __restrict__ ptr, const int* __restrict__ srcs,
                            float* __restrict__ out, int n) {
    const int tid = threadIdx.x;
    const int node = blockIdx.x * (blockDim.x >> 5) + (tid >> 5);
    if (node >= n) return;
    const int gl = tid & 31;             // lane within 32-lane group
    const int beg = ptr[node], end = ptr[node + 1];
    if (beg == end) return;

    constexpr int V = C / 32;            // 8 for C=256
    const int c0 = gl * V;

    float av[V], rvf[V];
    {
        const unsigned short* pr = xr + (size_t)node * ldr + c0;
        unsigned short rv[V];
        *(uint4*)rv = *(const uint4*)pr;
#pragma unroll
        for (int v4 = 0; v4 < V / 4; ++v4)
            *(float4*)(av + v4 * 4) = ((const float4*)(att + c0))[v4];
#pragma unroll
        for (int v = 0; v < V; ++v) rvf[v] = bf2f(rv[v]);
    }

    float runM = -3.0e38f, runS = 0.0f;
    float acc[V] = {};

    unsigned short lv[V];
    {
        const unsigned short* pl = xl + (size_t)srcs[beg] * ldl + c0;
        *(uint4*)lv = *(const uint4*)pl;
    }

    for (int j = beg; j < end; ++j) {
        float cf[V];
#pragma unroll
        for (int v = 0; v < V; ++v) cf[v] = bf2f(lv[v]);
        if (j + 1 < end) {                      // prefetch next row
            const unsigned short* pl = xl + (size_t)srcs[j + 1] * ldl + c0;
            *(uint4*)lv = *(const uint4*)pl;
        }

        float part = 0.0f;
#pragma unroll
        for (int v = 0; v < V; ++v) {
            float m = cf[v] + rvf[v];
            m = (m >= 0.0f) ? m : 0.2f * m;
            part += m * av[v];
        }
        // 5-step reduce within the 32-lane group (xor<32 never crosses halves)
        part += __shfl_xor(part, 1, 64);
        part += __shfl_xor(part, 2, 64);
        part += __shfl_xor(part, 4, 64);
        part += __shfl_xor(part, 8, 64);
        part += __shfl_xor(part, 16, 64);

        // branch-free online softmax (group-uniform values)
        const float newM = fmaxf(runM, part);
        const float sc = __expf(runM - newM);   // 1 if no move, 0 on first edge
        const float e1 = __expf(part - newM);
        runS = runS * sc + e1;
        runM = newM;
#pragma unroll
        for (int v = 0; v < V; ++v) acc[v] = acc[v] * sc + e1 * cf[v];
    }

    const float inv = 1.0f / fmaxf(runS, 1e-16f);
    float* po = out + (size_t)node * C + c0;
#pragma unroll
    for (int v4 = 0; v4 < V / 4; ++v4) {
        float4 o = ((float4*)po)[v4];
        o.x += acc[v4 * 4 + 0] * inv;
        o.y += acc[v4 * 4 + 1] * inv;
        o.z += acc[v4 * 4 + 2] * inv;
        o.w += acc[v4 * 4 + 3] * inv;
        ((float4*)po)[v4] = o;
    }
}

// ---------------------------------------------------------------------------
// csr_grp: round-8-verified 16-lane-group version (4 edges in flight), one
// wave per node.  Best for HIGH degree (o2m deg~40, m2a deg~30).
// ---------------------------------------------------------------------------
template <int C, bool HAS_EF>
__global__ void csr_grp(const unsigned short* __restrict__ xl, int ldl,
                        const unsigned short* __restrict__ xr, int ldr,
                        const unsigned short* __restrict__ ef,
                        const float* __restrict__ att,
                        const int* __restrict__ ptr, const int* __restrict__ srcs,
                        float* __restrict__ out, int n) {
    const int node = blockIdx.x * (blockDim.x >> 6) + (threadIdx.x >> 6);
    if (node >= n) return;
    const int lane = threadIdx.x & 63;
    const int grp  = lane >> 4;          // edge slot within chunk (0..3)
    const int sl   = lane & 15;          // channel-group lane
    const int beg = ptr[node], end = ptr[node + 1];
    if (beg == end) return;

    constexpr int W = C / 16;            // channels per lane (8 for C=128)
    const int c0 = sl * W;

    float av[W], rvf[W];
    {
        const unsigned short* pr = xr + (size_t)node * ldr + c0;
        unsigned short rv[W];
        *(uint4*)rv = *(const uint4*)pr;
        if constexpr (W == 16) *(uint4*)(rv + 8) = *(const uint4*)(pr + 8);
#pragma unroll
        for (int v4 = 0; v4 < W / 4; ++v4)
            *(float4*)(av + v4 * 4) = ((const float4*)(att + c0))[v4];
#pragma unroll
        for (int v = 0; v < W; ++v) rvf[v] = bf2f(rv[v]);
    }

    float runM = -3.0e38f, runS = 0.0f;
    float acc[W] = {};

    for (int cb = beg; cb < end; cb += 4) {
        const int j = cb + grp;
        const bool act = (j < end);
        const int js = act ? j : end - 1;
        const int s = srcs[js];

        const unsigned short* pl = xl + (size_t)s * ldl + c0;
        unsigned short lv[W];
        *(uint4*)lv = *(const uint4*)pl;
        if constexpr (W == 16) *(uint4*)(lv + 8) = *(const uint4*)(pl + 8);
        float cf[W];
#pragma unroll
        for (int v = 0; v < W; ++v) cf[v] = bf2f(lv[v]);

        float part = 0.0f;
        if constexpr (HAS_EF) {
            unsigned short efv[W];
            const unsigned short* pe = ef + (size_t)js * C + c0;
            *(uint4*)efv = *(const uint4*)pe;
            if constexpr (W == 16) *(uint4*)(efv + 8) = *(const uint4*)(pe + 8);
#pragma unroll
            for (int v = 0; v < W; ++v) {
                float m = cf[v] + rvf[v] + bf2f(efv[v]);
                m = (m >= 0.0f) ? m : 0.2f * m;
                part += m * av[v];
            }
        } else {
#pragma unroll
            for (int v = 0; v < W; ++v) {
                float m = cf[v] + rvf[v];
                m = (m >= 0.0f) ? m : 0.2f * m;
                part += m * av[v];
            }
        }
        part += __shfl_xor(part, 1, 64);
        part += __shfl_xor(part, 2, 64);
        part += __shfl_xor(part, 4, 64);
        part += __shfl_xor(part, 8, 64);
        if (!act) part = -3.0e38f;

        float cm = fmaxf(part, __shfl_xor(part, 16, 64));
        cm = fmaxf(cm, __shfl_xor(cm, 32, 64));

        if (cm > runM) {                 // wave-uniform branch
            const float sc = __expf(runM - cm);
            runS *= sc;
#pragma unroll
            for (int v = 0; v < W; ++v) acc[v] *= sc;
            runM = cm;
        }
        const float w = act ? __expf(part - runM) : 0.0f;
        float cs = w + __shfl_xor(w, 16, 64);
        cs += __shfl_xor(cs, 32, 64);
        runS += cs;
#pragma unroll
        for (int v = 0; v < W; ++v) acc[v] += w * cf[v];
    }

#pragma unroll
    for (int v = 0; v < W; ++v) acc[v] += __shfl_xor(acc[v], 16, 64);
#pragma unroll
    for (int v = 0; v < W; ++v) acc[v] += __shfl_xor(acc[v], 32, 64);

    const float inv = 1.0f / fmaxf(runS, 1e-16f);
    if (grp == 0) {
        float* po = out + (size_t)node * C + c0;
#pragma unroll
        for (int v4 = 0; v4 < W / 4; ++v4) {
            float4 o = ((float4*)po)[v4];
            o.x += acc[v4 * 4 + 0] * inv;
            o.y += acc[v4 * 4 + 1] * inv;
            o.z += acc[v4 * 4 + 2] * inv;
            o.w += acc[v4 * 4 + 3] * inv;
            ((float4*)po)[v4] = o;
        }
    }
}

// ---------------------------------------------------------------------------
// Workspace layout (float slots).  Ends ~83.5 MB (ws >= 103.6 MB proven).
// ---------------------------------------------------------------------------
#define F_H      0
#define F_XCOP   12800000
#define F_XCM    19200000
#define F_XCA    19520000
#define F_BTP    19648000
#define F_BTS    19713536
#define F_BTOL   19779072
#define F_BTOR   19795456
#define F_BTML   19803648
#define F_BTMR   19811840
#define F_BIASP  19820032
#define F_BIASS  19820544
#define F_CNT4   19821056    // int[107000]
#define F_CUR4   19928056    // int[107000]
#define F_BSUM   20035056    // int[256]
#define F_BOFF   20035312    // int[256]
#define F_PTR_P  20035568    // int[50001]
#define F_SRC_P  20085569    // int[200000]
#define F_PTR_S  20285569    // int[50001]
#define F_SRC_S  20335570    // int[200000]
#define F_PTR_O  20535570    // int[5001]
#define F_SRC_O  20540571    // int[200000]
#define F_PTR_A  20740571    // int[2001]
#define F_SRC_A  20742572    // int[60000]
#define F_EID_A  20802572    // int[60000]  -> ends 20,862,572 floats = 83.5 MB

extern "C" void kernel_launch(void* const* d_in, const int* in_sizes, int n_in,
                              void* d_out, int out_size, void* d_ws, size_t ws_size,
                              hipStream_t stream) {
    const float* x_op    = (const float*)d_in[0];
    const float* x_m     = (const float*)d_in[1];
    const float* x_a     = (const float*)d_in[2];
    const int*   ei_pred = (const int*)d_in[3];
    const int*   ei_succ = (const int*)d_in[4];
    const int*   src_o2m = (const int*)d_in[5];
    const int*   dst_o2m = (const int*)d_in[6];
    const int*   src_m2a = (const int*)d_in[7];
    const int*   dst_m2a = (const int*)d_in[8];
    const float* ea_m2a  = (const float*)d_in[9];

    const float* Wl_pred = (const float*)d_in[10];
    const float* bl_pred = (const float*)d_in[11];
    const float* Wr_pred = (const float*)d_in[12];
    const float* br_pred = (const float*)d_in[13];
    const float* att_pred= (const float*)d_in[14];
    const float* b_pred  = (const float*)d_in[15];

    const float* Wl_succ = (const float*)d_in[16];
    const float* bl_succ = (const float*)d_in[17];
    const float* Wr_succ = (const float*)d_in[18];
    const float* br_succ = (const float*)d_in[19];
    const float* att_succ= (const float*)d_in[20];
    const float* b_succ  = (const float*)d_in[21];

    const float* Wl_o2m  = (const float*)d_in[22];
    const float* bl_o2m  = (const float*)d_in[23];
    const float* Wr_o2m  = (const float*)d_in[24];
    const float* br_o2m  = (const float*)d_in[25];
    const float* att_o2m = (const float*)d_in[26];
    const float* b_o2m   = (const float*)d_in[27];

    const float* Wl_m2a  = (const float*)d_in[28];
    const float* bl_m2a  = (const float*)d_in[29];
    const float* Wr_m2a  = (const float*)d_in[30];
    const float* br_m2a  = (const float*)d_in[31];
    const float* att_m2a = (const float*)d_in[32];
    const float* b_m2a   = (const float*)d_in[33];
    const float* We_m2a  = (const float*)d_in[34];

    float* ws = (float*)d_ws;
    unsigned short* H     = (unsigned short*)(ws + F_H);
    unsigned short* xc_op = (unsigned short*)(ws + F_XCOP);
    unsigned short* xc_m  = (unsigned short*)(ws + F_XCM);
    unsigned short* xc_a  = (unsigned short*)(ws + F_XCA);
    unsigned short* BtP   = (unsigned short*)(ws + F_BTP);
    unsigned short* BtS   = (unsigned short*)(ws + F_BTS);
    unsigned short* BtOL  = (unsigned short*)(ws + F_BTOL);
    unsigned short* BtOR  = (unsigned short*)(ws + F_BTOR);
    unsigned short* BtML  = (unsigned short*)(ws + F_BTML);
    unsigned short* BtMR  = (unsigned short*)(ws + F_BTMR);
    float* biasP = ws + F_BIASP;
    float* biasS = ws + F_BIASS;
    int* cntP = (int*)(ws + F_CNT4);
    int* cntS = cntP + 50000;
    int* cntO = cntP + 100000;
    int* cntA = cntP + 105000;
    int* curP = (int*)(ws + F_CUR4);
    int* curS = curP + 50000;
    int* curO = curP + 100000;
    int* curA = curP + 105000;
    int* bsum = (int*)(ws + F_BSUM);
    int* boff = (int*)(ws + F_BOFF);
    int* ptrP = (int*)(ws + F_PTR_P); int* srcP = (int*)(ws + F_SRC_P);
    int* ptrS = (int*)(ws + F_PTR_S); int* srcS = (int*)(ws + F_SRC_S);
    int* ptrO = (int*)(ws + F_PTR_O); int* srcO = (int*)(ws + F_SRC_O);
    int* ptrA = (int*)(ws + F_PTR_A); int* srcA = (int*)(ws + F_SRC_A);
    int* eidA = (int*)(ws + F_EID_A);

    float* out_op = (float*)d_out + OUT_OP_OFF;
    float* out_m  = (float*)d_out + OUT_M_OFF;
    float* out_a  = (float*)d_out + OUT_A_OFF;

    // ---- batched CSR build (6 launches) ----
    zero4<<<(2 * NTOT + 255) / 256, 256, 0, stream>>>(cntP, 2 * NTOT);
    hist4<<<(ETOT + 255) / 256, 256, 0, stream>>>(ei_pred + E_OO, ei_succ + E_OO,
                                                  dst_o2m, dst_m2a, cntP, cntS, cntO, cntA);
    scan_blk4<<<NB_P + NB_S + NB_O + NB_A, 1024, 0, stream>>>(cntP, cntS, cntO, cntA,
                                                              ptrP, ptrS, ptrO, ptrA, bsum);
    scan_tops4<<<4, 1024, 0, stream>>>(bsum, boff, ptrP, ptrS, ptrO, ptrA);
    scan_add4<<<(NTOT + 255) / 256, 256, 0, stream>>>(ptrP, ptrS, ptrO, ptrA, boff);
    scatter4<<<(ETOT + 255) / 256, 256, 0, stream>>>(
        ei_pred, ei_pred + E_OO, ei_succ, ei_succ + E_OO,
        src_o2m, dst_o2m, src_m2a, dst_m2a,
        ptrP, ptrS, ptrO, ptrA, curP, curS, curO, curA,
        srcP, srcS, srcO, srcA, eidA);

    // ---- fused init + pack (2 launches) ----
    init3<<<(I3_A + 255) / 256, 256, 0, stream>>>(x_op, x_m, x_a, b_pred, b_succ, b_o2m, b_m2a,
                                                  out_op, out_m, out_a, xc_op, xc_m, xc_a);
    pack_all<<<(PK_BS + 255) / 256, 256, 0, stream>>>(
        Wl_pred, Wr_pred, Wl_succ, Wr_succ, Wl_o2m, Wr_o2m, Wl_m2a, Wr_m2a,
        bl_pred, br_pred, bl_succ, br_succ,
        BtP, BtS, BtOL, BtOR, BtML, BtMR, biasP, biasS);

    const int MT_OP = (N_OP + 127) / 128;
    const int MT_M  = (N_M + 127) / 128;
    const int MT_A  = (N_A + 127) / 128;

    // ---------------- conv 1: pred (op->op, C=256), H = [50000][512] ----------------
    mfma_gemm<<<dim3(MT_OP, 4), 256, 0, stream>>>(xc_op, BtP, biasP, H, N_OP, 256, 512);
    csr_serial2<256><<<(N_OP + 7) / 8, 256, 0, stream>>>(H, 512, H + 256, 512,
                                                         att_pred, ptrP, srcP, out_op, N_OP);

    // ---------------- conv 2: succ ----------------
    mfma_gemm<<<dim3(MT_OP, 4), 256, 0, stream>>>(xc_op, BtS, biasS, H, N_OP, 256, 512);
    csr_serial2<256><<<(N_OP + 7) / 8, 256, 0, stream>>>(H, 512, H + 256, 512,
                                                         att_succ, ptrS, srcS, out_op, N_OP);

    // ---------------- conv 3: o2m (op->machine, C=128, deg~40) ----------------
    {
        unsigned short* xlb = H;                 // [50000][128]
        unsigned short* xrb = H + 6400000;       // [5000][128]
        mfma_gemm<<<dim3(MT_OP, 1), 256, 0, stream>>>(xc_op, BtOL, bl_o2m, xlb, N_OP, 256, 128);
        mfma_gemm<<<dim3(MT_M, 1), 256, 0, stream>>>(xc_m, BtOR, br_o2m, xrb, N_M, 128, 128);
        csr_grp<128, false><<<(N_M + 3) / 4, 256, 0, stream>>>(xlb, 128, xrb, 128, nullptr,
                                                               att_o2m, ptrO, srcO, out_m, N_M);
    }

    // ---------------- conv 4: m2a (machine->agv, C=128, deg~30, edge feats) ----------------
    {
        unsigned short* xlb = H;                 // [5000][128]
        unsigned short* xrb = H + 1000000;       // [2000][128]
        unsigned short* efb = H + 2000000;       // [60000][128] CSR-slot order
        mfma_gemm<<<dim3(MT_M, 1), 256, 0, stream>>>(xc_m, BtML, bl_m2a, xlb, N_M, 128, 128);
        mfma_gemm<<<dim3(MT_A, 1), 256, 0, stream>>>(xc_a, BtMR, br_m2a, xrb, N_A, 128, 128);
        gemm_ef<8, 128, 4><<<E_MA / 4, 128, 0, stream>>>(ea_m2a, We_m2a, eidA, efb);
        csr_grp<128, true><<<(N_A + 3) / 4, 256, 0, stream>>>(xlb, 128, xrb, 128, efb,
                                                              att_m2a, ptrA, srcA, out_a, N_A);
    }
}

// Round 11
// 308.742 us; speedup vs baseline: 6.5069x; 1.0795x over previous
//
#include <hip/hip_runtime.h>

// ---------------------------------------------------------------------------
// Problem constants (fixed by setup_inputs)
// ---------------------------------------------------------------------------
#define N_OP   50000
#define N_M    5000
#define N_A    2000
#define C_OP   256
#define C_M    128
#define C_A    128
#define E_OO   200000
#define E_OM   200000
#define E_MA   60000
#define E_DIM  8

#define OUT_OP_OFF 0
#define OUT_M_OFF  (N_OP * C_OP)
#define OUT_A_OFF  (N_OP * C_OP + N_M * C_M)

typedef short bf16x8 __attribute__((ext_vector_type(8)));
typedef float f32x4 __attribute__((ext_vector_type(4)));
typedef __attribute__((address_space(1))) const unsigned gu32;
typedef __attribute__((address_space(3))) unsigned lu32;

__device__ __forceinline__ unsigned short f2bf(float f) {
    unsigned u = __float_as_uint(f);
    unsigned r = (u + 0x7FFFu + ((u >> 16) & 1u)) >> 16;
    return (unsigned short)r;
}
__device__ __forceinline__ float bf2f(unsigned short h) {
    return __uint_as_float(((unsigned)h) << 16);
}

// ---------------------------------------------------------------------------
// Fused residual-init + bf16 conversion for all 3 node types (1 launch).
// ---------------------------------------------------------------------------
__device__ __forceinline__ void init_one(const float* __restrict__ x,
                                         const float* __restrict__ b1,
                                         const float* __restrict__ b2,
                                         float* __restrict__ out,
                                         unsigned short* __restrict__ xc,
                                         int i, int cmask) {
    float4 v = ((const float4*)x)[i];
    const int cb = i & cmask;
    float4 b = ((const float4*)b1)[cb];
    if (b2) {
        float4 t = ((const float4*)b2)[cb];
        b.x += t.x; b.y += t.y; b.z += t.z; b.w += t.w;
    }
    float4 o;
    o.x = v.x + b.x; o.y = v.y + b.y; o.z = v.z + b.z; o.w = v.w + b.w;
    ((float4*)out)[i] = o;
    ushort4 r;
    r.x = f2bf(v.x); r.y = f2bf(v.y); r.z = f2bf(v.z); r.w = f2bf(v.w);
    ((ushort4*)xc)[i] = r;
}

#define I3_OP (N_OP * C_OP / 4)                 // 3,200,000
#define I3_M  (I3_OP + N_M * C_M / 4)           // 3,360,000
#define I3_A  (I3_M + N_A * C_A / 4)            // 3,424,000

__global__ void init3(const float* __restrict__ x_op, const float* __restrict__ x_m,
                      const float* __restrict__ x_a,
                      const float* __restrict__ bP, const float* __restrict__ bS,
                      const float* __restrict__ bO, const float* __restrict__ bA,
                      float* __restrict__ out_op, float* __restrict__ out_m,
                      float* __restrict__ out_a,
                      unsigned short* __restrict__ xcop, unsigned short* __restrict__ xcm,
                      unsigned short* __restrict__ xca) {
    int i = blockIdx.x * blockDim.x + threadIdx.x;
    if (i < I3_OP)      init_one(x_op, bP, bS, out_op, xcop, i, 63);
    else if (i < I3_M)  init_one(x_m, bO, nullptr, out_m, xcm, i - I3_OP, 31);
    else if (i < I3_A)  init_one(x_a, bA, nullptr, out_a, xca, i - I3_M, 31);
}

// ---------------------------------------------------------------------------
// All weight/bias packing in one launch.
// ---------------------------------------------------------------------------
#define PK_P   131072
#define PK_S   262144
#define PK_OL  294912
#define PK_OR  311296
#define PK_ML  327680
#define PK_MR  344064
#define PK_BP  344576
#define PK_BS  345088

__global__ void pack_all(const float* __restrict__ WlP, const float* __restrict__ WrP,
                         const float* __restrict__ WlS, const float* __restrict__ WrS,
                         const float* __restrict__ WOl, const float* __restrict__ WOr,
                         const float* __restrict__ WMl, const float* __restrict__ WMr,
                         const float* __restrict__ blP, const float* __restrict__ brP,
                         const float* __restrict__ blS, const float* __restrict__ brS,
                         unsigned short* __restrict__ BtP, unsigned short* __restrict__ BtS,
                         unsigned short* __restrict__ BtOL, unsigned short* __restrict__ BtOR,
                         unsigned short* __restrict__ BtML, unsigned short* __restrict__ BtMR,
                         float* __restrict__ biasP, float* __restrict__ biasS) {
    int i = blockIdx.x * blockDim.x + threadIdx.x;
    if (i < PK_P) {
        int n = i >> 8, k = i & 255;
        BtP[i] = f2bf((n < 256) ? WlP[k * 256 + n] : WrP[k * 256 + (n - 256)]);
    } else if (i < PK_S) {
        int j = i - PK_P; int n = j >> 8, k = j & 255;
        BtS[j] = f2bf((n < 256) ? WlS[k * 256 + n] : WrS[k * 256 + (n - 256)]);
    } else if (i < PK_OL) {
        int j = i - PK_S; int n = j >> 8, k = j & 255;
        BtOL[j] = f2bf(WOl[k * 128 + n]);
    } else if (i < PK_OR) {
        int j = i - PK_OL; int n = j >> 7, k = j & 127;
        BtOR[j] = f2bf(WOr[k * 128 + n]);
    } else if (i < PK_ML) {
        int j = i - PK_OR; int n = j >> 7, k = j & 127;
        BtML[j] = f2bf(WMl[k * 128 + n]);
    } else if (i < PK_MR) {
        int j = i - PK_ML; int n = j >> 7, k = j & 127;
        BtMR[j] = f2bf(WMr[k * 128 + n]);
    } else if (i < PK_BP) {
        int j = i - PK_MR;
        biasP[j] = (j < 256) ? blP[j] : brP[j - 256];
    } else if (i < PK_BS) {
        int j = i - PK_BP;
        biasS[j] = (j < 256) ? blS[j] : brS[j - 256];
    }
}

// ---------------------------------------------------------------------------
// MFMA bf16 GEMM: 128x128 tile, BK=64, double-buffered, XOR-swizzled LDS
// (verified rounds 5-10).
// ---------------------------------------------------------------------------
__device__ __forceinline__ void gload_lds16(const void* g, void* l) {
    __builtin_amdgcn_global_load_lds((gu32*)g, (lu32*)l, 16, 0, 0);
}

__global__ __launch_bounds__(256) void mfma_gemm(
    const unsigned short* __restrict__ A, const unsigned short* __restrict__ Bt,
    const float* __restrict__ bias, unsigned short* __restrict__ C,
    int M, int K, int ldc) {
    __shared__ unsigned short As[2][128 * 64];
    __shared__ unsigned short Bs[2][128 * 64];

    const int tid  = threadIdx.x;
    const int lane = tid & 63;
    const int wid  = tid >> 6;
    const int m0   = blockIdx.x * 128;
    const int n0   = blockIdx.y * 128;

    f32x4 acc[4][4] = {};

    const int srow   = tid >> 3;
    const int scolb  = (tid & 7) * 16;
    const int scole  = (scolb ^ ((srow & 7) << 4)) >> 1;

    int grA[4], grB[4];
#pragma unroll
    for (int i = 0; i < 4; ++i) {
        int gr = m0 + i * 32 + srow;
        grA[i] = (gr < M) ? gr : M - 1;
        grB[i] = n0 + i * 32 + srow;
    }

    const int nt = K >> 6;
    int cur = 0;

#define STAGE(buf, k0)                                                          \
    {                                                                           \
        _Pragma("unroll")                                                       \
        for (int i = 0; i < 4; ++i)                                             \
            gload_lds16(A + (size_t)grA[i] * K + (k0) + scole,                  \
                        &As[buf][i * 2048 + tid * 8]);                          \
        _Pragma("unroll")                                                       \
        for (int i = 0; i < 4; ++i)                                             \
            gload_lds16(Bt + (size_t)grB[i] * K + (k0) + scole,                 \
                        &Bs[buf][i * 2048 + tid * 8]);                          \
    }

    STAGE(0, 0)
    asm volatile("s_waitcnt vmcnt(0)" ::: "memory");
    __syncthreads();

    const int wr = (wid >> 1) * 64;
    const int wc = (wid & 1) * 64;

    for (int t = 0; t < nt; ++t) {
        if (t + 1 < nt) STAGE(cur ^ 1, (t + 1) * 64)
#pragma unroll
        for (int kh = 0; kh < 2; ++kh) {
            const int kob = kh * 64 + (lane >> 4) * 16;
            bf16x8 a[4], b[4];
#pragma unroll
            for (int mi = 0; mi < 4; ++mi) {
                const int row = wr + mi * 16 + (lane & 15);
                a[mi] = *(const bf16x8*)((const char*)As[cur] + row * 128 +
                                         (kob ^ ((row & 7) << 4)));
            }
#pragma unroll
            for (int ni = 0; ni < 4; ++ni) {
                const int row = wc + ni * 16 + (lane & 15);
                b[ni] = *(const bf16x8*)((const char*)Bs[cur] + row * 128 +
                                         (kob ^ ((row & 7) << 4)));
            }
#pragma unroll
            for (int mi = 0; mi < 4; ++mi)
#pragma unroll
                for (int ni = 0; ni < 4; ++ni)
                    acc[mi][ni] = __builtin_amdgcn_mfma_f32_16x16x32_bf16(
                        a[mi], b[ni], acc[mi][ni], 0, 0, 0);
        }
        asm volatile("s_waitcnt vmcnt(0)" ::: "memory");
        __syncthreads();
        cur ^= 1;
    }
#undef STAGE

    const int crow = (lane >> 4) * 4;
    const int ccol = lane & 15;
    float bcol[4];
#pragma unroll
    for (int ni = 0; ni < 4; ++ni) bcol[ni] = bias[n0 + wc + ni * 16 + ccol];
#pragma unroll
    for (int mi = 0; mi < 4; ++mi) {
#pragma unroll
        for (int j = 0; j < 4; ++j) {
            const int row = m0 + wr + mi * 16 + crow + j;
            if (row < M) {
                unsigned short* pc = C + (size_t)row * ldc + n0 + wc + ccol;
#pragma unroll
                for (int ni = 0; ni < 4; ++ni)
                    pc[ni * 16] = f2bf(acc[mi][ni][j] + bcol[ni]);
            }
        }
    }
}

// ---------------------------------------------------------------------------
// Small fp32 GEMM for edge features (K=8), rows permuted by eid (CSR order)
// ---------------------------------------------------------------------------
template <int K, int N, int TM>
__global__ void gemm_ef(const float* __restrict__ A, const float* __restrict__ W,
                        const int* __restrict__ eid, unsigned short* __restrict__ out) {
    __shared__ float As[TM][K];
    const int m0 = blockIdx.x * TM;
    const int tid = threadIdx.x;
    for (int idx = tid; idx < TM * K; idx += N) {
        int r = idx / K, k = idx - r * K;
        As[r][k] = A[(size_t)eid[m0 + r] * K + k];
    }
    __syncthreads();
    float acc[TM] = {};
    for (int k = 0; k < K; ++k) {
        const float w = W[k * N + tid];
#pragma unroll
        for (int r = 0; r < TM; ++r) acc[r] += As[r][k] * w;
    }
#pragma unroll
    for (int r = 0; r < TM; ++r) out[(size_t)(m0 + r) * N + tid] = f2bf(acc[r]);
}

// ---------------------------------------------------------------------------
// Batched CSR build for all 4 relations (6 launches, ONE atomic pass).
// hist_rank4 captures each edge's within-node rank from the histogram atomic
// (return value), so the final placement pass needs NO atomics (device-scope
// atomics are memory-side write-through on MI355X -> each costs an HBM RMW).
// ---------------------------------------------------------------------------
#define NB_P 49
#define NB_S 49
#define NB_O 5
#define NB_A 2
#define NTOT 107000          // 50000+50000+5000+2000
#define ETOT 660000

__global__ void zero4(int* __restrict__ p, int n) {
    int i = blockIdx.x * blockDim.x + threadIdx.x;
    if (i < n) p[i] = 0;
}

__global__ void hist_rank4(const int* __restrict__ dP, const int* __restrict__ dS,
                           const int* __restrict__ dO, const int* __restrict__ dA,
                           int* __restrict__ cP, int* __restrict__ cS,
                           int* __restrict__ cO, int* __restrict__ cA,
                           int* __restrict__ rk) {
    int i = blockIdx.x * blockDim.x + threadIdx.x;
    if (i < 200000)      rk[i] = atomicAdd(&cP[dP[i]], 1);
    else if (i < 400000) rk[i] = atomicAdd(&cS[dS[i - 200000]], 1);
    else if (i < 600000) rk[i] = atomicAdd(&cO[dO[i - 400000]], 1);
    else if (i < ETOT)   rk[i] = atomicAdd(&cA[dA[i - 600000]], 1);
}

__global__ void scan_blk4(const int* __restrict__ cP, const int* __restrict__ cS,
                          const int* __restrict__ cO, const int* __restrict__ cA,
                          int* __restrict__ pP, int* __restrict__ pS,
                          int* __restrict__ pO, int* __restrict__ pA,
                          int* __restrict__ bsum) {
    __shared__ int smem[1024];
    int b = blockIdx.x;
    const int* cnt; int* ptr; int n; int bo;
    if (b < NB_P)                { cnt = cP; ptr = pP; n = 50000; bo = 0; }
    else if (b < NB_P + NB_S)    { cnt = cS; ptr = pS; n = 50000; bo = 64;  b -= NB_P; }
    else if (b < NB_P + NB_S + NB_O) { cnt = cO; ptr = pO; n = 5000; bo = 128; b -= NB_P + NB_S; }
    else                         { cnt = cA; ptr = pA; n = 2000; bo = 192; b -= NB_P + NB_S + NB_O; }
    const int tid = threadIdx.x;
    const int i = b * 1024 + tid;
    const int v = (i < n) ? cnt[i] : 0;
    smem[tid] = v;
    __syncthreads();
    for (int o = 1; o < 1024; o <<= 1) {
        int t = (tid >= o) ? smem[tid - o] : 0;
        __syncthreads();
        smem[tid] += t;
        __syncthreads();
    }
    if (i < n) ptr[i] = smem[tid] - v;
    if (tid == 1023) bsum[bo + b] = smem[1023];
}

__global__ void scan_tops4(const int* __restrict__ bsum, int* __restrict__ boff,
                           int* __restrict__ pP, int* __restrict__ pS,
                           int* __restrict__ pO, int* __restrict__ pA) {
    __shared__ int smem[1024];
    const int seg = blockIdx.x;
    const int nb = (seg < 2) ? 49 : (seg == 2 ? 5 : 2);
    const int off = seg * 64;
    int* ptr_n = (seg == 0) ? pP + 50000 : (seg == 1) ? pS + 50000
               : (seg == 2) ? pO + 5000 : pA + 2000;
    const int tid = threadIdx.x;
    const int v = (tid < nb) ? bsum[off + tid] : 0;
    smem[tid] = v;
    __syncthreads();
    for (int o = 1; o < 1024; o <<= 1) {
        int t = (tid >= o) ? smem[tid - o] : 0;
        __syncthreads();
        smem[tid] += t;
        __syncthreads();
    }
    if (tid < nb) boff[off + tid] = smem[tid] - v;
    if (tid == 1023) *ptr_n = smem[1023];
}

__global__ void scan_add4(int* __restrict__ pP, int* __restrict__ pS,
                          int* __restrict__ pO, int* __restrict__ pA,
                          const int* __restrict__ boff) {
    int i = blockIdx.x * blockDim.x + threadIdx.x;
    int* ptr; int loc; int off;
    if (i < 50000)       { ptr = pP; loc = i;          off = 0; }
    else if (i < 100000) { ptr = pS; loc = i - 50000;  off = 64; }
    else if (i < 105000) { ptr = pO; loc = i - 100000; off = 128; }
    else if (i < NTOT)   { ptr = pA; loc = i - 105000; off = 192; }
    else return;
    ptr[loc] += boff[off + (loc >> 10)];
}

// atomic-free placement: pos = ptr[dst] + rank (ranks are unique per node)
__global__ void scatter_nr4(const int* __restrict__ sP, const int* __restrict__ dP,
                            const int* __restrict__ sS, const int* __restrict__ dS,
                            const int* __restrict__ sO, const int* __restrict__ dO,
                            const int* __restrict__ sA, const int* __restrict__ dA,
                            const int* __restrict__ pP, const int* __restrict__ pS,
                            const int* __restrict__ pO, const int* __restrict__ pA,
                            const int* __restrict__ rk,
                            int* __restrict__ srP, int* __restrict__ srS,
                            int* __restrict__ srO, int* __restrict__ srA,
                            int* __restrict__ eiA) {
    int i = blockIdx.x * blockDim.x + threadIdx.x;
    if (i < 200000) {
        srP[pP[dP[i]] + rk[i]] = sP[i];
    } else if (i < 400000) {
        const int j = i - 200000;
        srS[pS[dS[j]] + rk[i]] = sS[j];
    } else if (i < 600000) {
        const int j = i - 400000;
        srO[pO[dO[j]] + rk[i]] = sO[j];
    } else if (i < ETOT) {
        const int j = i - 600000;
        const int pos = pA[dA[j]] + rk[i];
        srA[pos] = sA[j];
        eiA[pos] = j;
    }
}

// ---------------------------------------------------------------------------
// csr_serial2: TWO nodes per wave (32 lanes each), single-pass online softmax
// (verified round 10).  For LOW degree C=256 convs.
// ---------------------------------------------------------------------------
template <int C>
__global__ void csr_serial2(const unsigned short* __restrict__ xl, int ldl,
                            const unsigned short* __restrict__ xr, int ldr,
                            const float* __restrict__ att,
                            const int* __restrict__ ptr, const int* __restrict__ srcs,
                            float* __restrict__ out, int n) {
    const int tid = threadIdx.x;
    const int node = blockIdx.x * (blockDim.x >> 5) + (tid >> 5);
    if (node >= n) return;
    const int gl = tid & 31;             // lane within 32-lane group
    const int beg = ptr[node], end = ptr[node + 1];
    if (beg == end) return;

    constexpr int V = C / 32;            // 8 for C=256
    const int c0 = gl * V;

    float av[V], rvf[V];
    {
        const unsigned short* pr = xr + (size_t)node * ldr + c0;
        unsigned short rv[V];
        *(uint4*)rv = *(const uint4*)pr;
#pragma unroll
        for (int v4 = 0; v4 < V / 4; ++v4)
            *(float4*)(av + v4 * 4) = ((const float4*)(att + c0))[v4];
#pragma unroll
        for (int v = 0; v < V; ++v) rvf[v] = bf2f(rv[v]);
    }

    float runM = -3.0e38f, runS = 0.0f;
    float acc[V] = {};

    unsigned short lv[V];
    {
        const unsigned short* pl = xl + (size_t)srcs[beg] * ldl + c0;
        *(uint4*)lv = *(const uint4*)pl;
    }

    for (int j = beg; j < end; ++j) {
        float cf[V];
#pragma unroll
        for (int v = 0; v < V; ++v) cf[v] = bf2f(lv[v]);
        if (j + 1 < end) {                      // prefetch next row
            const unsigned short* pl = xl + (size_t)srcs[j + 1] * ldl + c0;
            *(uint4*)lv = *(const uint4*)pl;
        }

        float part = 0.0f;
#pragma unroll
        for (int v = 0; v < V; ++v) {
            float m = cf[v] + rvf[v];
            m = (m >= 0.0f) ? m : 0.2f * m;
            part += m * av[v];
        }
        // 5-step reduce within the 32-lane group (xor<32 never crosses halves)
        part += __shfl_xor(part, 1, 64);
        part += __shfl_xor(part, 2, 64);
        part += __shfl_xor(part, 4, 64);
        part += __shfl_xor(part, 8, 64);
        part += __shfl_xor(part, 16, 64);

        // branch-free online softmax (group-uniform values)
        const float newM = fmaxf(runM, part);
        const float sc = __expf(runM - newM);   // 1 if no move, 0 on first edge
        const float e1 = __expf(part - newM);
        runS = runS * sc + e1;
        runM = newM;
#pragma unroll
        for (int v = 0; v < V; ++v) acc[v] = acc[v] * sc + e1 * cf[v];
    }

    const float inv = 1.0f / fmaxf(runS, 1e-16f);
    float* po = out + (size_t)node * C + c0;
#pragma unroll
    for (int v4 = 0; v4 < V / 4; ++v4) {
        float4 o = ((float4*)po)[v4];
        o.x += acc[v4 * 4 + 0] * inv;
        o.y += acc[v4 * 4 + 1] * inv;
        o.z += acc[v4 * 4 + 2] * inv;
        o.w += acc[v4 * 4 + 3] * inv;
        ((float4*)po)[v4] = o;
    }
}

// ---------------------------------------------------------------------------
// csr_grp: 16-lane-group version (4 edges in flight), one wave per node
// (verified round 8).  For HIGH degree (o2m deg~40, m2a deg~30).
// ---------------------------------------------------------------------------
template <int C, bool HAS_EF>
__global__ void csr_grp(const unsigned short* __restrict__ xl, int ldl,
                        const unsigned short* __restrict__ xr, int ldr,
                        const unsigned short* __restrict__ ef,
                        const float* __restrict__ att,
                        const int* __restrict__ ptr, const int* __restrict__ srcs,
                        float* __restrict__ out, int n) {
    const int node = blockIdx.x * (blockDim.x >> 6) + (threadIdx.x >> 6);
    if (node >= n) return;
    const int lane = threadIdx.x & 63;
    const int grp  = lane >> 4;          // edge slot within chunk (0..3)
    const int sl   = lane & 15;          // channel-group lane
    const int beg = ptr[node], end = ptr[node + 1];
    if (beg == end) return;

    constexpr int W = C / 16;            // channels per lane (8 for C=128)
    const int c0 = sl * W;

    float av[W], rvf[W];
    {
        const unsigned short* pr = xr + (size_t)node * ldr + c0;
        unsigned short rv[W];
        *(uint4*)rv = *(const uint4*)pr;
        if constexpr (W == 16) *(uint4*)(rv + 8) = *(const uint4*)(pr + 8);
#pragma unroll
        for (int v4 = 0; v4 < W / 4; ++v4)
            *(float4*)(av + v4 * 4) = ((const float4*)(att + c0))[v4];
#pragma unroll
        for (int v = 0; v < W; ++v) rvf[v] = bf2f(rv[v]);
    }

    float runM = -3.0e38f, runS = 0.0f;
    float acc[W] = {};

    for (int cb = beg; cb < end; cb += 4) {
        const int j = cb + grp;
        const bool act = (j < end);
        const int js = act ? j : end - 1;
        const int s = srcs[js];

        const unsigned short* pl = xl + (size_t)s * ldl + c0;
        unsigned short lv[W];
        *(uint4*)lv = *(const uint4*)pl;
        if constexpr (W == 16) *(uint4*)(lv + 8) = *(const uint4*)(pl + 8);
        float cf[W];
#pragma unroll
        for (int v = 0; v < W; ++v) cf[v] = bf2f(lv[v]);

        float part = 0.0f;
        if constexpr (HAS_EF) {
            unsigned short efv[W];
            const unsigned short* pe = ef + (size_t)js * C + c0;
            *(uint4*)efv = *(const uint4*)pe;
            if constexpr (W == 16) *(uint4*)(efv + 8) = *(const uint4*)(pe + 8);
#pragma unroll
            for (int v = 0; v < W; ++v) {
                float m = cf[v] + rvf[v] + bf2f(efv[v]);
                m = (m >= 0.0f) ? m : 0.2f * m;
                part += m * av[v];
            }
        } else {
#pragma unroll
            for (int v = 0; v < W; ++v) {
                float m = cf[v] + rvf[v];
                m = (m >= 0.0f) ? m : 0.2f * m;
                part += m * av[v];
            }
        }
        part += __shfl_xor(part, 1, 64);
        part += __shfl_xor(part, 2, 64);
        part += __shfl_xor(part, 4, 64);
        part += __shfl_xor(part, 8, 64);
        if (!act) part = -3.0e38f;

        float cm = fmaxf(part, __shfl_xor(part, 16, 64));
        cm = fmaxf(cm, __shfl_xor(cm, 32, 64));

        if (cm > runM) {                 // wave-uniform branch
            const float sc = __expf(runM - cm);
            runS *= sc;
#pragma unroll
            for (int v = 0; v < W; ++v) acc[v] *= sc;
            runM = cm;
        }
        const float w = act ? __expf(part - runM) : 0.0f;
        float cs = w + __shfl_xor(w, 16, 64);
        cs += __shfl_xor(cs, 32, 64);
        runS += cs;
#pragma unroll
        for (int v = 0; v < W; ++v) acc[v] += w * cf[v];
    }

#pragma unroll
    for (int v = 0; v < W; ++v) acc[v] += __shfl_xor(acc[v], 16, 64);
#pragma unroll
    for (int v = 0; v < W; ++v) acc[v] += __shfl_xor(acc[v], 32, 64);

    const float inv = 1.0f / fmaxf(runS, 1e-16f);
    if (grp == 0) {
        float* po = out + (size_t)node * C + c0;
#pragma unroll
        for (int v4 = 0; v4 < W / 4; ++v4) {
            float4 o = ((float4*)po)[v4];
            o.x += acc[v4 * 4 + 0] * inv;
            o.y += acc[v4 * 4 + 1] * inv;
            o.z += acc[v4 * 4 + 2] * inv;
            o.w += acc[v4 * 4 + 3] * inv;
            ((float4*)po)[v4] = o;
        }
    }
}

// ---------------------------------------------------------------------------
// Workspace layout (float slots).  Ends ~86.1 MB (ws >= 103.6 MB proven).
// ---------------------------------------------------------------------------
#define F_H      0
#define F_XCOP   12800000
#define F_XCM    19200000
#define F_XCA    19520000
#define F_BTP    19648000
#define F_BTS    19713536
#define F_BTOL   19779072
#define F_BTOR   19795456
#define F_BTML   19803648
#define F_BTMR   19811840
#define F_BIASP  19820032
#define F_BIASS  19820544
#define F_CNT4   19821056    // int[107000]
#define F_BSUM   19928056    // int[256]
#define F_BOFF   19928312    // int[256]
#define F_PTR_P  19928568    // int[50001]
#define F_SRC_P  19978569    // int[200000]
#define F_PTR_S  20178569    // int[50001]
#define F_SRC_S  20228570    // int[200000]
#define F_PTR_O  20428570    // int[5001]
#define F_SRC_O  20433571    // int[200000]
#define F_PTR_A  20633571    // int[2001]
#define F_SRC_A  20635572    // int[60000]
#define F_EID_A  20695572    // int[60000]
#define F_RANK   20755572    // int[660000] -> ends 21,415,572 floats = 85.7 MB

extern "C" void kernel_launch(void* const* d_in, const int* in_sizes, int n_in,
                              void* d_out, int out_size, void* d_ws, size_t ws_size,
                              hipStream_t stream) {
    const float* x_op    = (const float*)d_in[0];
    const float* x_m     = (const float*)d_in[1];
    const float* x_a     = (const float*)d_in[2];
    const int*   ei_pred = (const int*)d_in[3];
    const int*   ei_succ = (const int*)d_in[4];
    const int*   src_o2m = (const int*)d_in[5];
    const int*   dst_o2m = (const int*)d_in[6];
    const int*   src_m2a = (const int*)d_in[7];
    const int*   dst_m2a = (const int*)d_in[8];
    const float* ea_m2a  = (const float*)d_in[9];

    const float* Wl_pred = (const float*)d_in[10];
    const float* bl_pred = (const float*)d_in[11];
    const float* Wr_pred = (const float*)d_in[12];
    const float* br_pred = (const float*)d_in[13];
    const float* att_pred= (const float*)d_in[14];
    const float* b_pred  = (const float*)d_in[15];

    const float* Wl_succ = (const float*)d_in[16];
    const float* bl_succ = (const float*)d_in[17];
    const float* Wr_succ = (const float*)d_in[18];
    const float* br_succ = (const float*)d_in[19];
    const float* att_succ= (const float*)d_in[20];
    const float* b_succ  = (const float*)d_in[21];

    const float* Wl_o2m  = (const float*)d_in[22];
    const float* bl_o2m  = (const float*)d_in[23];
    const float* Wr_o2m  = (const float*)d_in[24];
    const float* br_o2m  = (const float*)d_in[25];
    const float* att_o2m = (const float*)d_in[26];
    const float* b_o2m   = (const float*)d_in[27];

    const float* Wl_m2a  = (const float*)d_in[28];
    const float* bl_m2a  = (const float*)d_in[29];
    const float* Wr_m2a  = (const float*)d_in[30];
    const float* br_m2a  = (const float*)d_in[31];
    const float* att_m2a = (const float*)d_in[32];
    const float* b_m2a   = (const float*)d_in[33];
    const float* We_m2a  = (const float*)d_in[34];

    float* ws = (float*)d_ws;
    unsigned short* H     = (unsigned short*)(ws + F_H);
    unsigned short* xc_op = (unsigned short*)(ws + F_XCOP);
    unsigned short* xc_m  = (unsigned short*)(ws + F_XCM);
    unsigned short* xc_a  = (unsigned short*)(ws + F_XCA);
    unsigned short* BtP   = (unsigned short*)(ws + F_BTP);
    unsigned short* BtS   = (unsigned short*)(ws + F_BTS);
    unsigned short* BtOL  = (unsigned short*)(ws + F_BTOL);
    unsigned short* BtOR  = (unsigned short*)(ws + F_BTOR);
    unsigned short* BtML  = (unsigned short*)(ws + F_BTML);
    unsigned short* BtMR  = (unsigned short*)(ws + F_BTMR);
    float* biasP = ws + F_BIASP;
    float* biasS = ws + F_BIASS;
    int* cntP = (int*)(ws + F_CNT4);
    int* cntS = cntP + 50000;
    int* cntO = cntP + 100000;
    int* cntA = cntP + 105000;
    int* bsum = (int*)(ws + F_BSUM);
    int* boff = (int*)(ws + F_BOFF);
    int* ptrP = (int*)(ws + F_PTR_P); int* srcP = (int*)(ws + F_SRC_P);
    int* ptrS = (int*)(ws + F_PTR_S); int* srcS = (int*)(ws + F_SRC_S);
    int* ptrO = (int*)(ws + F_PTR_O); int* srcO = (int*)(ws + F_SRC_O);
    int* ptrA = (int*)(ws + F_PTR_A); int* srcA = (int*)(ws + F_SRC_A);
    int* eidA = (int*)(ws + F_EID_A);
    int* rk   = (int*)(ws + F_RANK);

    float* out_op = (float*)d_out + OUT_OP_OFF;
    float* out_m  = (float*)d_out + OUT_M_OFF;
    float* out_a  = (float*)d_out + OUT_A_OFF;

    // ---- batched CSR build (6 launches, one atomic pass) ----
    zero4<<<(NTOT + 255) / 256, 256, 0, stream>>>(cntP, NTOT);
    hist_rank4<<<(ETOT + 255) / 256, 256, 0, stream>>>(ei_pred + E_OO, ei_succ + E_OO,
                                                       dst_o2m, dst_m2a,
                                                       cntP, cntS, cntO, cntA, rk);
    scan_blk4<<<NB_P + NB_S + NB_O + NB_A, 1024, 0, stream>>>(cntP, cntS, cntO, cntA,
                                                              ptrP, ptrS, ptrO, ptrA, bsum);
    scan_tops4<<<4, 1024, 0, stream>>>(bsum, boff, ptrP, ptrS, ptrO, ptrA);
    scan_add4<<<(NTOT + 255) / 256, 256, 0, stream>>>(ptrP, ptrS, ptrO, ptrA, boff);
    scatter_nr4<<<(ETOT + 255) / 256, 256, 0, stream>>>(
        ei_pred, ei_pred + E_OO, ei_succ, ei_succ + E_OO,
        src_o2m, dst_o2m, src_m2a, dst_m2a,
        ptrP, ptrS, ptrO, ptrA, rk,
        srcP, srcS, srcO, srcA, eidA);

    // ---- fused init + pack (2 launches) ----
    init3<<<(I3_A + 255) / 256, 256, 0, stream>>>(x_op, x_m, x_a, b_pred, b_succ, b_o2m, b_m2a,
                                                  out_op, out_m, out_a, xc_op, xc_m, xc_a);
    pack_all<<<(PK_BS + 255) / 256, 256, 0, stream>>>(
        Wl_pred, Wr_pred, Wl_succ, Wr_succ, Wl_o2m, Wr_o2m, Wl_m2a, Wr_m2a,
        bl_pred, br_pred, bl_succ, br_succ,
        BtP, BtS, BtOL, BtOR, BtML, BtMR, biasP, biasS);

    const int MT_OP = (N_OP + 127) / 128;
    const int MT_M  = (N_M + 127) / 128;
    const int MT_A  = (N_A + 127) / 128;

    // ---------------- conv 1: pred (op->op, C=256), H = [50000][512] ----------------
    mfma_gemm<<<dim3(MT_OP, 4), 256, 0, stream>>>(xc_op, BtP, biasP, H, N_OP, 256, 512);
    csr_serial2<256><<<(N_OP + 7) / 8, 256, 0, stream>>>(H, 512, H + 256, 512,
                                                         att_pred, ptrP, srcP, out_op, N_OP);

    // ---------------- conv 2: succ ----------------
    mfma_gemm<<<dim3(MT_OP, 4), 256, 0, stream>>>(xc_op, BtS, biasS, H, N_OP, 256, 512);
    csr_serial2<256><<<(N_OP + 7) / 8, 256, 0, stream>>>(H, 512, H + 256, 512,
                                                         att_succ, ptrS, srcS, out_op, N_OP);

    // ---------------- conv 3: o2m (op->machine, C=128, deg~40) ----------------
    {
        unsigned short* xlb = H;                 // [50000][128]
        unsigned short* xrb = H + 6400000;       // [5000][128]
        mfma_gemm<<<dim3(MT_OP, 1), 256, 0, stream>>>(xc_op, BtOL, bl_o2m, xlb, N_OP, 256, 128);
        mfma_gemm<<<dim3(MT_M, 1), 256, 0, stream>>>(xc_m, BtOR, br_o2m, xrb, N_M, 128, 128);
        csr_grp<128, false><<<(N_M + 3) / 4, 256, 0, stream>>>(xlb, 128, xrb, 128, nullptr,
                                                               att_o2m, ptrO, srcO, out_m, N_M);
    }

    // ---------------- conv 4: m2a (machine->agv, C=128, deg~30, edge feats) ----------------
    {
        unsigned short* xlb = H;                 // [5000][128]
        unsigned short* xrb = H + 1000000;       // [2000][128]
        unsigned short* efb = H + 2000000;       // [60000][128] CSR-slot order
        mfma_gemm<<<dim3(MT_M, 1), 256, 0, stream>>>(xc_m, BtML, bl_m2a, xlb, N_M, 128, 128);
        mfma_gemm<<<dim3(MT_A, 1), 256, 0, stream>>>(xc_a, BtMR, br_m2a, xrb, N_A, 128, 128);
        gemm_ef<8, 128, 4><<<E_MA / 4, 128, 0, stream>>>(ea_m2a, We_m2a, eidA, efb);
        csr_grp<128, true><<<(N_A + 3) / 4, 256, 0, stream>>>(xlb, 128, xrb, 128, efb,
                                                              att_m2a, ptrA, srcA, out_a, N_A);
    }
}

// Round 12
// 291.846 us; speedup vs baseline: 6.8836x; 1.0579x over previous
//
#include <hip/hip_runtime.h>

// ---------------------------------------------------------------------------
// Problem constants (fixed by setup_inputs)
// ---------------------------------------------------------------------------
#define N_OP   50000
#define N_M    5000
#define N_A    2000
#define C_OP   256
#define C_M    128
#define C_A    128
#define E_OO   200000
#define E_OM   200000
#define E_MA   60000
#define E_DIM  8

#define OUT_OP_OFF 0
#define OUT_M_OFF  (N_OP * C_OP)
#define OUT_A_OFF  (N_OP * C_OP + N_M * C_M)

typedef short bf16x8 __attribute__((ext_vector_type(8)));
typedef float f32x4 __attribute__((ext_vector_type(4)));
typedef __attribute__((address_space(1))) const unsigned gu32;
typedef __attribute__((address_space(3))) unsigned lu32;

__device__ __forceinline__ unsigned short f2bf(float f) {
    unsigned u = __float_as_uint(f);
    unsigned r = (u + 0x7FFFu + ((u >> 16) & 1u)) >> 16;
    return (unsigned short)r;
}
__device__ __forceinline__ float bf2f(unsigned short h) {
    return __uint_as_float(((unsigned)h) << 16);
}

// ---------------------------------------------------------------------------
// Sizing for the fused prep kernel (hist blocks FIRST so atomics start early;
// the BW-bound init/pack blocks fill the CUs while hist waves park on the
// memory-side atomic round-trips).
// ---------------------------------------------------------------------------
#define NTOT 107000          // 50000+50000+5000+2000
#define ETOT 660000

#define I3_OP (N_OP * C_OP / 4)                 // 3,200,000
#define I3_M  (I3_OP + N_M * C_M / 4)           // 3,360,000
#define I3_A  (I3_M + N_A * C_A / 4)            // 3,424,000

#define PK_P   131072
#define PK_S   262144
#define PK_OL  294912
#define PK_OR  311296
#define PK_ML  327680
#define PK_MR  344064
#define PK_BP  344576
#define PK_BS  345088

#define PREP_HIST_BLK ((ETOT + 255) / 256)      // 2579
#define PREP_INIT_BLK (I3_A / 256)              // 13375 (exact)
#define PREP_PACK_BLK (PK_BS / 256)             // 1348 (exact)
#define PREP_TOTAL    (PREP_HIST_BLK + PREP_INIT_BLK + PREP_PACK_BLK)

__device__ __forceinline__ void init_one(const float* __restrict__ x,
                                         const float* __restrict__ b1,
                                         const float* __restrict__ b2,
                                         float* __restrict__ out,
                                         unsigned short* __restrict__ xc,
                                         int i, int cmask) {
    float4 v = ((const float4*)x)[i];
    const int cb = i & cmask;
    float4 b = ((const float4*)b1)[cb];
    if (b2) {
        float4 t = ((const float4*)b2)[cb];
        b.x += t.x; b.y += t.y; b.z += t.z; b.w += t.w;
    }
    float4 o;
    o.x = v.x + b.x; o.y = v.y + b.y; o.z = v.z + b.z; o.w = v.w + b.w;
    ((float4*)out)[i] = o;
    ushort4 r;
    r.x = f2bf(v.x); r.y = f2bf(v.y); r.z = f2bf(v.z); r.w = f2bf(v.w);
    ((ushort4*)xc)[i] = r;
}

__global__ void prep_all(
    // hist args
    const int* __restrict__ dP, const int* __restrict__ dS,
    const int* __restrict__ dO, const int* __restrict__ dA,
    int* __restrict__ cP, int* __restrict__ cS,
    int* __restrict__ cO, int* __restrict__ cA, int* __restrict__ rk,
    // init args
    const float* __restrict__ x_op, const float* __restrict__ x_m,
    const float* __restrict__ x_a,
    const float* __restrict__ bP, const float* __restrict__ bS,
    const float* __restrict__ bO, const float* __restrict__ bA,
    float* __restrict__ out_op, float* __restrict__ out_m, float* __restrict__ out_a,
    unsigned short* __restrict__ xcop, unsigned short* __restrict__ xcm,
    unsigned short* __restrict__ xca,
    // pack args
    const float* __restrict__ WlP, const float* __restrict__ WrP,
    const float* __restrict__ WlS, const float* __restrict__ WrS,
    const float* __restrict__ WOl, const float* __restrict__ WOr,
    const float* __restrict__ WMl, const float* __restrict__ WMr,
    const float* __restrict__ blP, const float* __restrict__ brP,
    const float* __restrict__ blS, const float* __restrict__ brS,
    unsigned short* __restrict__ BtP, unsigned short* __restrict__ BtS,
    unsigned short* __restrict__ BtOL, unsigned short* __restrict__ BtOR,
    unsigned short* __restrict__ BtML, unsigned short* __restrict__ BtMR,
    float* __restrict__ biasP, float* __restrict__ biasS) {
    const int b = blockIdx.x;
    const int tid = threadIdx.x;
    if (b < PREP_HIST_BLK) {
        // ---- histogram with rank capture (one atomic pass) ----
        int i = b * 256 + tid;
        if (i < 200000)      rk[i] = atomicAdd(&cP[dP[i]], 1);
        else if (i < 400000) rk[i] = atomicAdd(&cS[dS[i - 200000]], 1);
        else if (i < 600000) rk[i] = atomicAdd(&cO[dO[i - 400000]], 1);
        else if (i < ETOT)   rk[i] = atomicAdd(&cA[dA[i - 600000]], 1);
    } else if (b < PREP_HIST_BLK + PREP_INIT_BLK) {
        // ---- residual-init + bf16 conversion ----
        int i = (b - PREP_HIST_BLK) * 256 + tid;
        if (i < I3_OP)      init_one(x_op, bP, bS, out_op, xcop, i, 63);
        else if (i < I3_M)  init_one(x_m, bO, nullptr, out_m, xcm, i - I3_OP, 31);
        else                init_one(x_a, bA, nullptr, out_a, xca, i - I3_M, 31);
    } else {
        // ---- weight/bias packing ----
        int i = (b - PREP_HIST_BLK - PREP_INIT_BLK) * 256 + tid;
        if (i < PK_P) {
            int n = i >> 8, k = i & 255;
            BtP[i] = f2bf((n < 256) ? WlP[k * 256 + n] : WrP[k * 256 + (n - 256)]);
        } else if (i < PK_S) {
            int j = i - PK_P; int n = j >> 8, k = j & 255;
            BtS[j] = f2bf((n < 256) ? WlS[k * 256 + n] : WrS[k * 256 + (n - 256)]);
        } else if (i < PK_OL) {
            int j = i - PK_S; int n = j >> 8, k = j & 255;
            BtOL[j] = f2bf(WOl[k * 128 + n]);
        } else if (i < PK_OR) {
            int j = i - PK_OL; int n = j >> 7, k = j & 127;
            BtOR[j] = f2bf(WOr[k * 128 + n]);
        } else if (i < PK_ML) {
            int j = i - PK_OR; int n = j >> 7, k = j & 127;
            BtML[j] = f2bf(WMl[k * 128 + n]);
        } else if (i < PK_MR) {
            int j = i - PK_ML; int n = j >> 7, k = j & 127;
            BtMR[j] = f2bf(WMr[k * 128 + n]);
        } else if (i < PK_BP) {
            int j = i - PK_MR;
            biasP[j] = (j < 256) ? blP[j] : brP[j - 256];
        } else if (i < PK_BS) {
            int j = i - PK_BP;
            biasS[j] = (j < 256) ? blS[j] : brS[j - 256];
        }
    }
}

// ---------------------------------------------------------------------------
// MFMA bf16 GEMM body (verified rounds 5-11): 128x128 tile, BK=64,
// double-buffered, XOR-swizzled LDS.  Refactored to a device function so
// multiple fused kernels share it; LDS passed by reference.
// ---------------------------------------------------------------------------
__device__ __forceinline__ void gload_lds16(const void* g, void* l) {
    __builtin_amdgcn_global_load_lds((gu32*)g, (lu32*)l, 16, 0, 0);
}

__device__ __forceinline__ void gemm_body(
    const unsigned short* __restrict__ A, const unsigned short* __restrict__ Bt,
    const float* __restrict__ bias, unsigned short* __restrict__ C,
    int M, int K, int ldc, int bx, int by,
    unsigned short (&As)[2][128 * 64], unsigned short (&Bs)[2][128 * 64]) {
    const int tid  = threadIdx.x;
    const int lane = tid & 63;
    const int wid  = tid >> 6;
    const int m0   = bx * 128;
    const int n0   = by * 128;

    f32x4 acc[4][4] = {};

    const int srow   = tid >> 3;
    const int scolb  = (tid & 7) * 16;
    const int scole  = (scolb ^ ((srow & 7) << 4)) >> 1;

    int grA[4], grB[4];
#pragma unroll
    for (int i = 0; i < 4; ++i) {
        int gr = m0 + i * 32 + srow;
        grA[i] = (gr < M) ? gr : M - 1;
        grB[i] = n0 + i * 32 + srow;
    }

    const int nt = K >> 6;
    int cur = 0;

#define STAGE(buf, k0)                                                          \
    {                                                                           \
        _Pragma("unroll")                                                       \
        for (int i = 0; i < 4; ++i)                                             \
            gload_lds16(A + (size_t)grA[i] * K + (k0) + scole,                  \
                        &As[buf][i * 2048 + tid * 8]);                          \
        _Pragma("unroll")                                                       \
        for (int i = 0; i < 4; ++i)                                             \
            gload_lds16(Bt + (size_t)grB[i] * K + (k0) + scole,                 \
                        &Bs[buf][i * 2048 + tid * 8]);                          \
    }

    STAGE(0, 0)
    asm volatile("s_waitcnt vmcnt(0)" ::: "memory");
    __syncthreads();

    const int wr = (wid >> 1) * 64;
    const int wc = (wid & 1) * 64;

    for (int t = 0; t < nt; ++t) {
        if (t + 1 < nt) STAGE(cur ^ 1, (t + 1) * 64)
#pragma unroll
        for (int kh = 0; kh < 2; ++kh) {
            const int kob = kh * 64 + (lane >> 4) * 16;
            bf16x8 a[4], b[4];
#pragma unroll
            for (int mi = 0; mi < 4; ++mi) {
                const int row = wr + mi * 16 + (lane & 15);
                a[mi] = *(const bf16x8*)((const char*)As[cur] + row * 128 +
                                         (kob ^ ((row & 7) << 4)));
            }
#pragma unroll
            for (int ni = 0; ni < 4; ++ni) {
                const int row = wc + ni * 16 + (lane & 15);
                b[ni] = *(const bf16x8*)((const char*)Bs[cur] + row * 128 +
                                         (kob ^ ((row & 7) << 4)));
            }
#pragma unroll
            for (int mi = 0; mi < 4; ++mi)
#pragma unroll
                for (int ni = 0; ni < 4; ++ni)
                    acc[mi][ni] = __builtin_amdgcn_mfma_f32_16x16x32_bf16(
                        a[mi], b[ni], acc[mi][ni], 0, 0, 0);
        }
        asm volatile("s_waitcnt vmcnt(0)" ::: "memory");
        __syncthreads();
        cur ^= 1;
    }
#undef STAGE

    const int crow = (lane >> 4) * 4;
    const int ccol = lane & 15;
    float bcol[4];
#pragma unroll
    for (int ni = 0; ni < 4; ++ni) bcol[ni] = bias[n0 + wc + ni * 16 + ccol];
#pragma unroll
    for (int mi = 0; mi < 4; ++mi) {
#pragma unroll
        for (int j = 0; j < 4; ++j) {
            const int row = m0 + wr + mi * 16 + crow + j;
            if (row < M) {
                unsigned short* pc = C + (size_t)row * ldc + n0 + wc + ccol;
#pragma unroll
                for (int ni = 0; ni < 4; ++ni)
                    pc[ni * 16] = f2bf(acc[mi][ni][j] + bcol[ni]);
            }
        }
    }
}

// plain GEMM (conv 2)
__global__ __launch_bounds__(256) void mfma_gemm(
    const unsigned short* __restrict__ A, const unsigned short* __restrict__ Bt,
    const float* __restrict__ bias, unsigned short* __restrict__ C,
    int M, int K, int ldc) {
    __shared__ unsigned short As[2][128 * 64];
    __shared__ unsigned short Bs[2][128 * 64];
    gemm_body(A, Bt, bias, C, M, K, ldc, blockIdx.x, blockIdx.y, As, Bs);
}

// conv-1 GEMM with the atomic-free CSR scatter fused into extra blocks
// (scatter only needs ptr/rk from the scans; GEMM hides its latency).
#define SCAT_XBLK 645
__global__ __launch_bounds__(256) void gemm_scat(
    const unsigned short* __restrict__ A, const unsigned short* __restrict__ Bt,
    const float* __restrict__ bias, unsigned short* __restrict__ C,
    int M, int K, int ldc, int mt,
    const int* __restrict__ sP, const int* __restrict__ dP,
    const int* __restrict__ sS, const int* __restrict__ dS,
    const int* __restrict__ sO, const int* __restrict__ dO,
    const int* __restrict__ sA, const int* __restrict__ dA,
    const int* __restrict__ pP, const int* __restrict__ pS,
    const int* __restrict__ pO, const int* __restrict__ pA,
    const int* __restrict__ rk,
    int* __restrict__ srP, int* __restrict__ srS,
    int* __restrict__ srO, int* __restrict__ srA, int* __restrict__ eiA) {
    __shared__ unsigned short As[2][128 * 64];
    __shared__ unsigned short Bs[2][128 * 64];
    if ((int)blockIdx.x < mt) {
        gemm_body(A, Bt, bias, C, M, K, ldc, blockIdx.x, blockIdx.y, As, Bs);
    } else {
        const int i = (((int)blockIdx.x - mt) * 4 + (int)blockIdx.y) * 256 + (int)threadIdx.x;
        if (i < 200000) {
            srP[pP[dP[i]] + rk[i]] = sP[i];
        } else if (i < 400000) {
            const int j = i - 200000;
            srS[pS[dS[j]] + rk[i]] = sS[j];
        } else if (i < 600000) {
            const int j = i - 400000;
            srO[pO[dO[j]] + rk[i]] = sO[j];
        } else if (i < ETOT) {
            const int j = i - 600000;
            const int pos = pA[dA[j]] + rk[i];
            srA[pos] = sA[j];
            eiA[pos] = j;
        }
    }
}

// two GEMMs batched in one launch (conv 3: o2m L + R)
__global__ __launch_bounds__(256) void gemm_pair(
    const unsigned short* A1, const unsigned short* Bt1, const float* b1,
    unsigned short* C1, int M1, int K1, int l1, int n1,
    const unsigned short* A2, const unsigned short* Bt2, const float* b2,
    unsigned short* C2, int M2, int K2, int l2) {
    __shared__ unsigned short As[2][128 * 64];
    __shared__ unsigned short Bs[2][128 * 64];
    const unsigned short *A, *Bt; const float* bi; unsigned short* C;
    int M, K, ldc, bx;
    if ((int)blockIdx.x < n1) { A = A1; Bt = Bt1; bi = b1; C = C1; M = M1; K = K1; ldc = l1; bx = blockIdx.x; }
    else                      { A = A2; Bt = Bt2; bi = b2; C = C2; M = M2; K = K2; ldc = l2; bx = blockIdx.x - n1; }
    gemm_body(A, Bt, bi, C, M, K, ldc, bx, blockIdx.y, As, Bs);
}

// conv 4: two GEMMs + edge-feature GEMM (K=8, CSR-permuted rows) in one launch
__global__ __launch_bounds__(256) void gemm_tri(
    const unsigned short* A1, const unsigned short* Bt1, const float* b1,
    unsigned short* C1, int M1, int K1, int n1,
    const unsigned short* A2, const unsigned short* Bt2, const float* b2,
    unsigned short* C2, int M2, int K2, int n12,
    const float* __restrict__ ea, const float* __restrict__ We,
    const int* __restrict__ eid, unsigned short* __restrict__ efo) {
    __shared__ unsigned short As[2][128 * 64];
    __shared__ unsigned short Bs[2][128 * 64];
    __shared__ float Ef[8][8];
    const int b = blockIdx.x;
    if (b < n12) {
        const unsigned short *A, *Bt; const float* bi; unsigned short* C;
        int M, K, bx;
        if (b < n1) { A = A1; Bt = Bt1; bi = b1; C = C1; M = M1; K = K1; bx = b; }
        else        { A = A2; Bt = Bt2; bi = b2; C = C2; M = M2; K = K2; bx = b - n1; }
        gemm_body(A, Bt, bi, C, M, K, 128, bx, 0, As, Bs);
    } else {
        const int eb = b - n12;          // 8 edges per block
        const int m0 = eb * 8;
        const int tid = threadIdx.x;
        if (tid < 64) {
            int r = tid >> 3, k = tid & 7;
            Ef[r][k] = ea[(size_t)eid[m0 + r] * 8 + k];
        }
        __syncthreads();
        const int col = tid & 127, half = tid >> 7;
        float acc[4] = {};
        for (int k = 0; k < 8; ++k) {
            const float w = We[k * 128 + col];
#pragma unroll
            for (int r = 0; r < 4; ++r) acc[r] += Ef[half * 4 + r][k] * w;
        }
#pragma unroll
        for (int r = 0; r < 4; ++r)
            efo[(size_t)(m0 + half * 4 + r) * 128 + col] = f2bf(acc[r]);
    }
}

// ---------------------------------------------------------------------------
// CSR scan chain (verified rounds 4-11)
// ---------------------------------------------------------------------------
#define NB_P 49
#define NB_S 49
#define NB_O 5
#define NB_A 2

__global__ void zero4(int* __restrict__ p, int n) {
    int i = blockIdx.x * blockDim.x + threadIdx.x;
    if (i < n) p[i] = 0;
}

__global__ void scan_blk4(const int* __restrict__ cP, const int* __restrict__ cS,
                          const int* __restrict__ cO, const int* __restrict__ cA,
                          int* __restrict__ pP, int* __restrict__ pS,
                          int* __restrict__ pO, int* __restrict__ pA,
                          int* __restrict__ bsum) {
    __shared__ int smem[1024];
    int b = blockIdx.x;
    const int* cnt; int* ptr; int n; int bo;
    if (b < NB_P)                { cnt = cP; ptr = pP; n = 50000; bo = 0; }
    else if (b < NB_P + NB_S)    { cnt = cS; ptr = pS; n = 50000; bo = 64;  b -= NB_P; }
    else if (b < NB_P + NB_S + NB_O) { cnt = cO; ptr = pO; n = 5000; bo = 128; b -= NB_P + NB_S; }
    else                         { cnt = cA; ptr = pA; n = 2000; bo = 192; b -= NB_P + NB_S + NB_O; }
    const int tid = threadIdx.x;
    const int i = b * 1024 + tid;
    const int v = (i < n) ? cnt[i] : 0;
    smem[tid] = v;
    __syncthreads();
    for (int o = 1; o < 1024; o <<= 1) {
        int t = (tid >= o) ? smem[tid - o] : 0;
        __syncthreads();
        smem[tid] += t;
        __syncthreads();
    }
    if (i < n) ptr[i] = smem[tid] - v;
    if (tid == 1023) bsum[bo + b] = smem[1023];
}

__global__ void scan_tops4(const int* __restrict__ bsum, int* __restrict__ boff,
                           int* __restrict__ pP, int* __restrict__ pS,
                           int* __restrict__ pO, int* __restrict__ pA) {
    __shared__ int smem[1024];
    const int seg = blockIdx.x;
    const int nb = (seg < 2) ? 49 : (seg == 2 ? 5 : 2);
    const int off = seg * 64;
    int* ptr_n = (seg == 0) ? pP + 50000 : (seg == 1) ? pS + 50000
               : (seg == 2) ? pO + 5000 : pA + 2000;
    const int tid = threadIdx.x;
    const int v = (tid < nb) ? bsum[off + tid] : 0;
    smem[tid] = v;
    __syncthreads();
    for (int o = 1; o < 1024; o <<= 1) {
        int t = (tid >= o) ? smem[tid - o] : 0;
        __syncthreads();
        smem[tid] += t;
        __syncthreads();
    }
    if (tid < nb) boff[off + tid] = smem[tid] - v;
    if (tid == 1023) *ptr_n = smem[1023];
}

__global__ void scan_add4(int* __restrict__ pP, int* __restrict__ pS,
                          int* __restrict__ pO, int* __restrict__ pA,
                          const int* __restrict__ boff) {
    int i = blockIdx.x * blockDim.x + threadIdx.x;
    int* ptr; int loc; int off;
    if (i < 50000)       { ptr = pP; loc = i;          off = 0; }
    else if (i < 100000) { ptr = pS; loc = i - 50000;  off = 64; }
    else if (i < 105000) { ptr = pO; loc = i - 100000; off = 128; }
    else if (i < NTOT)   { ptr = pA; loc = i - 105000; off = 192; }
    else return;
    ptr[loc] += boff[off + (loc >> 10)];
}

// ---------------------------------------------------------------------------
// csr_serial2: TWO nodes per wave (32 lanes each), single-pass online softmax
// (verified round 10).  For LOW degree C=256 convs.
// ---------------------------------------------------------------------------
template <int C>
__global__ void csr_serial2(const unsigned short* __restrict__ xl, int ldl,
                            const unsigned short* __restrict__ xr, int ldr,
                            const float* __restrict__ att,
                            const int* __restrict__ ptr, const int* __restrict__ srcs,
                            float* __restrict__ out, int n) {
    const int tid = threadIdx.x;
    const int node = blockIdx.x * (blockDim.x >> 5) + (tid >> 5);
    if (node >= n) return;
    const int gl = tid & 31;
    const int beg = ptr[node], end = ptr[node + 1];
    if (beg == end) return;

    constexpr int V = C / 32;
    const int c0 = gl * V;

    float av[V], rvf[V];
    {
        const unsigned short* pr = xr + (size_t)node * ldr + c0;
        unsigned short rv[V];
        *(uint4*)rv = *(const uint4*)pr;
#pragma unroll
        for (int v4 = 0; v4 < V / 4; ++v4)
            *(float4*)(av + v4 * 4) = ((const float4*)(att + c0))[v4];
#pragma unroll
        for (int v = 0; v < V; ++v) rvf[v] = bf2f(rv[v]);
    }

    float runM = -3.0e38f, runS = 0.0f;
    float acc[V] = {};

    unsigned short lv[V];
    {
        const unsigned short* pl = xl + (size_t)srcs[beg] * ldl + c0;
        *(uint4*)lv = *(const uint4*)pl;
    }

    for (int j = beg; j < end; ++j) {
        float cf[V];
#pragma unroll
        for (int v = 0; v < V; ++v) cf[v] = bf2f(lv[v]);
        if (j + 1 < end) {
            const unsigned short* pl = xl + (size_t)srcs[j + 1] * ldl + c0;
            *(uint4*)lv = *(const uint4*)pl;
        }

        float part = 0.0f;
#pragma unroll
        for (int v = 0; v < V; ++v) {
            float m = cf[v] + rvf[v];
            m = (m >= 0.0f) ? m : 0.2f * m;
            part += m * av[v];
        }
        part += __shfl_xor(part, 1, 64);
        part += __shfl_xor(part, 2, 64);
        part += __shfl_xor(part, 4, 64);
        part += __shfl_xor(part, 8, 64);
        part += __shfl_xor(part, 16, 64);

        const float newM = fmaxf(runM, part);
        const float sc = __expf(runM - newM);
        const float e1 = __expf(part - newM);
        runS = runS * sc + e1;
        runM = newM;
#pragma unroll
        for (int v = 0; v < V; ++v) acc[v] = acc[v] * sc + e1 * cf[v];
    }

    const float inv = 1.0f / fmaxf(runS, 1e-16f);
    float* po = out + (size_t)node * C + c0;
#pragma unroll
    for (int v4 = 0; v4 < V / 4; ++v4) {
        float4 o = ((float4*)po)[v4];
        o.x += acc[v4 * 4 + 0] * inv;
        o.y += acc[v4 * 4 + 1] * inv;
        o.z += acc[v4 * 4 + 2] * inv;
        o.w += acc[v4 * 4 + 3] * inv;
        ((float4*)po)[v4] = o;
    }
}

// ---------------------------------------------------------------------------
// csr_grp: 16-lane-group version (4 edges in flight), one wave per node
// (verified round 8).  For HIGH degree (o2m deg~40, m2a deg~30).
// ---------------------------------------------------------------------------
template <int C, bool HAS_EF>
__global__ void csr_grp(const unsigned short* __restrict__ xl, int ldl,
                        const unsigned short* __restrict__ xr, int ldr,
                        const unsigned short* __restrict__ ef,
                        const float* __restrict__ att,
                        const int* __restrict__ ptr, const int* __restrict__ srcs,
                        float* __restrict__ out, int n) {
    const int node = blockIdx.x * (blockDim.x >> 6) + (threadIdx.x >> 6);
    if (node >= n) return;
    const int lane = threadIdx.x & 63;
    const int grp  = lane >> 4;
    const int sl   = lane & 15;
    const int beg = ptr[node], end = ptr[node + 1];
    if (beg == end) return;

    constexpr int W = C / 16;
    const int c0 = sl * W;

    float av[W], rvf[W];
    {
        const unsigned short* pr = xr + (size_t)node * ldr + c0;
        unsigned short rv[W];
        *(uint4*)rv = *(const uint4*)pr;
        if constexpr (W == 16) *(uint4*)(rv + 8) = *(const uint4*)(pr + 8);
#pragma unroll
        for (int v4 = 0; v4 < W / 4; ++v4)
            *(float4*)(av + v4 * 4) = ((const float4*)(att + c0))[v4];
#pragma unroll
        for (int v = 0; v < W; ++v) rvf[v] = bf2f(rv[v]);
    }

    float runM = -3.0e38f, runS = 0.0f;
    float acc[W] = {};

    for (int cb = beg; cb < end; cb += 4) {
        const int j = cb + grp;
        const bool act = (j < end);
        const int js = act ? j : end - 1;
        const int s = srcs[js];

        const unsigned short* pl = xl + (size_t)s * ldl + c0;
        unsigned short lv[W];
        *(uint4*)lv = *(const uint4*)pl;
        if constexpr (W == 16) *(uint4*)(lv + 8) = *(const uint4*)(pl + 8);
        float cf[W];
#pragma unroll
        for (int v = 0; v < W; ++v) cf[v] = bf2f(lv[v]);

        float part = 0.0f;
        if constexpr (HAS_EF) {
            unsigned short efv[W];
            const unsigned short* pe = ef + (size_t)js * C + c0;
            *(uint4*)efv = *(const uint4*)pe;
            if constexpr (W == 16) *(uint4*)(efv + 8) = *(const uint4*)(pe + 8);
#pragma unroll
            for (int v = 0; v < W; ++v) {
                float m = cf[v] + rvf[v] + bf2f(efv[v]);
                m = (m >= 0.0f) ? m : 0.2f * m;
                part += m * av[v];
            }
        } else {
#pragma unroll
            for (int v = 0; v < W; ++v) {
                float m = cf[v] + rvf[v];
                m = (m >= 0.0f) ? m : 0.2f * m;
                part += m * av[v];
            }
        }
        part += __shfl_xor(part, 1, 64);
        part += __shfl_xor(part, 2, 64);
        part += __shfl_xor(part, 4, 64);
        part += __shfl_xor(part, 8, 64);
        if (!act) part = -3.0e38f;

        float cm = fmaxf(part, __shfl_xor(part, 16, 64));
        cm = fmaxf(cm, __shfl_xor(cm, 32, 64));

        if (cm > runM) {
            const float sc = __expf(runM - cm);
            runS *= sc;
#pragma unroll
            for (int v = 0; v < W; ++v) acc[v] *= sc;
            runM = cm;
        }
        const float w = act ? __expf(part - runM) : 0.0f;
        float cs = w + __shfl_xor(w, 16, 64);
        cs += __shfl_xor(cs, 32, 64);
        runS += cs;
#pragma unroll
        for (int v = 0; v < W; ++v) acc[v] += w * cf[v];
    }

#pragma unroll
    for (int v = 0; v < W; ++v) acc[v] += __shfl_xor(acc[v], 16, 64);
#pragma unroll
    for (int v = 0; v < W; ++v) acc[v] += __shfl_xor(acc[v], 32, 64);

    const float inv = 1.0f / fmaxf(runS, 1e-16f);
    if (grp == 0) {
        float* po = out + (size_t)node * C + c0;
#pragma unroll
        for (int v4 = 0; v4 < W / 4; ++v4) {
            float4 o = ((float4*)po)[v4];
            o.x += acc[v4 * 4 + 0] * inv;
            o.y += acc[v4 * 4 + 1] * inv;
            o.z += acc[v4 * 4 + 2] * inv;
            o.w += acc[v4 * 4 + 3] * inv;
            ((float4*)po)[v4] = o;
        }
    }
}

// ---------------------------------------------------------------------------
// Workspace layout (float slots).  Ends ~85.7 MB (ws >= 103.6 MB proven).
// ---------------------------------------------------------------------------
#define F_H      0
#define F_XCOP   12800000
#define F_XCM    19200000
#define F_XCA    19520000
#define F_BTP    19648000
#define F_BTS    19713536
#define F_BTOL   19779072
#define F_BTOR   19795456
#define F_BTML   19803648
#define F_BTMR   19811840
#define F_BIASP  19820032
#define F_BIASS  19820544
#define F_CNT4   19821056    // int[107000]
#define F_BSUM   19928056    // int[256]
#define F_BOFF   19928312    // int[256]
#define F_PTR_P  19928568    // int[50001]
#define F_SRC_P  19978569    // int[200000]
#define F_PTR_S  20178569    // int[50001]
#define F_SRC_S  20228570    // int[200000]
#define F_PTR_O  20428570    // int[5001]
#define F_SRC_O  20433571    // int[200000]
#define F_PTR_A  20633571    // int[2001]
#define F_SRC_A  20635572    // int[60000]
#define F_EID_A  20695572    // int[60000]
#define F_RANK   20755572    // int[660000] -> ends 21,415,572 floats = 85.7 MB

extern "C" void kernel_launch(void* const* d_in, const int* in_sizes, int n_in,
                              void* d_out, int out_size, void* d_ws, size_t ws_size,
                              hipStream_t stream) {
    const float* x_op    = (const float*)d_in[0];
    const float* x_m     = (const float*)d_in[1];
    const float* x_a     = (const float*)d_in[2];
    const int*   ei_pred = (const int*)d_in[3];
    const int*   ei_succ = (const int*)d_in[4];
    const int*   src_o2m = (const int*)d_in[5];
    const int*   dst_o2m = (const int*)d_in[6];
    const int*   src_m2a = (const int*)d_in[7];
    const int*   dst_m2a = (const int*)d_in[8];
    const float* ea_m2a  = (const float*)d_in[9];

    const float* Wl_pred = (const float*)d_in[10];
    const float* bl_pred = (const float*)d_in[11];
    const float* Wr_pred = (const float*)d_in[12];
    const float* br_pred = (const float*)d_in[13];
    const float* att_pred= (const float*)d_in[14];
    const float* b_pred  = (const float*)d_in[15];

    const float* Wl_succ = (const float*)d_in[16];
    const float* bl_succ = (const float*)d_in[17];
    const float* Wr_succ = (const float*)d_in[18];
    const float* br_succ = (const float*)d_in[19];
    const float* att_succ= (const float*)d_in[20];
    const float* b_succ  = (const float*)d_in[21];

    const float* Wl_o2m  = (const float*)d_in[22];
    const float* bl_o2m  = (const float*)d_in[23];
    const float* Wr_o2m  = (const float*)d_in[24];
    const float* br_o2m  = (const float*)d_in[25];
    const float* att_o2m = (const float*)d_in[26];
    const float* b_o2m   = (const float*)d_in[27];

    const float* Wl_m2a  = (const float*)d_in[28];
    const float* bl_m2a  = (const float*)d_in[29];
    const float* Wr_m2a  = (const float*)d_in[30];
    const float* br_m2a  = (const float*)d_in[31];
    const float* att_m2a = (const float*)d_in[32];
    const float* b_m2a   = (const float*)d_in[33];
    const float* We_m2a  = (const float*)d_in[34];

    float* ws = (float*)d_ws;
    unsigned short* H     = (unsigned short*)(ws + F_H);
    unsigned short* xc_op = (unsigned short*)(ws + F_XCOP);
    unsigned short* xc_m  = (unsigned short*)(ws + F_XCM);
    unsigned short* xc_a  = (unsigned short*)(ws + F_XCA);
    unsigned short* BtP   = (unsigned short*)(ws + F_BTP);
    unsigned short* BtS   = (unsigned short*)(ws + F_BTS);
    unsigned short* BtOL  = (unsigned short*)(ws + F_BTOL);
    unsigned short* BtOR  = (unsigned short*)(ws + F_BTOR);
    unsigned short* BtML  = (unsigned short*)(ws + F_BTML);
    unsigned short* BtMR  = (unsigned short*)(ws + F_BTMR);
    float* biasP = ws + F_BIASP;
    float* biasS = ws + F_BIASS;
    int* cntP = (int*)(ws + F_CNT4);
    int* cntS = cntP + 50000;
    int* cntO = cntP + 100000;
    int* cntA = cntP + 105000;
    int* bsum = (int*)(ws + F_BSUM);
    int* boff = (int*)(ws + F_BOFF);
    int* ptrP = (int*)(ws + F_PTR_P); int* srcP = (int*)(ws + F_SRC_P);
    int* ptrS = (int*)(ws + F_PTR_S); int* srcS = (int*)(ws + F_SRC_S);
    int* ptrO = (int*)(ws + F_PTR_O); int* srcO = (int*)(ws + F_SRC_O);
    int* ptrA = (int*)(ws + F_PTR_A); int* srcA = (int*)(ws + F_SRC_A);
    int* eidA = (int*)(ws + F_EID_A);
    int* rk   = (int*)(ws + F_RANK);

    float* out_op = (float*)d_out + OUT_OP_OFF;
    float* out_m  = (float*)d_out + OUT_M_OFF;
    float* out_a  = (float*)d_out + OUT_A_OFF;

    // 1. zero counters (must precede the hist atomics)
    zero4<<<(NTOT + 255) / 256, 256, 0, stream>>>(cntP, NTOT);

    // 2. fused prep: hist+rank (latency-bound) overlapped with init3 + pack
    prep_all<<<PREP_TOTAL, 256, 0, stream>>>(
        ei_pred + E_OO, ei_succ + E_OO, dst_o2m, dst_m2a,
        cntP, cntS, cntO, cntA, rk,
        x_op, x_m, x_a, b_pred, b_succ, b_o2m, b_m2a,
        out_op, out_m, out_a, xc_op, xc_m, xc_a,
        Wl_pred, Wr_pred, Wl_succ, Wr_succ, Wl_o2m, Wr_o2m, Wl_m2a, Wr_m2a,
        bl_pred, br_pred, bl_succ, br_succ,
        BtP, BtS, BtOL, BtOR, BtML, BtMR, biasP, biasS);

    // 3-5. scan chain
    scan_blk4<<<NB_P + NB_S + NB_O + NB_A, 1024, 0, stream>>>(cntP, cntS, cntO, cntA,
                                                              ptrP, ptrS, ptrO, ptrA, bsum);
    scan_tops4<<<4, 1024, 0, stream>>>(bsum, boff, ptrP, ptrS, ptrO, ptrA);
    scan_add4<<<(NTOT + 255) / 256, 256, 0, stream>>>(ptrP, ptrS, ptrO, ptrA, boff);

    const int MT_OP = (N_OP + 127) / 128;   // 391
    const int MT_M  = (N_M + 127) / 128;    // 40
    const int MT_A  = (N_A + 127) / 128;    // 16

    // 6. conv-1 GEMM with CSR scatter fused into trailing blocks
    gemm_scat<<<dim3(MT_OP + SCAT_XBLK, 4), 256, 0, stream>>>(
        xc_op, BtP, biasP, H, N_OP, 256, 512, MT_OP,
        ei_pred, ei_pred + E_OO, ei_succ, ei_succ + E_OO,
        src_o2m, dst_o2m, src_m2a, dst_m2a,
        ptrP, ptrS, ptrO, ptrA, rk,
        srcP, srcS, srcO, srcA, eidA);
    // 7. conv 1 edge pipeline
    csr_serial2<256><<<(N_OP + 7) / 8, 256, 0, stream>>>(H, 512, H + 256, 512,
                                                         att_pred, ptrP, srcP, out_op, N_OP);

    // 8-9. conv 2
    mfma_gemm<<<dim3(MT_OP, 4), 256, 0, stream>>>(xc_op, BtS, biasS, H, N_OP, 256, 512);
    csr_serial2<256><<<(N_OP + 7) / 8, 256, 0, stream>>>(H, 512, H + 256, 512,
                                                         att_succ, ptrS, srcS, out_op, N_OP);

    // 10-11. conv 3: o2m (both GEMMs in one launch)
    {
        unsigned short* xlb = H;                 // [50000][128]
        unsigned short* xrb = H + 6400000;       // [5000][128]
        gemm_pair<<<dim3(MT_OP + MT_M, 1), 256, 0, stream>>>(
            xc_op, BtOL, bl_o2m, xlb, N_OP, 256, 128, MT_OP,
            xc_m, BtOR, br_o2m, xrb, N_M, 128, 128);
        csr_grp<128, false><<<(N_M + 3) / 4, 256, 0, stream>>>(xlb, 128, xrb, 128, nullptr,
                                                               att_o2m, ptrO, srcO, out_m, N_M);
    }

    // 12-13. conv 4: m2a (two GEMMs + edge-feature GEMM in one launch)
    {
        unsigned short* xlb = H;                 // [5000][128]
        unsigned short* xrb = H + 1000000;       // [2000][128]
        unsigned short* efb = H + 2000000;       // [60000][128] CSR-slot order
        gemm_tri<<<dim3(MT_M + MT_A + E_MA / 8, 1), 256, 0, stream>>>(
            xc_m, BtML, bl_m2a, xlb, N_M, 128, MT_M,
            xc_a, BtMR, br_m2a, xrb, N_A, 128, MT_M + MT_A,
            ea_m2a, We_m2a, eidA, efb);
        csr_grp<128, true><<<(N_A + 3) / 4, 256, 0, stream>>>(xlb, 128, xrb, 128, efb,
                                                              att_m2a, ptrA, srcA, out_a, N_A);
    }
}